// Round 8
// baseline (388.970 us; speedup 1.0000x reference)
//
#include <hip/hip_runtime.h>
#include <hip/hip_bf16.h>

#define Bq 2
#define Tq 2048
#define Cq 1024
#define Hq 16
#define HSq 64
#define EPSq 1e-5f

using bf16 = __hip_bfloat16;
using f32x4 = __attribute__((ext_vector_type(4))) float;
using f32x16 = __attribute__((ext_vector_type(16))) float;
using bf16x8 = __attribute__((ext_vector_type(8))) __bf16;

__device__ __forceinline__ bf16 f2bf(float f) { return __float2bfloat16(f); }
__device__ __forceinline__ unsigned short f2u(float f) {
    return __builtin_bit_cast(unsigned short, __float2bfloat16(f));
}
// async global->LDS, 16B per lane; LDS dest = wave-uniform base + lane*16
__device__ __forceinline__ void gload16(const void* g, void* l) {
    __builtin_amdgcn_global_load_lds((const __attribute__((address_space(1))) void*)g,
                                     (__attribute__((address_space(3))) void*)l, 16, 0, 0);
}

// q pre-scale: softmax 1/sqrt(64) * log2(e), so attn uses exp2 directly (saves
// one v_mul per S element vs __expf's internal mul).
#define QSCALE 0.180336884f

// ------------- transpose f32 src -> bf16 dst (dims multiples of 32) -------------
__global__ void k_transpose(const float* __restrict__ src, bf16* __restrict__ dst,
                            int R, int Cc, long strideSrc, long strideDst) {
    __shared__ bf16 tile[32][33];
    const long zb = blockIdx.z;
    src += zb * strideSrc;
    dst += zb * strideDst;
    int c0 = blockIdx.x * 32, r0 = blockIdx.y * 32;
    int tx = threadIdx.x & 31, ty = threadIdx.x >> 5;
    for (int i = ty; i < 32; i += 8)
        tile[i][tx] = f2bf(src[(long)(r0 + i) * Cc + (c0 + tx)]);
    __syncthreads();
    for (int i = ty; i < 32; i += 8)
        dst[(long)(c0 + i) * R + (r0 + tx)] = tile[tx][i];
}

// ---- fused: per-head transpose of Wq/Wk/Wv ([16][1024][64] -> [3072][1024] bf16)
//      + qkv bias pack piggyback ----------
__global__ void k_transpose3(const float* __restrict__ Wq, const float* __restrict__ Wk,
                             const float* __restrict__ Wv, const float* __restrict__ bqv,
                             const float* __restrict__ bkv, const float* __restrict__ bvv,
                             bf16* __restrict__ dst, float* __restrict__ bdst) {
    __shared__ bf16 tile[32][33];
    const int zb = blockIdx.z;  // 0..47
    const int which = zb >> 4, head = zb & 15;
    const float* src = (which == 0 ? Wq : which == 1 ? Wk : Wv) + (long)head * 65536;
    bf16* d = dst + (long)which * 1048576 + (long)head * 65536;
    int c0 = blockIdx.x * 32, r0 = blockIdx.y * 32;
    int tx = threadIdx.x & 31, ty = threadIdx.x >> 5;
    for (int i = ty; i < 32; i += 8)
        tile[i][tx] = f2bf(src[(long)(r0 + i) * 64 + (c0 + tx)]);
    if (blockIdx.x == 0 && blockIdx.y == 0 && zb < 12) {
        int i = zb * 256 + threadIdx.x;  // 0..3071
        bdst[i] = i < 1024 ? bqv[i] : i < 2048 ? bkv[i - 1024] : bvv[i - 2048];
    }
    __syncthreads();
    for (int i = ty; i < 32; i += 8)
        d[(long)(c0 + i) * 1024 + (r0 + tx)] = tile[tx][i];
}

// ---------------- LayerNorm over the SEQUENCE axis (per (b,c)), f32 in ----------
__global__ void k_ln_part(const float* __restrict__ x, float* __restrict__ ps,
                          float* __restrict__ pss) {
    int c = blockIdx.x * 256 + threadIdx.x;
    int b = blockIdx.y;
    int tc = blockIdx.z;  // 32 chunks of 64 timesteps
    const float* p = x + (long)b * Tq * Cq + (long)tc * 64 * Cq + c;
    float s = 0.f, ss = 0.f;
    for (int t = 0; t < 64; ++t) {
        float v = p[(long)t * Cq];
        s += v;
        ss += v * v;
    }
    long o = ((long)tc * Bq + b) * Cq + c;
    ps[o] = s;
    pss[o] = ss;
}

__global__ void k_ln_fin(const float* __restrict__ ps, const float* __restrict__ pss,
                         float* __restrict__ mean, float* __restrict__ rstd) {
    int i = blockIdx.x * 256 + threadIdx.x;  // b*Cq + c
    float s = 0.f, ss = 0.f;
    for (int tc = 0; tc < 32; ++tc) {
        s += ps[(long)tc * (Bq * Cq) + i];
        ss += pss[(long)tc * (Bq * Cq) + i];
    }
    float m = s / (float)Tq;
    float var = (ss - s * m) / (float)(Tq - 1);  // ddof=1 (unbiased)
    var = fmaxf(var, 0.f);
    mean[i] = m;
    rstd[i] = 1.0f / (sqrtf(var) + EPSq);  // eps OUTSIDE sqrt
}

__global__ void k_ln_apply(const float* __restrict__ x, const float* __restrict__ mean,
                           const float* __restrict__ rstd, const float* __restrict__ gamma,
                           const float* __restrict__ beta, bf16* __restrict__ out) {
    long i = (long)blockIdx.x * 256 + threadIdx.x;
    int c = (int)(i & (Cq - 1));
    long bt = i >> 10;
    int b = (int)(bt >> 11);
    float m = mean[b * Cq + c], r = rstd[b * Cq + c];
    out[i] = f2bf(gamma[c] * ((x[i] - m) * r) + beta[c]);
}

// XCD-aware bijective chunked swizzle (nwg % 8 == 0 for all our grids)
__device__ __forceinline__ void xcd_swizzle(int& bx, int& by) {
    const int gx = gridDim.x;
    const int nwg = gx * gridDim.y;
    const int bid = blockIdx.y * gx + blockIdx.x;
    const int swz = (bid & 7) * (nwg >> 3) + (bid >> 3);
    bx = swz % gx;
    by = swz / gx;
}

// ======= bf16 NT-GEMM 128x64, 2-deep counted-vmcnt pipeline (proj, FF2) =========
// Verified r7: proj+FF2 dropped below top-5 (was 61+17us). T3/T4 on the n64
// structure: 3 LDS buffers (72 KiB -> 2 blocks/CU), stage(t+2) post-barrier,
// ONE counted s_waitcnt vmcnt(6) per K-step. MODE 1/3: outF = acc+bias+residF.
template <int MODE>
__global__ __launch_bounds__(256, 2) void k_gemm_n64p(
    const bf16* __restrict__ A, int lda, const bf16* __restrict__ Bt, int ldb, int K,
    const float* __restrict__ bias, const float* __restrict__ residF,
    float* __restrict__ outF, int ldout) {
    __shared__ __bf16 lds[36864];  // 3 x 12288 (72 KiB)
    int bx, by;
    xcd_swizzle(bx, by);
    const int m0 = by * 128, n0 = bx * 64;
    const int tid = threadIdx.x;
    const int lane = tid & 63, wave = tid >> 6;
    const int lane15 = lane & 15, quad = lane >> 4;
    const int wm = wave * 32;
    const int srow = wave * 16 + (lane >> 2);
    const int scol = (((lane & 3) ^ ((lane >> 3) & 3)) * 8);  // pre-swizzled source
    const int sq8 = (quad ^ ((lane15 >> 1) & 3)) * 8;         // swizzled read slot
    const bf16* Ap = A + (long)(m0 + srow) * lda + scol;
    const bf16* Ap2 = Ap + 64L * lda;
    const bf16* Bp = Bt + (long)(n0 + srow) * ldb + scol;
    const int NT = K >> 6;

    f32x4 acc[2][4];
#pragma unroll
    for (int i = 0; i < 2; ++i)
#pragma unroll
        for (int j = 0; j < 4; ++j)
#pragma unroll
            for (int p = 0; p < 4; ++p) acc[i][j][p] = 0.f;

    auto stage = [&](int t, int ofs) {
        const long ko = (long)t << 6;
        __bf16* b = &lds[ofs + wave * 512];
        gload16(Ap + ko, b);
        gload16(Ap2 + ko, b + 2048);
        gload16(Ap + ko + 32, b + 4096);
        gload16(Ap2 + ko + 32, b + 6144);
        gload16(Bp + ko, b + 8192);
        gload16(Bp + ko + 32, b + 10240);
    };
    auto comp = [&](int ofs) {
        const __bf16* base = &lds[ofs];
#pragma unroll
        for (int kk = 0; kk < 2; ++kk) {
            bf16x8 af[2], bfr[4];
#pragma unroll
            for (int i = 0; i < 2; ++i)
                af[i] = *(const bf16x8*)(base + kk * 4096 + (wm + i * 16 + lane15) * 32 + sq8);
#pragma unroll
            for (int j = 0; j < 4; ++j)
                bfr[j] =
                    *(const bf16x8*)(base + 8192 + kk * 2048 + (j * 16 + lane15) * 32 + sq8);
#pragma unroll
            for (int i = 0; i < 2; ++i)
#pragma unroll
                for (int j = 0; j < 4; ++j)
                    acc[i][j] = __builtin_amdgcn_mfma_f32_16x16x32_bf16(af[i], bfr[j],
                                                                        acc[i][j], 0, 0, 0);
        }
    };

    stage(0, 0);
    stage(1, 12288);
    int o0 = 0, o1 = 12288, o2 = 24576;  // cur / next / staging target
    for (int t = 0; t < NT - 1; ++t) {
        asm volatile("s_waitcnt vmcnt(6)" ::: "memory");  // tile t landed (all 6)
        __builtin_amdgcn_s_barrier();
        if (t + 2 < NT) stage(t + 2, o2);
        comp(o0);
        const int tmp = o0;
        o0 = o1;
        o1 = o2;
        o2 = tmp;
    }
    asm volatile("s_waitcnt vmcnt(0)" ::: "memory");  // last tile
    __builtin_amdgcn_s_barrier();
    comp(o0);

#pragma unroll
    for (int i = 0; i < 2; ++i) {
#pragma unroll
        for (int p = 0; p < 4; ++p) {
            const int m = m0 + wm + i * 16 + quad * 4 + p;
#pragma unroll
            for (int j = 0; j < 4; ++j) {
                const int n = n0 + j * 16 + lane15;
                outF[(long)m * ldout + n] =
                    acc[i][j][p] + bias[n] + residF[(long)m * ldout + n];
            }
        }
    }
}

// ======== 256x256 8-phase pipelined NT-GEMM (m201 template, plain HIP) ==========
// Verified r5/r7 (MODE 2, FF1). T3+T4+T5; counted vmcnt(4) per K-tile.
// MODE 0: +bias, scatter qkv (q scaled by QSCALE, k plain, V^T packed).
// MODE 2: relu(+bias) -> bf16.
template <int MODE>
__global__ __launch_bounds__(512, 2) void k_gemm_8ph(
    const bf16* __restrict__ A, int lda, const bf16* __restrict__ Bt, int ldb, int K,
    const float* __restrict__ bias, bf16* __restrict__ outB, int ldout) {
    __shared__ __bf16 sA[2][2][256 * 32];
    __shared__ __bf16 sB[2][2][256 * 32];
    int bx, by;
    xcd_swizzle(bx, by);
    const int m0 = by * 256, n0 = bx * 256;
    const int tid = threadIdx.x;
    const int lane = tid & 63, wave = tid >> 6;
    const int lane15 = lane & 15, quad = lane >> 4;
    const int wr = wave >> 2, wc = wave & 3;  // wave tile: rows wr*128, cols wc*64
    const int sq8 = (quad ^ ((lane15 >> 1) & 3)) * 8;  // swizzled read slot
    const int arow = wr * 128 + lane15;
    const int brow = wc * 64 + lane15;
    const int sr = wave * 16 + (lane >> 2);                  // stage row
    const int sc = ((lane & 3) ^ ((lane >> 3) & 3)) * 8;     // pre-swizzled src slot
    const bf16* ApS = A + (long)(m0 + sr) * lda + sc;
    const bf16* BpS = Bt + (long)(n0 + sr) * ldb + sc;
    const int NT = K >> 6;       // K-tiles
    const int NP = NT << 2;      // planes (4 per tile)

    auto stage_plane = [&](int q) {
        if (q >= NP) return;
        const int t = q >> 2, slot = q & 3;
        const int db = t & 1, kk = slot >> 1;
        const long ko = ((long)t << 6) + kk * 32;
        if (!(slot & 1)) {
            gload16(ApS + ko, &sA[db][kk][wave * 512]);
            gload16(ApS + ko + 128L * lda, &sA[db][kk][4096 + wave * 512]);
        } else {
            gload16(BpS + ko, &sB[db][kk][wave * 512]);
            gload16(BpS + ko + 128L * ldb, &sB[db][kk][4096 + wave * 512]);
        }
    };

    f32x4 acc[8][4];
#pragma unroll
    for (int i = 0; i < 8; ++i)
#pragma unroll
        for (int j = 0; j < 4; ++j)
#pragma unroll
            for (int p = 0; p < 4; ++p) acc[i][j][p] = 0.f;

    stage_plane(0);
    stage_plane(1);
    stage_plane(2);
    stage_plane(3);
    stage_plane(4);
    stage_plane(5);
    asm volatile("s_waitcnt vmcnt(4)" ::: "memory");
    __builtin_amdgcn_s_barrier();

    for (int t = 0; t < NT; ++t) {
        const int db = t & 1;
        const __bf16* A0 = sA[db][0];
        const __bf16* A1 = sA[db][1];
        const __bf16* B0 = sB[db][0];
        const __bf16* B1 = sB[db][1];
        bf16x8 af[4], bfx[4];
        // ---- phase 0: kk0, m-half 0 ----
#pragma unroll
        for (int j = 0; j < 4; ++j)
            bfx[j] = *(const bf16x8*)(&B0[(brow + j * 16) * 32 + sq8]);
#pragma unroll
        for (int ii = 0; ii < 4; ++ii)
            af[ii] = *(const bf16x8*)(&A0[(arow + ii * 16) * 32 + sq8]);
        stage_plane(4 * t + 6);
        __builtin_amdgcn_s_barrier();
        __builtin_amdgcn_s_setprio(1);
#pragma unroll
        for (int ii = 0; ii < 4; ++ii)
#pragma unroll
            for (int j = 0; j < 4; ++j)
                acc[ii][j] =
                    __builtin_amdgcn_mfma_f32_16x16x32_bf16(af[ii], bfx[j], acc[ii][j], 0, 0, 0);
        __builtin_amdgcn_s_setprio(0);
        __builtin_amdgcn_s_barrier();
        // ---- phase 1: kk0, m-half 1 ----
#pragma unroll
        for (int ii = 0; ii < 4; ++ii)
            af[ii] = *(const bf16x8*)(&A0[(arow + 64 + ii * 16) * 32 + sq8]);
        stage_plane(4 * t + 7);
        __builtin_amdgcn_s_barrier();
        __builtin_amdgcn_s_setprio(1);
#pragma unroll
        for (int ii = 0; ii < 4; ++ii)
#pragma unroll
            for (int j = 0; j < 4; ++j)
                acc[4 + ii][j] = __builtin_amdgcn_mfma_f32_16x16x32_bf16(af[ii], bfx[j],
                                                                         acc[4 + ii][j], 0, 0, 0);
        __builtin_amdgcn_s_setprio(0);
        __builtin_amdgcn_s_barrier();
        // ---- phase 2: kk1, m-half 0 ----
#pragma unroll
        for (int j = 0; j < 4; ++j)
            bfx[j] = *(const bf16x8*)(&B1[(brow + j * 16) * 32 + sq8]);
#pragma unroll
        for (int ii = 0; ii < 4; ++ii)
            af[ii] = *(const bf16x8*)(&A1[(arow + ii * 16) * 32 + sq8]);
        stage_plane(4 * t + 8);
        __builtin_amdgcn_s_barrier();
        __builtin_amdgcn_s_setprio(1);
#pragma unroll
        for (int ii = 0; ii < 4; ++ii)
#pragma unroll
            for (int j = 0; j < 4; ++j)
                acc[ii][j] =
                    __builtin_amdgcn_mfma_f32_16x16x32_bf16(af[ii], bfx[j], acc[ii][j], 0, 0, 0);
        __builtin_amdgcn_s_setprio(0);
        __builtin_amdgcn_s_barrier();
        // ---- phase 3: kk1, m-half 1 ----
#pragma unroll
        for (int ii = 0; ii < 4; ++ii)
            af[ii] = *(const bf16x8*)(&A1[(arow + 64 + ii * 16) * 32 + sq8]);
        stage_plane(4 * t + 9);
        __builtin_amdgcn_s_barrier();
        __builtin_amdgcn_s_setprio(1);
#pragma unroll
        for (int ii = 0; ii < 4; ++ii)
#pragma unroll
            for (int j = 0; j < 4; ++j)
                acc[4 + ii][j] = __builtin_amdgcn_mfma_f32_16x16x32_bf16(af[ii], bfx[j],
                                                                         acc[4 + ii][j], 0, 0, 0);
        __builtin_amdgcn_s_setprio(0);
        asm volatile("s_waitcnt vmcnt(4)" ::: "memory");
        __builtin_amdgcn_s_barrier();
    }
    // epilogue (C/D layout col=lane&15, row=quad*4+reg; verified m89/m91)
    if (MODE == 0) {
#pragma unroll
        for (int i = 0; i < 8; ++i) {
            const int mm = m0 + wr * 128 + i * 16 + quad * 4;  // t base; p adds 0..3
            const int b = mm >> 11, t4 = mm & (Tq - 1);
#pragma unroll
            for (int j = 0; j < 4; ++j) {
                const int n = n0 + wc * 64 + j * 16 + lane15;
                const int which = n >> 10, hh = (n >> 6) & (Hq - 1), d = n & (HSq - 1);
                const long bh = (long)b * Hq + hh;
                const float bb = bias[n];
                if (which == 0) {  // q, pre-scaled by QSCALE (softmax*log2e folded)
#pragma unroll
                    for (int p = 0; p < 4; ++p)
                        outB[bh * 131072 + (long)(t4 + p) * HSq + d] =
                            f2bf((acc[i][j][p] + bb) * QSCALE);
                } else if (which == 1) {  // k
#pragma unroll
                    for (int p = 0; p < 4; ++p)
                        outB[4194304L + bh * 131072 + (long)(t4 + p) * HSq + d] =
                            f2bf(acc[i][j][p] + bb);
                } else {  // V stored transposed [bh][d][t], 4 consecutive t packed
                    ushort4 pk;
                    pk.x = f2u(acc[i][j][0] + bb);
                    pk.y = f2u(acc[i][j][1] + bb);
                    pk.z = f2u(acc[i][j][2] + bb);
                    pk.w = f2u(acc[i][j][3] + bb);
                    *(ushort4*)(&outB[8388608L + bh * 131072 + (long)d * Tq + t4]) = pk;
                }
            }
        }
    } else {  // MODE 2: relu(acc + bias) -> bf16
#pragma unroll
        for (int i = 0; i < 8; ++i) {
#pragma unroll
            for (int p = 0; p < 4; ++p) {
                const int m = m0 + wr * 128 + i * 16 + quad * 4 + p;
#pragma unroll
                for (int j = 0; j < 4; ++j) {
                    const int n = n0 + wc * 64 + j * 16 + lane15;
                    outB[(long)m * ldout + n] = f2bf(fmaxf(acc[i][j][p] + bias[n], 0.f));
                }
            }
        }
    }
}

// ---------------- flash attention, kc-split x2, bh-major XCD locality ------------
// Block remap: XCD x (= linear id % 8, HW round-robin) owns bh in {4x..4x+3}; all
// 32 blocks (16 q-tiles x 2 kc-halves) sharing one bh's K/V land on ONE XCD ->
// K/V (512 KB x 4 bh = 2 MB) stays L2-resident instead of 8-XCD re-fetch.
// Bijective remap: correctness-invariant even if the dispatch assumption is off.
// q is pre-scaled by QSCALE (1/8 * log2e) -> exp2f, no per-element mul.
__global__ __launch_bounds__(256, 4) void k_attn(const bf16* __restrict__ qkv,
                                                 float* __restrict__ po0,
                                                 float* __restrict__ po1,
                                                 float* __restrict__ rs0,
                                                 float* __restrict__ rs1) {
    __shared__ __bf16 sK[64 * 72];
    __shared__ __bf16 sVt[64 * 72];
    const int nlin = blockIdx.x + (int)(gridDim.x * (blockIdx.y + gridDim.y * blockIdx.z));
    const int xcd = nlin & 7, s = nlin >> 3;
    const int bh = (xcd << 2) | (s >> 5);
    const int rem = s & 31;
    const int q0 = (rem & 15) * 128;
    const int z = rem >> 4;
    const int kc0 = z << 10;
    float* __restrict__ po = z ? po1 : po0;
    float* __restrict__ rsb = z ? rs1 : rs0;
    const int tid = threadIdx.x, wave = tid >> 6, lane = tid & 63;
    const int lane31 = lane & 31, laneh = lane >> 5;
    const bf16* Qp = qkv + (long)bh * 131072;
    const bf16* Kp = qkv + 4194304L + (long)bh * 131072;
    const bf16* Vtp = qkv + 8388608L + (long)bh * 131072;
    bf16x8 qa[4];
#pragma unroll
    for (int s2 = 0; s2 < 4; ++s2)
        qa[s2] = *(const bf16x8*)(&Qp[(long)(q0 + wave * 32 + lane31) * HSq + s2 * 16 + laneh * 8]);
    f32x16 o[2];
#pragma unroll
    for (int dt = 0; dt < 2; ++dt)
#pragma unroll
        for (int r = 0; r < 16; ++r) o[dt][r] = 0.f;
    float rs = 0.f;
    const int r0 = tid >> 3, c0 = (tid & 7) * 8;
    const int r1 = r0 + 32;

    uint4 nk0 = *(const uint4*)(&Kp[(long)(kc0 + r0) * HSq + c0]);
    uint4 nk1 = *(const uint4*)(&Kp[(long)(kc0 + r1) * HSq + c0]);
    uint4 nv0 = *(const uint4*)(&Vtp[(long)r0 * Tq + kc0 + c0]);
    uint4 nv1 = *(const uint4*)(&Vtp[(long)r1 * Tq + kc0 + c0]);

    for (int kc = kc0; kc < kc0 + 1024; kc += 64) {
        __syncthreads();
        *(uint4*)(&sK[r0 * 72 + c0]) = nk0;
        *(uint4*)(&sK[r1 * 72 + c0]) = nk1;
        *(uint4*)(&sVt[r0 * 72 + c0]) = nv0;
        *(uint4*)(&sVt[r1 * 72 + c0]) = nv1;
        __syncthreads();
        if (kc + 64 < kc0 + 1024) {
            nk0 = *(const uint4*)(&Kp[(long)(kc + 64 + r0) * HSq + c0]);
            nk1 = *(const uint4*)(&Kp[(long)(kc + 64 + r1) * HSq + c0]);
            nv0 = *(const uint4*)(&Vtp[(long)r0 * Tq + kc + 64 + c0]);
            nv1 = *(const uint4*)(&Vtp[(long)r1 * Tq + kc + 64 + c0]);
        }
#pragma unroll
        for (int nt = 0; nt < 2; ++nt) {
            f32x16 zz;
#pragma unroll
            for (int r = 0; r < 16; ++r) zz[r] = 0.f;
            __builtin_amdgcn_s_setprio(1);
#pragma unroll
            for (int s2 = 0; s2 < 4; ++s2) {
                bf16x8 kb =
                    *(const bf16x8*)(&sK[(nt * 32 + lane31) * 72 + s2 * 16 + laneh * 8]);
                zz = __builtin_amdgcn_mfma_f32_32x32x16_bf16(kb, qa[s2], zz, 0, 0, 0);
            }
            __builtin_amdgcn_s_setprio(0);
            float e[16];
#pragma unroll
            for (int r = 0; r < 16; ++r) {
                e[r] = exp2f(zz[r]);  // q pre-scaled by log2e: exp2 == exp
                rs += e[r];
            }
            unsigned int pk[8];
#pragma unroll
            for (int g = 0; g < 4; ++g)
#pragma unroll
                for (int h = 0; h < 2; ++h)
                    pk[g * 2 + h] = (unsigned int)f2u(e[g * 4 + 2 * h]) |
                                    ((unsigned int)f2u(e[g * 4 + 2 * h + 1]) << 16);
            unsigned int sa0 = laneh ? pk[0] : pk[2], sa1 = laneh ? pk[1] : pk[3];
            unsigned int ra0 = __shfl_xor((int)sa0, 32), ra1 = __shfl_xor((int)sa1, 32);
            unsigned int sb0 = laneh ? pk[4] : pk[6], sb1 = laneh ? pk[5] : pk[7];
            unsigned int rb0 = __shfl_xor((int)sb0, 32), rb1 = __shfl_xor((int)sb1, 32);
            uint4 f0, f1;
            if (laneh == 0) {
                f0 = {pk[0], pk[1], ra0, ra1};
                f1 = {pk[4], pk[5], rb0, rb1};
            } else {
                f0 = {ra0, ra1, pk[2], pk[3]};
                f1 = {rb0, rb1, pk[6], pk[7]};
            }
            bf16x8 pa0 = __builtin_bit_cast(bf16x8, f0);
            bf16x8 pa1 = __builtin_bit_cast(bf16x8, f1);
            __builtin_amdgcn_s_setprio(1);
#pragma unroll
            for (int dt = 0; dt < 2; ++dt) {
                bf16x8 vb0 =
                    *(const bf16x8*)(&sVt[(dt * 32 + lane31) * 72 + nt * 32 + laneh * 8]);
                bf16x8 vb1 = *(const bf16x8*)(&sVt[(dt * 32 + lane31) * 72 + nt * 32 + 16 +
                                                   laneh * 8]);
                o[dt] = __builtin_amdgcn_mfma_f32_32x32x16_bf16(pa0, vb0, o[dt], 0, 0, 0);
                o[dt] = __builtin_amdgcn_mfma_f32_32x32x16_bf16(pa1, vb1, o[dt], 0, 0, 0);
            }
            __builtin_amdgcn_s_setprio(0);
        }
    }
    // partial epilogue: store unnormalized O (f32) + this half's row sums
    float ltot = rs + __shfl_xor(rs, 32);
    if (laneh == 0) rsb[(bh << 11) + q0 + wave * 32 + lane31] = ltot;
#pragma unroll
    for (int r = 0; r < 16; ++r) {
        const int tl = (r & 3) + 8 * (r >> 2) + 4 * laneh;
        const int t = q0 + wave * 32 + tl;
        float* pb = po + ((long)(bh << 11) + t) * 64;
#pragma unroll
        for (int dt = 0; dt < 2; ++dt) pb[dt * 32 + lane31] = o[dt][r];
    }
}

// combine: out[b][t][h*64+d] = bf16((po0+po1) / (rs0+rs1)) — 4 floats/thread
__global__ __launch_bounds__(256) void k_attn_combine(
    const float* __restrict__ po0, const float* __restrict__ po1,
    const float* __restrict__ rs0, const float* __restrict__ rs1,
    bf16* __restrict__ out) {
    const long i = ((long)blockIdx.x * 256 + threadIdx.x) * 4;
    const int d = (int)(i & 63);
    const long qq = i >> 6;  // bh*2048 + t
    const int bh = (int)(qq >> 11), t = (int)(qq & 2047);
    const float inv = 1.0f / (rs0[qq] + rs1[qq]);
    const f32x4 a = *(const f32x4*)(po0 + i);
    const f32x4 b = *(const f32x4*)(po1 + i);
    const int bb = bh >> 4, hh = bh & 15;
    ushort4 pk;
    pk.x = f2u((a[0] + b[0]) * inv);
    pk.y = f2u((a[1] + b[1]) * inv);
    pk.z = f2u((a[2] + b[2]) * inv);
    pk.w = f2u((a[3] + b[3]) * inv);
    *(ushort4*)(&out[(((long)bb * Tq + t) << 10) + hh * 64 + d]) = pk;
}

extern "C" void kernel_launch(void* const* d_in, const int* in_sizes, int n_in,
                              void* d_out, int out_size, void* d_ws, size_t ws_size,
                              hipStream_t stream) {
    const float* x = (const float*)d_in[0];
    const float* Wq = (const float*)d_in[1];
    const float* bqv = (const float*)d_in[2];
    const float* Wk = (const float*)d_in[3];
    const float* bkv = (const float*)d_in[4];
    const float* Wv = (const float*)d_in[5];
    const float* bvv = (const float*)d_in[6];
    const float* Wo = (const float*)d_in[7];
    const float* bo = (const float*)d_in[8];
    const float* W1 = (const float*)d_in[9];
    const float* b1 = (const float*)d_in[10];
    const float* W2 = (const float*)d_in[11];
    const float* b2 = (const float*)d_in[12];
    const float* g1 = (const float*)d_in[13];
    const float* be1 = (const float*)d_in[14];
    const float* g2 = (const float*)d_in[15];
    const float* be2 = (const float*)d_in[16];

    // ---- workspace: ~56.7 MiB total (safe under 64 MiB) ----
    char* ws = (char*)d_ws;
    size_t off = 0;
    auto alloc = [&](size_t bytes) {
        void* p = ws + off;
        off += (bytes + 255) & ~(size_t)255;
        return p;
    };
    bf16* regA = (bf16*)alloc(32L * 1024 * 1024);  // qkv (24 MiB)+attn_out tail, then a1 (32 MiB)
    float* x2 = (float*)alloc(4096L * 1024 * 4);   // 16 MiB: attn po0 scratch, then f32 residual
    bf16* buf1 = (bf16*)alloc(4096L * 1024 * 2);   // 8 MiB: WqkvT -> WoT -> W1T -> W2T
    float* bqkv = (float*)alloc(3072L * 4);
    float* ps = (float*)alloc(32L * Bq * Cq * 4);  // LN partials; attn rs0 scratch
    float* pss = (float*)alloc(32L * Bq * Cq * 4); // LN partials; attn rs1 scratch
    float* mean1 = (float*)alloc(Bq * Cq * 4);
    float* rstd1 = (float*)alloc(Bq * Cq * 4);
    float* mean2 = (float*)alloc(Bq * Cq * 4);
    float* rstd2 = (float*)alloc(Bq * Cq * 4);
    bf16* dres = (bf16*)d_out;          // d_out first 8 MiB bf16 scratch: h -> h2
    float* outF = (float*)d_out;
    float* po1 = (float*)d_out;         // full 16 MiB of d_out as attn po1 (h dead then)
    bf16* attn_out = regA + 12582912;   // 8 MiB free tail of regA (qkv uses 24 of 32 MiB)

    // LN1 -> h (bf16, in d_out)
    k_ln_part<<<dim3(4, Bq, 32), 256, 0, stream>>>(x, ps, pss);
    k_ln_fin<<<dim3(8), 256, 0, stream>>>(ps, pss, mean1, rstd1);
    k_ln_apply<<<dim3(16384), 256, 0, stream>>>(x, mean1, rstd1, g1, be1, dres);

    // Wq/Wk/Wv per-head transpose + bias pack (single launch)
    k_transpose3<<<dim3(2, 32, 48), 256, 0, stream>>>(Wq, Wk, Wv, bqv, bkv, bvv, buf1, bqkv);
    // QKV projection -> q(scaled),k,vt in regA  (8-phase 256^2 pipeline, 192 blocks)
    k_gemm_8ph<0><<<dim3(12, 16), 512, 0, stream>>>(dres, 1024, buf1, 1024, 1024, bqkv, regA, 0);
    // attention kc-split x2 -> partials (po0=x2, po1=d_out, rs in ps/pss)
    k_attn<<<dim3(16, 32, 2), 256, 0, stream>>>(regA, x2, po1, ps, pss);
    k_attn_combine<<<dim3(4096), 256, 0, stream>>>(x2, po1, ps, pss, attn_out);
    // Wo^T -> buf1; x2 = attn@Wo + bo + x   (pipelined 128x64, 512 blocks, 2/CU)
    k_transpose<<<dim3(32, 32, 1), 256, 0, stream>>>(Wo, buf1, 1024, 1024, 0, 0);
    k_gemm_n64p<1><<<dim3(16, 32), 256, 0, stream>>>(attn_out, 1024, buf1, 1024, 1024, bo, x,
                                                     x2, 1024);
    // LN2 -> h2 (bf16, in d_out; po1 dead)
    k_ln_part<<<dim3(4, Bq, 32), 256, 0, stream>>>(x2, ps, pss);
    k_ln_fin<<<dim3(8), 256, 0, stream>>>(ps, pss, mean2, rstd2);
    k_ln_apply<<<dim3(16384), 256, 0, stream>>>(x2, mean2, rstd2, g2, be2, dres);

    // ---- FF ----
    k_transpose<<<dim3(128, 32, 1), 256, 0, stream>>>(W1, buf1, 1024, 4096, 0, 0);  // W1T
    // a1 = relu(h2 @ W1T + b1) -> regA [4096][4096] bf16  (8-phase 256^2 pipeline)
    k_gemm_8ph<2><<<dim3(16, 16), 512, 0, stream>>>(dres, 1024, buf1, 1024, 1024, b1, regA,
                                                    4096);
    k_transpose<<<dim3(32, 128, 1), 256, 0, stream>>>(W2, buf1, 4096, 1024, 0, 0);  // W2T
    // d_out(f32) = a1 @ W2T + b2 + x2   (pipelined 128x64, 512 blocks, 2/CU)
    k_gemm_n64p<3><<<dim3(16, 32), 256, 0, stream>>>(regA, 4096, buf1, 4096, 4096, b2, x2,
                                                     outF, 1024);
}

// Round 9
// 382.650 us; speedup vs baseline: 1.0165x; 1.0165x over previous
//
#include <hip/hip_runtime.h>
#include <hip/hip_bf16.h>

#define Bq 2
#define Tq 2048
#define Cq 1024
#define Hq 16
#define HSq 64
#define EPSq 1e-5f

using bf16 = __hip_bfloat16;
using f32x4 = __attribute__((ext_vector_type(4))) float;
using f32x16 = __attribute__((ext_vector_type(16))) float;
using bf16x8 = __attribute__((ext_vector_type(8))) __bf16;

__device__ __forceinline__ bf16 f2bf(float f) { return __float2bfloat16(f); }
__device__ __forceinline__ unsigned short f2u(float f) {
    return __builtin_bit_cast(unsigned short, __float2bfloat16(f));
}
// async global->LDS, 16B per lane; LDS dest = wave-uniform base + lane*16
__device__ __forceinline__ void gload16(const void* g, void* l) {
    __builtin_amdgcn_global_load_lds((const __attribute__((address_space(1))) void*)g,
                                     (__attribute__((address_space(3))) void*)l, 16, 0, 0);
}

// q pre-scale: softmax 1/sqrt(64) * log2(e); attn uses raw v_exp_f32 (exp2).
#define QSCALE 0.180336884f

// ------------- transpose f32 src -> bf16 dst (dims multiples of 32) -------------
__global__ void k_transpose(const float* __restrict__ src, bf16* __restrict__ dst,
                            int R, int Cc, long strideSrc, long strideDst) {
    __shared__ bf16 tile[32][33];
    const long zb = blockIdx.z;
    src += zb * strideSrc;
    dst += zb * strideDst;
    int c0 = blockIdx.x * 32, r0 = blockIdx.y * 32;
    int tx = threadIdx.x & 31, ty = threadIdx.x >> 5;
    for (int i = ty; i < 32; i += 8)
        tile[i][tx] = f2bf(src[(long)(r0 + i) * Cc + (c0 + tx)]);
    __syncthreads();
    for (int i = ty; i < 32; i += 8)
        dst[(long)(c0 + i) * R + (r0 + tx)] = tile[tx][i];
}

// ---- fused: per-head transpose of Wq/Wk/Wv ([16][1024][64] -> [3072][1024] bf16)
//      + qkv bias pack piggyback ----------
__global__ void k_transpose3(const float* __restrict__ Wq, const float* __restrict__ Wk,
                             const float* __restrict__ Wv, const float* __restrict__ bqv,
                             const float* __restrict__ bkv, const float* __restrict__ bvv,
                             bf16* __restrict__ dst, float* __restrict__ bdst) {
    __shared__ bf16 tile[32][33];
    const int zb = blockIdx.z;  // 0..47
    const int which = zb >> 4, head = zb & 15;
    const float* src = (which == 0 ? Wq : which == 1 ? Wk : Wv) + (long)head * 65536;
    bf16* d = dst + (long)which * 1048576 + (long)head * 65536;
    int c0 = blockIdx.x * 32, r0 = blockIdx.y * 32;
    int tx = threadIdx.x & 31, ty = threadIdx.x >> 5;
    for (int i = ty; i < 32; i += 8)
        tile[i][tx] = f2bf(src[(long)(r0 + i) * 64 + (c0 + tx)]);
    if (blockIdx.x == 0 && blockIdx.y == 0 && zb < 12) {
        int i = zb * 256 + threadIdx.x;  // 0..3071
        bdst[i] = i < 1024 ? bqv[i] : i < 2048 ? bkv[i - 1024] : bvv[i - 2048];
    }
    __syncthreads();
    for (int i = ty; i < 32; i += 8)
        d[(long)(c0 + i) * 1024 + (r0 + tx)] = tile[tx][i];
}

// ---------------- LayerNorm over the SEQUENCE axis (per (b,c)), f32 in ----------
__global__ void k_ln_part(const float* __restrict__ x, float* __restrict__ ps,
                          float* __restrict__ pss) {
    int c = blockIdx.x * 256 + threadIdx.x;
    int b = blockIdx.y;
    int tc = blockIdx.z;  // 32 chunks of 64 timesteps
    const float* p = x + (long)b * Tq * Cq + (long)tc * 64 * Cq + c;
    float s = 0.f, ss = 0.f;
    for (int t = 0; t < 64; ++t) {
        float v = p[(long)t * Cq];
        s += v;
        ss += v * v;
    }
    long o = ((long)tc * Bq + b) * Cq + c;
    ps[o] = s;
    pss[o] = ss;
}

__global__ void k_ln_fin(const float* __restrict__ ps, const float* __restrict__ pss,
                         float* __restrict__ mean, float* __restrict__ rstd) {
    int i = blockIdx.x * 256 + threadIdx.x;  // b*Cq + c
    float s = 0.f, ss = 0.f;
    for (int tc = 0; tc < 32; ++tc) {
        s += ps[(long)tc * (Bq * Cq) + i];
        ss += pss[(long)tc * (Bq * Cq) + i];
    }
    float m = s / (float)Tq;
    float var = (ss - s * m) / (float)(Tq - 1);  // ddof=1 (unbiased)
    var = fmaxf(var, 0.f);
    mean[i] = m;
    rstd[i] = 1.0f / (sqrtf(var) + EPSq);  // eps OUTSIDE sqrt
}

__global__ void k_ln_apply(const float* __restrict__ x, const float* __restrict__ mean,
                           const float* __restrict__ rstd, const float* __restrict__ gamma,
                           const float* __restrict__ beta, bf16* __restrict__ out) {
    long i = (long)blockIdx.x * 256 + threadIdx.x;
    int c = (int)(i & (Cq - 1));
    long bt = i >> 10;
    int b = (int)(bt >> 11);
    float m = mean[b * Cq + c], r = rstd[b * Cq + c];
    out[i] = f2bf(gamma[c] * ((x[i] - m) * r) + beta[c]);
}

// XCD-aware bijective chunked swizzle (nwg % 8 == 0 for all our grids)
__device__ __forceinline__ void xcd_swizzle(int& bx, int& by) {
    const int gx = gridDim.x;
    const int nwg = gx * gridDim.y;
    const int bid = blockIdx.y * gx + blockIdx.x;
    const int swz = (bid & 7) * (nwg >> 3) + (bid >> 3);
    bx = swz % gx;
    by = swz / gx;
}

// ======= bf16 NT-GEMM 128x64, 2-deep counted-vmcnt pipeline (proj, FF2) =========
// Verified r7. T3/T4 on the n64 structure: 3 LDS buffers (72 KiB -> 2 blocks/CU),
// stage(t+2) post-barrier, ONE counted s_waitcnt vmcnt(6) per K-step.
// MODE 1/3: outF = acc+bias+residF.
template <int MODE>
__global__ __launch_bounds__(256, 2) void k_gemm_n64p(
    const bf16* __restrict__ A, int lda, const bf16* __restrict__ Bt, int ldb, int K,
    const float* __restrict__ bias, const float* __restrict__ residF,
    float* __restrict__ outF, int ldout) {
    __shared__ __bf16 lds[36864];  // 3 x 12288 (72 KiB)
    int bx, by;
    xcd_swizzle(bx, by);
    const int m0 = by * 128, n0 = bx * 64;
    const int tid = threadIdx.x;
    const int lane = tid & 63, wave = tid >> 6;
    const int lane15 = lane & 15, quad = lane >> 4;
    const int wm = wave * 32;
    const int srow = wave * 16 + (lane >> 2);
    const int scol = (((lane & 3) ^ ((lane >> 3) & 3)) * 8);  // pre-swizzled source
    const int sq8 = (quad ^ ((lane15 >> 1) & 3)) * 8;         // swizzled read slot
    const bf16* Ap = A + (long)(m0 + srow) * lda + scol;
    const bf16* Ap2 = Ap + 64L * lda;
    const bf16* Bp = Bt + (long)(n0 + srow) * ldb + scol;
    const int NT = K >> 6;

    f32x4 acc[2][4];
#pragma unroll
    for (int i = 0; i < 2; ++i)
#pragma unroll
        for (int j = 0; j < 4; ++j)
#pragma unroll
            for (int p = 0; p < 4; ++p) acc[i][j][p] = 0.f;

    auto stage = [&](int t, int ofs) {
        const long ko = (long)t << 6;
        __bf16* b = &lds[ofs + wave * 512];
        gload16(Ap + ko, b);
        gload16(Ap2 + ko, b + 2048);
        gload16(Ap + ko + 32, b + 4096);
        gload16(Ap2 + ko + 32, b + 6144);
        gload16(Bp + ko, b + 8192);
        gload16(Bp + ko + 32, b + 10240);
    };
    auto comp = [&](int ofs) {
        const __bf16* base = &lds[ofs];
#pragma unroll
        for (int kk = 0; kk < 2; ++kk) {
            bf16x8 af[2], bfr[4];
#pragma unroll
            for (int i = 0; i < 2; ++i)
                af[i] = *(const bf16x8*)(base + kk * 4096 + (wm + i * 16 + lane15) * 32 + sq8);
#pragma unroll
            for (int j = 0; j < 4; ++j)
                bfr[j] =
                    *(const bf16x8*)(base + 8192 + kk * 2048 + (j * 16 + lane15) * 32 + sq8);
#pragma unroll
            for (int i = 0; i < 2; ++i)
#pragma unroll
                for (int j = 0; j < 4; ++j)
                    acc[i][j] = __builtin_amdgcn_mfma_f32_16x16x32_bf16(af[i], bfr[j],
                                                                        acc[i][j], 0, 0, 0);
        }
    };

    stage(0, 0);
    stage(1, 12288);
    int o0 = 0, o1 = 12288, o2 = 24576;  // cur / next / staging target
    for (int t = 0; t < NT - 1; ++t) {
        asm volatile("s_waitcnt vmcnt(6)" ::: "memory");  // tile t landed (all 6)
        __builtin_amdgcn_s_barrier();
        if (t + 2 < NT) stage(t + 2, o2);
        comp(o0);
        const int tmp = o0;
        o0 = o1;
        o1 = o2;
        o2 = tmp;
    }
    asm volatile("s_waitcnt vmcnt(0)" ::: "memory");  // last tile
    __builtin_amdgcn_s_barrier();
    comp(o0);

#pragma unroll
    for (int i = 0; i < 2; ++i) {
#pragma unroll
        for (int p = 0; p < 4; ++p) {
            const int m = m0 + wm + i * 16 + quad * 4 + p;
#pragma unroll
            for (int j = 0; j < 4; ++j) {
                const int n = n0 + j * 16 + lane15;
                outF[(long)m * ldout + n] =
                    acc[i][j][p] + bias[n] + residF[(long)m * ldout + n];
            }
        }
    }
}

// ======== 256x256 8-phase pipelined NT-GEMM (m201 template, plain HIP) ==========
// Verified r5/r7/r8. T3+T4+T5; counted vmcnt(4) per K-tile.
// MODE 0: +bias, scatter qkv (q scaled by QSCALE, k plain, V^T packed).
// MODE 2: relu(+bias) -> bf16.
template <int MODE>
__global__ __launch_bounds__(512, 2) void k_gemm_8ph(
    const bf16* __restrict__ A, int lda, const bf16* __restrict__ Bt, int ldb, int K,
    const float* __restrict__ bias, bf16* __restrict__ outB, int ldout) {
    __shared__ __bf16 sA[2][2][256 * 32];
    __shared__ __bf16 sB[2][2][256 * 32];
    int bx, by;
    xcd_swizzle(bx, by);
    const int m0 = by * 256, n0 = bx * 256;
    const int tid = threadIdx.x;
    const int lane = tid & 63, wave = tid >> 6;
    const int lane15 = lane & 15, quad = lane >> 4;
    const int wr = wave >> 2, wc = wave & 3;  // wave tile: rows wr*128, cols wc*64
    const int sq8 = (quad ^ ((lane15 >> 1) & 3)) * 8;  // swizzled read slot
    const int arow = wr * 128 + lane15;
    const int brow = wc * 64 + lane15;
    const int sr = wave * 16 + (lane >> 2);                  // stage row
    const int sc = ((lane & 3) ^ ((lane >> 3) & 3)) * 8;     // pre-swizzled src slot
    const bf16* ApS = A + (long)(m0 + sr) * lda + sc;
    const bf16* BpS = Bt + (long)(n0 + sr) * ldb + sc;
    const int NT = K >> 6;       // K-tiles
    const int NP = NT << 2;      // planes (4 per tile)

    auto stage_plane = [&](int q) {
        if (q >= NP) return;
        const int t = q >> 2, slot = q & 3;
        const int db = t & 1, kk = slot >> 1;
        const long ko = ((long)t << 6) + kk * 32;
        if (!(slot & 1)) {
            gload16(ApS + ko, &sA[db][kk][wave * 512]);
            gload16(ApS + ko + 128L * lda, &sA[db][kk][4096 + wave * 512]);
        } else {
            gload16(BpS + ko, &sB[db][kk][wave * 512]);
            gload16(BpS + ko + 128L * ldb, &sB[db][kk][4096 + wave * 512]);
        }
    };

    f32x4 acc[8][4];
#pragma unroll
    for (int i = 0; i < 8; ++i)
#pragma unroll
        for (int j = 0; j < 4; ++j)
#pragma unroll
            for (int p = 0; p < 4; ++p) acc[i][j][p] = 0.f;

    stage_plane(0);
    stage_plane(1);
    stage_plane(2);
    stage_plane(3);
    stage_plane(4);
    stage_plane(5);
    asm volatile("s_waitcnt vmcnt(4)" ::: "memory");
    __builtin_amdgcn_s_barrier();

    for (int t = 0; t < NT; ++t) {
        const int db = t & 1;
        const __bf16* A0 = sA[db][0];
        const __bf16* A1 = sA[db][1];
        const __bf16* B0 = sB[db][0];
        const __bf16* B1 = sB[db][1];
        bf16x8 af[4], bfx[4];
        // ---- phase 0: kk0, m-half 0 ----
#pragma unroll
        for (int j = 0; j < 4; ++j)
            bfx[j] = *(const bf16x8*)(&B0[(brow + j * 16) * 32 + sq8]);
#pragma unroll
        for (int ii = 0; ii < 4; ++ii)
            af[ii] = *(const bf16x8*)(&A0[(arow + ii * 16) * 32 + sq8]);
        stage_plane(4 * t + 6);
        __builtin_amdgcn_s_barrier();
        __builtin_amdgcn_s_setprio(1);
#pragma unroll
        for (int ii = 0; ii < 4; ++ii)
#pragma unroll
            for (int j = 0; j < 4; ++j)
                acc[ii][j] =
                    __builtin_amdgcn_mfma_f32_16x16x32_bf16(af[ii], bfx[j], acc[ii][j], 0, 0, 0);
        __builtin_amdgcn_s_setprio(0);
        __builtin_amdgcn_s_barrier();
        // ---- phase 1: kk0, m-half 1 ----
#pragma unroll
        for (int ii = 0; ii < 4; ++ii)
            af[ii] = *(const bf16x8*)(&A0[(arow + 64 + ii * 16) * 32 + sq8]);
        stage_plane(4 * t + 7);
        __builtin_amdgcn_s_barrier();
        __builtin_amdgcn_s_setprio(1);
#pragma unroll
        for (int ii = 0; ii < 4; ++ii)
#pragma unroll
            for (int j = 0; j < 4; ++j)
                acc[4 + ii][j] = __builtin_amdgcn_mfma_f32_16x16x32_bf16(af[ii], bfx[j],
                                                                         acc[4 + ii][j], 0, 0, 0);
        __builtin_amdgcn_s_setprio(0);
        __builtin_amdgcn_s_barrier();
        // ---- phase 2: kk1, m-half 0 ----
#pragma unroll
        for (int j = 0; j < 4; ++j)
            bfx[j] = *(const bf16x8*)(&B1[(brow + j * 16) * 32 + sq8]);
#pragma unroll
        for (int ii = 0; ii < 4; ++ii)
            af[ii] = *(const bf16x8*)(&A1[(arow + ii * 16) * 32 + sq8]);
        stage_plane(4 * t + 8);
        __builtin_amdgcn_s_barrier();
        __builtin_amdgcn_s_setprio(1);
#pragma unroll
        for (int ii = 0; ii < 4; ++ii)
#pragma unroll
            for (int j = 0; j < 4; ++j)
                acc[ii][j] =
                    __builtin_amdgcn_mfma_f32_16x16x32_bf16(af[ii], bfx[j], acc[ii][j], 0, 0, 0);
        __builtin_amdgcn_s_setprio(0);
        __builtin_amdgcn_s_barrier();
        // ---- phase 3: kk1, m-half 1 ----
#pragma unroll
        for (int ii = 0; ii < 4; ++ii)
            af[ii] = *(const bf16x8*)(&A1[(arow + 64 + ii * 16) * 32 + sq8]);
        stage_plane(4 * t + 9);
        __builtin_amdgcn_s_barrier();
        __builtin_amdgcn_s_setprio(1);
#pragma unroll
        for (int ii = 0; ii < 4; ++ii)
#pragma unroll
            for (int j = 0; j < 4; ++j)
                acc[4 + ii][j] = __builtin_amdgcn_mfma_f32_16x16x32_bf16(af[ii], bfx[j],
                                                                         acc[4 + ii][j], 0, 0, 0);
        __builtin_amdgcn_s_setprio(0);
        asm volatile("s_waitcnt vmcnt(4)" ::: "memory");
        __builtin_amdgcn_s_barrier();
    }
    // epilogue (C/D layout col=lane&15, row=quad*4+reg; verified m89/m91)
    if (MODE == 0) {
#pragma unroll
        for (int i = 0; i < 8; ++i) {
            const int mm = m0 + wr * 128 + i * 16 + quad * 4;  // t base; p adds 0..3
            const int b = mm >> 11, t4 = mm & (Tq - 1);
#pragma unroll
            for (int j = 0; j < 4; ++j) {
                const int n = n0 + wc * 64 + j * 16 + lane15;
                const int which = n >> 10, hh = (n >> 6) & (Hq - 1), d = n & (HSq - 1);
                const long bh = (long)b * Hq + hh;
                const float bb = bias[n];
                if (which == 0) {  // q, pre-scaled by QSCALE (softmax*log2e folded)
#pragma unroll
                    for (int p = 0; p < 4; ++p)
                        outB[bh * 131072 + (long)(t4 + p) * HSq + d] =
                            f2bf((acc[i][j][p] + bb) * QSCALE);
                } else if (which == 1) {  // k
#pragma unroll
                    for (int p = 0; p < 4; ++p)
                        outB[4194304L + bh * 131072 + (long)(t4 + p) * HSq + d] =
                            f2bf(acc[i][j][p] + bb);
                } else {  // V stored transposed [bh][d][t], 4 consecutive t packed
                    ushort4 pk;
                    pk.x = f2u(acc[i][j][0] + bb);
                    pk.y = f2u(acc[i][j][1] + bb);
                    pk.z = f2u(acc[i][j][2] + bb);
                    pk.w = f2u(acc[i][j][3] + bb);
                    *(ushort4*)(&outB[8388608L + bh * 131072 + (long)d * Tq + t4]) = pk;
                }
            }
        }
    } else {  // MODE 2: relu(acc + bias) -> bf16
#pragma unroll
        for (int i = 0; i < 8; ++i) {
#pragma unroll
            for (int p = 0; p < 4; ++p) {
                const int m = m0 + wr * 128 + i * 16 + quad * 4 + p;
#pragma unroll
                for (int j = 0; j < 4; ++j) {
                    const int n = n0 + wc * 64 + j * 16 + lane15;
                    outB[(long)m * ldout + n] = f2bf(fmaxf(acc[i][j][p] + bias[n], 0.f));
                }
            }
        }
    }
}

// ---------------- flash attention, kc-split x2, bh-major XCD locality ------------
// Verified r8: FETCH 69.7 -> 12.3 MB (K/V L2-resident). r8 regression was the
// libm exp2f slow path (+13.7us VALU); fixed: __builtin_amdgcn_exp2f = raw
// v_exp_f32, ONE transcendental per element (fewer ops than r7's __expf).
__global__ __launch_bounds__(256, 4) void k_attn(const bf16* __restrict__ qkv,
                                                 float* __restrict__ po0,
                                                 float* __restrict__ po1,
                                                 float* __restrict__ rs0,
                                                 float* __restrict__ rs1) {
    __shared__ __bf16 sK[64 * 72];
    __shared__ __bf16 sVt[64 * 72];
    const int nlin = blockIdx.x + (int)(gridDim.x * (blockIdx.y + gridDim.y * blockIdx.z));
    const int xcd = nlin & 7, s = nlin >> 3;
    const int bh = (xcd << 2) | (s >> 5);
    const int rem = s & 31;
    const int q0 = (rem & 15) * 128;
    const int z = rem >> 4;
    const int kc0 = z << 10;
    float* __restrict__ po = z ? po1 : po0;
    float* __restrict__ rsb = z ? rs1 : rs0;
    const int tid = threadIdx.x, wave = tid >> 6, lane = tid & 63;
    const int lane31 = lane & 31, laneh = lane >> 5;
    const bf16* Qp = qkv + (long)bh * 131072;
    const bf16* Kp = qkv + 4194304L + (long)bh * 131072;
    const bf16* Vtp = qkv + 8388608L + (long)bh * 131072;
    bf16x8 qa[4];
#pragma unroll
    for (int s2 = 0; s2 < 4; ++s2)
        qa[s2] = *(const bf16x8*)(&Qp[(long)(q0 + wave * 32 + lane31) * HSq + s2 * 16 + laneh * 8]);
    f32x16 o[2];
#pragma unroll
    for (int dt = 0; dt < 2; ++dt)
#pragma unroll
        for (int r = 0; r < 16; ++r) o[dt][r] = 0.f;
    float rs = 0.f;
    const int r0 = tid >> 3, c0 = (tid & 7) * 8;
    const int r1 = r0 + 32;

    uint4 nk0 = *(const uint4*)(&Kp[(long)(kc0 + r0) * HSq + c0]);
    uint4 nk1 = *(const uint4*)(&Kp[(long)(kc0 + r1) * HSq + c0]);
    uint4 nv0 = *(const uint4*)(&Vtp[(long)r0 * Tq + kc0 + c0]);
    uint4 nv1 = *(const uint4*)(&Vtp[(long)r1 * Tq + kc0 + c0]);

    for (int kc = kc0; kc < kc0 + 1024; kc += 64) {
        __syncthreads();
        *(uint4*)(&sK[r0 * 72 + c0]) = nk0;
        *(uint4*)(&sK[r1 * 72 + c0]) = nk1;
        *(uint4*)(&sVt[r0 * 72 + c0]) = nv0;
        *(uint4*)(&sVt[r1 * 72 + c0]) = nv1;
        __syncthreads();
        if (kc + 64 < kc0 + 1024) {
            nk0 = *(const uint4*)(&Kp[(long)(kc + 64 + r0) * HSq + c0]);
            nk1 = *(const uint4*)(&Kp[(long)(kc + 64 + r1) * HSq + c0]);
            nv0 = *(const uint4*)(&Vtp[(long)r0 * Tq + kc + 64 + c0]);
            nv1 = *(const uint4*)(&Vtp[(long)r1 * Tq + kc + 64 + c0]);
        }
#pragma unroll
        for (int nt = 0; nt < 2; ++nt) {
            f32x16 zz;
#pragma unroll
            for (int r = 0; r < 16; ++r) zz[r] = 0.f;
            __builtin_amdgcn_s_setprio(1);
#pragma unroll
            for (int s2 = 0; s2 < 4; ++s2) {
                bf16x8 kb =
                    *(const bf16x8*)(&sK[(nt * 32 + lane31) * 72 + s2 * 16 + laneh * 8]);
                zz = __builtin_amdgcn_mfma_f32_32x32x16_bf16(kb, qa[s2], zz, 0, 0, 0);
            }
            __builtin_amdgcn_s_setprio(0);
            float e[16];
#pragma unroll
            for (int r = 0; r < 16; ++r) {
                e[r] = __builtin_amdgcn_exp2f(zz[r]);  // raw v_exp_f32 (q pre-scaled)
                rs += e[r];
            }
            unsigned int pk[8];
#pragma unroll
            for (int g = 0; g < 4; ++g)
#pragma unroll
                for (int h = 0; h < 2; ++h)
                    pk[g * 2 + h] = (unsigned int)f2u(e[g * 4 + 2 * h]) |
                                    ((unsigned int)f2u(e[g * 4 + 2 * h + 1]) << 16);
            unsigned int sa0 = laneh ? pk[0] : pk[2], sa1 = laneh ? pk[1] : pk[3];
            unsigned int ra0 = __shfl_xor((int)sa0, 32), ra1 = __shfl_xor((int)sa1, 32);
            unsigned int sb0 = laneh ? pk[4] : pk[6], sb1 = laneh ? pk[5] : pk[7];
            unsigned int rb0 = __shfl_xor((int)sb0, 32), rb1 = __shfl_xor((int)sb1, 32);
            uint4 f0, f1;
            if (laneh == 0) {
                f0 = {pk[0], pk[1], ra0, ra1};
                f1 = {pk[4], pk[5], rb0, rb1};
            } else {
                f0 = {ra0, ra1, pk[2], pk[3]};
                f1 = {rb0, rb1, pk[6], pk[7]};
            }
            bf16x8 pa0 = __builtin_bit_cast(bf16x8, f0);
            bf16x8 pa1 = __builtin_bit_cast(bf16x8, f1);
            __builtin_amdgcn_s_setprio(1);
#pragma unroll
            for (int dt = 0; dt < 2; ++dt) {
                bf16x8 vb0 =
                    *(const bf16x8*)(&sVt[(dt * 32 + lane31) * 72 + nt * 32 + laneh * 8]);
                bf16x8 vb1 = *(const bf16x8*)(&sVt[(dt * 32 + lane31) * 72 + nt * 32 + 16 +
                                                   laneh * 8]);
                o[dt] = __builtin_amdgcn_mfma_f32_32x32x16_bf16(pa0, vb0, o[dt], 0, 0, 0);
                o[dt] = __builtin_amdgcn_mfma_f32_32x32x16_bf16(pa1, vb1, o[dt], 0, 0, 0);
            }
            __builtin_amdgcn_s_setprio(0);
        }
    }
    // partial epilogue: store unnormalized O (f32) + this half's row sums
    float ltot = rs + __shfl_xor(rs, 32);
    if (laneh == 0) rsb[(bh << 11) + q0 + wave * 32 + lane31] = ltot;
#pragma unroll
    for (int r = 0; r < 16; ++r) {
        const int tl = (r & 3) + 8 * (r >> 2) + 4 * laneh;
        const int t = q0 + wave * 32 + tl;
        float* pb = po + ((long)(bh << 11) + t) * 64;
#pragma unroll
        for (int dt = 0; dt < 2; ++dt) pb[dt * 32 + lane31] = o[dt][r];
    }
}

// combine: out[b][t][h*64+d] = bf16((po0+po1) / (rs0+rs1)) — 4 floats/thread
__global__ __launch_bounds__(256) void k_attn_combine(
    const float* __restrict__ po0, const float* __restrict__ po1,
    const float* __restrict__ rs0, const float* __restrict__ rs1,
    bf16* __restrict__ out) {
    const long i = ((long)blockIdx.x * 256 + threadIdx.x) * 4;
    const int d = (int)(i & 63);
    const long qq = i >> 6;  // bh*2048 + t
    const int bh = (int)(qq >> 11), t = (int)(qq & 2047);
    const float inv = 1.0f / (rs0[qq] + rs1[qq]);
    const f32x4 a = *(const f32x4*)(po0 + i);
    const f32x4 b = *(const f32x4*)(po1 + i);
    const int bb = bh >> 4, hh = bh & 15;
    ushort4 pk;
    pk.x = f2u((a[0] + b[0]) * inv);
    pk.y = f2u((a[1] + b[1]) * inv);
    pk.z = f2u((a[2] + b[2]) * inv);
    pk.w = f2u((a[3] + b[3]) * inv);
    *(ushort4*)(&out[(((long)bb * Tq + t) << 10) + hh * 64 + d]) = pk;
}

extern "C" void kernel_launch(void* const* d_in, const int* in_sizes, int n_in,
                              void* d_out, int out_size, void* d_ws, size_t ws_size,
                              hipStream_t stream) {
    const float* x = (const float*)d_in[0];
    const float* Wq = (const float*)d_in[1];
    const float* bqv = (const float*)d_in[2];
    const float* Wk = (const float*)d_in[3];
    const float* bkv = (const float*)d_in[4];
    const float* Wv = (const float*)d_in[5];
    const float* bvv = (const float*)d_in[6];
    const float* Wo = (const float*)d_in[7];
    const float* bo = (const float*)d_in[8];
    const float* W1 = (const float*)d_in[9];
    const float* b1 = (const float*)d_in[10];
    const float* W2 = (const float*)d_in[11];
    const float* b2 = (const float*)d_in[12];
    const float* g1 = (const float*)d_in[13];
    const float* be1 = (const float*)d_in[14];
    const float* g2 = (const float*)d_in[15];
    const float* be2 = (const float*)d_in[16];

    // ---- workspace: ~56.7 MiB total (safe under 64 MiB) ----
    char* ws = (char*)d_ws;
    size_t off = 0;
    auto alloc = [&](size_t bytes) {
        void* p = ws + off;
        off += (bytes + 255) & ~(size_t)255;
        return p;
    };
    bf16* regA = (bf16*)alloc(32L * 1024 * 1024);  // qkv (24 MiB)+attn_out tail, then a1 (32 MiB)
    float* x2 = (float*)alloc(4096L * 1024 * 4);   // 16 MiB: attn po0 scratch, then f32 residual
    bf16* buf1 = (bf16*)alloc(4096L * 1024 * 2);   // 8 MiB: WqkvT -> WoT -> W1T -> W2T
    float* bqkv = (float*)alloc(3072L * 4);
    float* ps = (float*)alloc(32L * Bq * Cq * 4);  // LN partials; attn rs0 scratch
    float* pss = (float*)alloc(32L * Bq * Cq * 4); // LN partials; attn rs1 scratch
    float* mean1 = (float*)alloc(Bq * Cq * 4);
    float* rstd1 = (float*)alloc(Bq * Cq * 4);
    float* mean2 = (float*)alloc(Bq * Cq * 4);
    float* rstd2 = (float*)alloc(Bq * Cq * 4);
    bf16* dres = (bf16*)d_out;          // d_out first 8 MiB bf16 scratch: h -> h2
    float* outF = (float*)d_out;
    float* po1 = (float*)d_out;         // full 16 MiB of d_out as attn po1 (h dead then)
    bf16* attn_out = regA + 12582912;   // 8 MiB free tail of regA (qkv uses 24 of 32 MiB)

    // LN1 -> h (bf16, in d_out)
    k_ln_part<<<dim3(4, Bq, 32), 256, 0, stream>>>(x, ps, pss);
    k_ln_fin<<<dim3(8), 256, 0, stream>>>(ps, pss, mean1, rstd1);
    k_ln_apply<<<dim3(16384), 256, 0, stream>>>(x, mean1, rstd1, g1, be1, dres);

    // Wq/Wk/Wv per-head transpose + bias pack (single launch)
    k_transpose3<<<dim3(2, 32, 48), 256, 0, stream>>>(Wq, Wk, Wv, bqv, bkv, bvv, buf1, bqkv);
    // QKV projection -> q(scaled),k,vt in regA  (8-phase 256^2 pipeline, 192 blocks)
    k_gemm_8ph<0><<<dim3(12, 16), 512, 0, stream>>>(dres, 1024, buf1, 1024, 1024, bqkv, regA, 0);
    // attention kc-split x2 -> partials (po0=x2, po1=d_out, rs in ps/pss)
    k_attn<<<dim3(16, 32, 2), 256, 0, stream>>>(regA, x2, po1, ps, pss);
    k_attn_combine<<<dim3(4096), 256, 0, stream>>>(x2, po1, ps, pss, attn_out);
    // Wo^T -> buf1; x2 = attn@Wo + bo + x   (pipelined 128x64, 512 blocks, 2/CU)
    k_transpose<<<dim3(32, 32, 1), 256, 0, stream>>>(Wo, buf1, 1024, 1024, 0, 0);
    k_gemm_n64p<1><<<dim3(16, 32), 256, 0, stream>>>(attn_out, 1024, buf1, 1024, 1024, bo, x,
                                                     x2, 1024);
    // LN2 -> h2 (bf16, in d_out; po1 dead)
    k_ln_part<<<dim3(4, Bq, 32), 256, 0, stream>>>(x2, ps, pss);
    k_ln_fin<<<dim3(8), 256, 0, stream>>>(ps, pss, mean2, rstd2);
    k_ln_apply<<<dim3(16384), 256, 0, stream>>>(x2, mean2, rstd2, g2, be2, dres);

    // ---- FF ----
    k_transpose<<<dim3(128, 32, 1), 256, 0, stream>>>(W1, buf1, 1024, 4096, 0, 0);  // W1T
    // a1 = relu(h2 @ W1T + b1) -> regA [4096][4096] bf16  (8-phase 256^2 pipeline)
    k_gemm_8ph<2><<<dim3(16, 16), 512, 0, stream>>>(dres, 1024, buf1, 1024, 1024, b1, regA,
                                                    4096);
    k_transpose<<<dim3(32, 128, 1), 256, 0, stream>>>(W2, buf1, 4096, 1024, 0, 0);  // W2T
    // d_out(f32) = a1 @ W2T + b2 + x2   (pipelined 128x64, 512 blocks, 2/CU)
    k_gemm_n64p<3><<<dim3(16, 32), 256, 0, stream>>>(regA, 4096, buf1, 4096, 4096, b2, x2,
                                                     outF, 1024);
}

// Round 10
// 379.204 us; speedup vs baseline: 1.0258x; 1.0091x over previous
//
#include <hip/hip_runtime.h>
#include <hip/hip_bf16.h>

#define Bq 2
#define Tq 2048
#define Cq 1024
#define Hq 16
#define HSq 64
#define EPSq 1e-5f

using bf16 = __hip_bfloat16;
using f32x4 = __attribute__((ext_vector_type(4))) float;
using f32x16 = __attribute__((ext_vector_type(16))) float;
using bf16x8 = __attribute__((ext_vector_type(8))) __bf16;

__device__ __forceinline__ bf16 f2bf(float f) { return __float2bfloat16(f); }
__device__ __forceinline__ unsigned short f2u(float f) {
    return __builtin_bit_cast(unsigned short, __float2bfloat16(f));
}
// async global->LDS, 16B per lane; LDS dest = wave-uniform base + lane*16
__device__ __forceinline__ void gload16(const void* g, void* l) {
    __builtin_amdgcn_global_load_lds((const __attribute__((address_space(1))) void*)g,
                                     (__attribute__((address_space(3))) void*)l, 16, 0, 0);
}

// q pre-scale: softmax 1/sqrt(64) * log2(e); attn uses raw v_exp_f32 (exp2).
#define QSCALE 0.180336884f

// ------------- transpose f32 src -> bf16 dst (dims multiples of 32) -------------
__global__ void k_transpose(const float* __restrict__ src, bf16* __restrict__ dst,
                            int R, int Cc, long strideSrc, long strideDst) {
    __shared__ bf16 tile[32][33];
    const long zb = blockIdx.z;
    src += zb * strideSrc;
    dst += zb * strideDst;
    int c0 = blockIdx.x * 32, r0 = blockIdx.y * 32;
    int tx = threadIdx.x & 31, ty = threadIdx.x >> 5;
    for (int i = ty; i < 32; i += 8)
        tile[i][tx] = f2bf(src[(long)(r0 + i) * Cc + (c0 + tx)]);
    __syncthreads();
    for (int i = ty; i < 32; i += 8)
        dst[(long)(c0 + i) * R + (r0 + tx)] = tile[tx][i];
}

// ---- fused: per-head transpose of Wq/Wk/Wv ([16][1024][64] -> [3072][1024] bf16)
//      + qkv bias pack piggyback ----------
__global__ void k_transpose3(const float* __restrict__ Wq, const float* __restrict__ Wk,
                             const float* __restrict__ Wv, const float* __restrict__ bqv,
                             const float* __restrict__ bkv, const float* __restrict__ bvv,
                             bf16* __restrict__ dst, float* __restrict__ bdst) {
    __shared__ bf16 tile[32][33];
    const int zb = blockIdx.z;  // 0..47
    const int which = zb >> 4, head = zb & 15;
    const float* src = (which == 0 ? Wq : which == 1 ? Wk : Wv) + (long)head * 65536;
    bf16* d = dst + (long)which * 1048576 + (long)head * 65536;
    int c0 = blockIdx.x * 32, r0 = blockIdx.y * 32;
    int tx = threadIdx.x & 31, ty = threadIdx.x >> 5;
    for (int i = ty; i < 32; i += 8)
        tile[i][tx] = f2bf(src[(long)(r0 + i) * 64 + (c0 + tx)]);
    if (blockIdx.x == 0 && blockIdx.y == 0 && zb < 12) {
        int i = zb * 256 + threadIdx.x;  // 0..3071
        bdst[i] = i < 1024 ? bqv[i] : i < 2048 ? bkv[i - 1024] : bvv[i - 2048];
    }
    __syncthreads();
    for (int i = ty; i < 32; i += 8)
        d[(long)(c0 + i) * 1024 + (r0 + tx)] = tile[tx][i];
}

// ---------------- LayerNorm over the SEQUENCE axis (per (b,c)), f32 in ----------
__global__ void k_ln_part(const float* __restrict__ x, float* __restrict__ ps,
                          float* __restrict__ pss) {
    int c = blockIdx.x * 256 + threadIdx.x;
    int b = blockIdx.y;
    int tc = blockIdx.z;  // 32 chunks of 64 timesteps
    const float* p = x + (long)b * Tq * Cq + (long)tc * 64 * Cq + c;
    float s = 0.f, ss = 0.f;
    for (int t = 0; t < 64; ++t) {
        float v = p[(long)t * Cq];
        s += v;
        ss += v * v;
    }
    long o = ((long)tc * Bq + b) * Cq + c;
    ps[o] = s;
    pss[o] = ss;
}

__global__ void k_ln_fin(const float* __restrict__ ps, const float* __restrict__ pss,
                         float* __restrict__ mean, float* __restrict__ rstd) {
    int i = blockIdx.x * 256 + threadIdx.x;  // b*Cq + c
    float s = 0.f, ss = 0.f;
    for (int tc = 0; tc < 32; ++tc) {
        s += ps[(long)tc * (Bq * Cq) + i];
        ss += pss[(long)tc * (Bq * Cq) + i];
    }
    float m = s / (float)Tq;
    float var = (ss - s * m) / (float)(Tq - 1);  // ddof=1 (unbiased)
    var = fmaxf(var, 0.f);
    mean[i] = m;
    rstd[i] = 1.0f / (sqrtf(var) + EPSq);  // eps OUTSIDE sqrt
}

__global__ void k_ln_apply(const float* __restrict__ x, const float* __restrict__ mean,
                           const float* __restrict__ rstd, const float* __restrict__ gamma,
                           const float* __restrict__ beta, bf16* __restrict__ out) {
    long i = (long)blockIdx.x * 256 + threadIdx.x;
    int c = (int)(i & (Cq - 1));
    long bt = i >> 10;
    int b = (int)(bt >> 11);
    float m = mean[b * Cq + c], r = rstd[b * Cq + c];
    out[i] = f2bf(gamma[c] * ((x[i] - m) * r) + beta[c]);
}

// XCD-aware bijective chunked swizzle (nwg % 8 == 0 for all our grids)
__device__ __forceinline__ void xcd_swizzle(int& bx, int& by) {
    const int gx = gridDim.x;
    const int nwg = gx * gridDim.y;
    const int bid = blockIdx.y * gx + blockIdx.x;
    const int swz = (bid & 7) * (nwg >> 3) + (bid >> 3);
    bx = swz % gx;
    by = swz / gx;
}

// ==== bf16 NT-GEMM 128x128, 64x64 wave-tiles, depth-3 counted pipeline ==========
// Successor to k_gemm_n64p (51.5us, MfmaUtil 26%): r9 PMC showed it LDS-bound
// (96 ds_read_b128/CU-step = 1152 of 1931 cyc; 32x64 wave-tiles re-read the B
// panel 4x). Square 64x64 wave-tiles cut LDS fragment traffic 1.5x (64 reads
// per 128x128-step). BK=32 keeps buffers small: 4 x 16 KiB = 64 KiB -> still
// 2 blocks/CU (TLP preserved). Depth-3 prefetch (stage t+3), counted vmcnt:
//   prologue stage(0,1,2) -> 12 outstanding (4 loads/tile/wave)
//   iter t<NT-2: vmcnt(8) retires tile t; barrier; stage(t+3); comp(t)
//   tail: vmcnt(4) -> comp(NT-2); vmcnt(0) -> comp(NT-1)   [never 0 in loop]
// Overwrite hazard: stage(t+3) targets buf(t-1); its last reader comp(t-1)
// finished (lgkmcnt-retired) before the barrier every wave passed.
// MODE 1/3: outF = acc + bias + residF (f32).
template <int MODE>
__global__ __launch_bounds__(256, 2) void k_gemm_p128(
    const bf16* __restrict__ A, int lda, const bf16* __restrict__ Bt, int ldb, int K,
    const float* __restrict__ bias, const float* __restrict__ residF,
    float* __restrict__ outF, int ldout) {
    __shared__ __bf16 lds[4 * 8192];  // 4 buffers x 16 KiB
    int bx, by;
    xcd_swizzle(bx, by);
    const int m0 = by * 128, n0 = bx * 128;
    const int tid = threadIdx.x;
    const int lane = tid & 63, wave = tid >> 6;
    const int lane15 = lane & 15, quad = lane >> 4;
    const int wm = (wave >> 1) * 64, wn = (wave & 1) * 64;  // 2x2 waves of 64x64
    const int srow = wave * 16 + (lane >> 2);
    const int scol = (((lane & 3) ^ ((lane >> 3) & 3)) * 8);  // pre-swizzled source
    const int sq8 = (quad ^ ((lane15 >> 1) & 3)) * 8;         // swizzled read slot
    const bf16* Ap = A + (long)(m0 + srow) * lda + scol;
    const bf16* Ap2 = Ap + 64L * lda;
    const bf16* Bp = Bt + (long)(n0 + srow) * ldb + scol;
    const bf16* Bp2 = Bp + 64L * ldb;
    const int NT = K >> 5;  // BK=32

    f32x4 acc[4][4];
#pragma unroll
    for (int i = 0; i < 4; ++i)
#pragma unroll
        for (int j = 0; j < 4; ++j)
#pragma unroll
            for (int p = 0; p < 4; ++p) acc[i][j][p] = 0.f;

    // buffer layout (elems): A rows0-63 [0,2048) rows64-127 [2048,4096),
    //                        B rows0-63 [4096,6144) rows64-127 [6144,8192)
    auto stage = [&](int t, int bufi) {
        const long ko = (long)t << 5;
        __bf16* b = &lds[bufi * 8192 + wave * 512];
        gload16(Ap + ko, b);
        gload16(Ap2 + ko, b + 2048);
        gload16(Bp + ko, b + 4096);
        gload16(Bp2 + ko, b + 6144);
    };
    auto comp = [&](int bufi) {
        const __bf16* base = &lds[bufi * 8192];
        bf16x8 af[4], bfr[4];
#pragma unroll
        for (int i = 0; i < 4; ++i)
            af[i] = *(const bf16x8*)(base + (wm + i * 16 + lane15) * 32 + sq8);
#pragma unroll
        for (int j = 0; j < 4; ++j)
            bfr[j] = *(const bf16x8*)(base + 4096 + (wn + j * 16 + lane15) * 32 + sq8);
#pragma unroll
        for (int i = 0; i < 4; ++i)
#pragma unroll
            for (int j = 0; j < 4; ++j)
                acc[i][j] =
                    __builtin_amdgcn_mfma_f32_16x16x32_bf16(af[i], bfr[j], acc[i][j], 0, 0, 0);
    };

    stage(0, 0);
    stage(1, 1);
    stage(2, 2);
    for (int t = 0; t < NT - 2; ++t) {
        asm volatile("s_waitcnt vmcnt(8)" ::: "memory");  // tile t's 4 loads landed
        __builtin_amdgcn_s_barrier();
        if (t + 3 < NT) stage(t + 3, (t + 3) & 3);
        comp(t & 3);
    }
    asm volatile("s_waitcnt vmcnt(4)" ::: "memory");  // tile NT-2 landed
    __builtin_amdgcn_s_barrier();
    comp((NT - 2) & 3);
    asm volatile("s_waitcnt vmcnt(0)" ::: "memory");  // tile NT-1 landed
    __builtin_amdgcn_s_barrier();
    comp((NT - 1) & 3);

#pragma unroll
    for (int i = 0; i < 4; ++i) {
#pragma unroll
        for (int p = 0; p < 4; ++p) {
            const int m = m0 + wm + i * 16 + quad * 4 + p;
#pragma unroll
            for (int j = 0; j < 4; ++j) {
                const int n = n0 + wn + j * 16 + lane15;
                outF[(long)m * ldout + n] =
                    acc[i][j][p] + bias[n] + residF[(long)m * ldout + n];
            }
        }
    }
}

// ======== 256x256 8-phase pipelined NT-GEMM (m201 template, plain HIP) ==========
// Verified r5/r7/r8/r9. T3+T4+T5; counted vmcnt(4) per K-tile.
// MODE 0: +bias, scatter qkv (q scaled by QSCALE, k plain, V^T packed).
// MODE 2: relu(+bias) -> bf16.
template <int MODE>
__global__ __launch_bounds__(512, 2) void k_gemm_8ph(
    const bf16* __restrict__ A, int lda, const bf16* __restrict__ Bt, int ldb, int K,
    const float* __restrict__ bias, bf16* __restrict__ outB, int ldout) {
    __shared__ __bf16 sA[2][2][256 * 32];
    __shared__ __bf16 sB[2][2][256 * 32];
    int bx, by;
    xcd_swizzle(bx, by);
    const int m0 = by * 256, n0 = bx * 256;
    const int tid = threadIdx.x;
    const int lane = tid & 63, wave = tid >> 6;
    const int lane15 = lane & 15, quad = lane >> 4;
    const int wr = wave >> 2, wc = wave & 3;  // wave tile: rows wr*128, cols wc*64
    const int sq8 = (quad ^ ((lane15 >> 1) & 3)) * 8;  // swizzled read slot
    const int arow = wr * 128 + lane15;
    const int brow = wc * 64 + lane15;
    const int sr = wave * 16 + (lane >> 2);                  // stage row
    const int sc = ((lane & 3) ^ ((lane >> 3) & 3)) * 8;     // pre-swizzled src slot
    const bf16* ApS = A + (long)(m0 + sr) * lda + sc;
    const bf16* BpS = Bt + (long)(n0 + sr) * ldb + sc;
    const int NT = K >> 6;       // K-tiles
    const int NP = NT << 2;      // planes (4 per tile)

    auto stage_plane = [&](int q) {
        if (q >= NP) return;
        const int t = q >> 2, slot = q & 3;
        const int db = t & 1, kk = slot >> 1;
        const long ko = ((long)t << 6) + kk * 32;
        if (!(slot & 1)) {
            gload16(ApS + ko, &sA[db][kk][wave * 512]);
            gload16(ApS + ko + 128L * lda, &sA[db][kk][4096 + wave * 512]);
        } else {
            gload16(BpS + ko, &sB[db][kk][wave * 512]);
            gload16(BpS + ko + 128L * ldb, &sB[db][kk][4096 + wave * 512]);
        }
    };

    f32x4 acc[8][4];
#pragma unroll
    for (int i = 0; i < 8; ++i)
#pragma unroll
        for (int j = 0; j < 4; ++j)
#pragma unroll
            for (int p = 0; p < 4; ++p) acc[i][j][p] = 0.f;

    stage_plane(0);
    stage_plane(1);
    stage_plane(2);
    stage_plane(3);
    stage_plane(4);
    stage_plane(5);
    asm volatile("s_waitcnt vmcnt(4)" ::: "memory");
    __builtin_amdgcn_s_barrier();

    for (int t = 0; t < NT; ++t) {
        const int db = t & 1;
        const __bf16* A0 = sA[db][0];
        const __bf16* A1 = sA[db][1];
        const __bf16* B0 = sB[db][0];
        const __bf16* B1 = sB[db][1];
        bf16x8 af[4], bfx[4];
        // ---- phase 0: kk0, m-half 0 ----
#pragma unroll
        for (int j = 0; j < 4; ++j)
            bfx[j] = *(const bf16x8*)(&B0[(brow + j * 16) * 32 + sq8]);
#pragma unroll
        for (int ii = 0; ii < 4; ++ii)
            af[ii] = *(const bf16x8*)(&A0[(arow + ii * 16) * 32 + sq8]);
        stage_plane(4 * t + 6);
        __builtin_amdgcn_s_barrier();
        __builtin_amdgcn_s_setprio(1);
#pragma unroll
        for (int ii = 0; ii < 4; ++ii)
#pragma unroll
            for (int j = 0; j < 4; ++j)
                acc[ii][j] =
                    __builtin_amdgcn_mfma_f32_16x16x32_bf16(af[ii], bfx[j], acc[ii][j], 0, 0, 0);
        __builtin_amdgcn_s_setprio(0);
        __builtin_amdgcn_s_barrier();
        // ---- phase 1: kk0, m-half 1 ----
#pragma unroll
        for (int ii = 0; ii < 4; ++ii)
            af[ii] = *(const bf16x8*)(&A0[(arow + 64 + ii * 16) * 32 + sq8]);
        stage_plane(4 * t + 7);
        __builtin_amdgcn_s_barrier();
        __builtin_amdgcn_s_setprio(1);
#pragma unroll
        for (int ii = 0; ii < 4; ++ii)
#pragma unroll
            for (int j = 0; j < 4; ++j)
                acc[4 + ii][j] = __builtin_amdgcn_mfma_f32_16x16x32_bf16(af[ii], bfx[j],
                                                                         acc[4 + ii][j], 0, 0, 0);
        __builtin_amdgcn_s_setprio(0);
        __builtin_amdgcn_s_barrier();
        // ---- phase 2: kk1, m-half 0 ----
#pragma unroll
        for (int j = 0; j < 4; ++j)
            bfx[j] = *(const bf16x8*)(&B1[(brow + j * 16) * 32 + sq8]);
#pragma unroll
        for (int ii = 0; ii < 4; ++ii)
            af[ii] = *(const bf16x8*)(&A1[(arow + ii * 16) * 32 + sq8]);
        stage_plane(4 * t + 8);
        __builtin_amdgcn_s_barrier();
        __builtin_amdgcn_s_setprio(1);
#pragma unroll
        for (int ii = 0; ii < 4; ++ii)
#pragma unroll
            for (int j = 0; j < 4; ++j)
                acc[ii][j] =
                    __builtin_amdgcn_mfma_f32_16x16x32_bf16(af[ii], bfx[j], acc[ii][j], 0, 0, 0);
        __builtin_amdgcn_s_setprio(0);
        __builtin_amdgcn_s_barrier();
        // ---- phase 3: kk1, m-half 1 ----
#pragma unroll
        for (int ii = 0; ii < 4; ++ii)
            af[ii] = *(const bf16x8*)(&A1[(arow + 64 + ii * 16) * 32 + sq8]);
        stage_plane(4 * t + 9);
        __builtin_amdgcn_s_barrier();
        __builtin_amdgcn_s_setprio(1);
#pragma unroll
        for (int ii = 0; ii < 4; ++ii)
#pragma unroll
            for (int j = 0; j < 4; ++j)
                acc[4 + ii][j] = __builtin_amdgcn_mfma_f32_16x16x32_bf16(af[ii], bfx[j],
                                                                         acc[4 + ii][j], 0, 0, 0);
        __builtin_amdgcn_s_setprio(0);
        asm volatile("s_waitcnt vmcnt(4)" ::: "memory");
        __builtin_amdgcn_s_barrier();
    }
    // epilogue (C/D layout col=lane&15, row=quad*4+reg; verified m89/m91)
    if (MODE == 0) {
#pragma unroll
        for (int i = 0; i < 8; ++i) {
            const int mm = m0 + wr * 128 + i * 16 + quad * 4;  // t base; p adds 0..3
            const int b = mm >> 11, t4 = mm & (Tq - 1);
#pragma unroll
            for (int j = 0; j < 4; ++j) {
                const int n = n0 + wc * 64 + j * 16 + lane15;
                const int which = n >> 10, hh = (n >> 6) & (Hq - 1), d = n & (HSq - 1);
                const long bh = (long)b * Hq + hh;
                const float bb = bias[n];
                if (which == 0) {  // q, pre-scaled by QSCALE (softmax*log2e folded)
#pragma unroll
                    for (int p = 0; p < 4; ++p)
                        outB[bh * 131072 + (long)(t4 + p) * HSq + d] =
                            f2bf((acc[i][j][p] + bb) * QSCALE);
                } else if (which == 1) {  // k
#pragma unroll
                    for (int p = 0; p < 4; ++p)
                        outB[4194304L + bh * 131072 + (long)(t4 + p) * HSq + d] =
                            f2bf(acc[i][j][p] + bb);
                } else {  // V stored transposed [bh][d][t], 4 consecutive t packed
                    ushort4 pk;
                    pk.x = f2u(acc[i][j][0] + bb);
                    pk.y = f2u(acc[i][j][1] + bb);
                    pk.z = f2u(acc[i][j][2] + bb);
                    pk.w = f2u(acc[i][j][3] + bb);
                    *(ushort4*)(&outB[8388608L + bh * 131072 + (long)d * Tq + t4]) = pk;
                }
            }
        }
    } else {  // MODE 2: relu(acc + bias) -> bf16
#pragma unroll
        for (int i = 0; i < 8; ++i) {
#pragma unroll
            for (int p = 0; p < 4; ++p) {
                const int m = m0 + wr * 128 + i * 16 + quad * 4 + p;
#pragma unroll
                for (int j = 0; j < 4; ++j) {
                    const int n = n0 + wc * 64 + j * 16 + lane15;
                    outB[(long)m * ldout + n] = f2bf(fmaxf(acc[i][j][p] + bias[n], 0.f));
                }
            }
        }
    }
}

// ---------------- flash attention, kc-split x2, bh-major XCD locality ------------
// Verified r8/r9: FETCH 69.7 -> 12.3 MB (K/V L2-resident); raw v_exp_f32.
__global__ __launch_bounds__(256, 4) void k_attn(const bf16* __restrict__ qkv,
                                                 float* __restrict__ po0,
                                                 float* __restrict__ po1,
                                                 float* __restrict__ rs0,
                                                 float* __restrict__ rs1) {
    __shared__ __bf16 sK[64 * 72];
    __shared__ __bf16 sVt[64 * 72];
    const int nlin = blockIdx.x + (int)(gridDim.x * (blockIdx.y + gridDim.y * blockIdx.z));
    const int xcd = nlin & 7, s = nlin >> 3;
    const int bh = (xcd << 2) | (s >> 5);
    const int rem = s & 31;
    const int q0 = (rem & 15) * 128;
    const int z = rem >> 4;
    const int kc0 = z << 10;
    float* __restrict__ po = z ? po1 : po0;
    float* __restrict__ rsb = z ? rs1 : rs0;
    const int tid = threadIdx.x, wave = tid >> 6, lane = tid & 63;
    const int lane31 = lane & 31, laneh = lane >> 5;
    const bf16* Qp = qkv + (long)bh * 131072;
    const bf16* Kp = qkv + 4194304L + (long)bh * 131072;
    const bf16* Vtp = qkv + 8388608L + (long)bh * 131072;
    bf16x8 qa[4];
#pragma unroll
    for (int s2 = 0; s2 < 4; ++s2)
        qa[s2] = *(const bf16x8*)(&Qp[(long)(q0 + wave * 32 + lane31) * HSq + s2 * 16 + laneh * 8]);
    f32x16 o[2];
#pragma unroll
    for (int dt = 0; dt < 2; ++dt)
#pragma unroll
        for (int r = 0; r < 16; ++r) o[dt][r] = 0.f;
    float rs = 0.f;
    const int r0 = tid >> 3, c0 = (tid & 7) * 8;
    const int r1 = r0 + 32;

    uint4 nk0 = *(const uint4*)(&Kp[(long)(kc0 + r0) * HSq + c0]);
    uint4 nk1 = *(const uint4*)(&Kp[(long)(kc0 + r1) * HSq + c0]);
    uint4 nv0 = *(const uint4*)(&Vtp[(long)r0 * Tq + kc0 + c0]);
    uint4 nv1 = *(const uint4*)(&Vtp[(long)r1 * Tq + kc0 + c0]);

    for (int kc = kc0; kc < kc0 + 1024; kc += 64) {
        __syncthreads();
        *(uint4*)(&sK[r0 * 72 + c0]) = nk0;
        *(uint4*)(&sK[r1 * 72 + c0]) = nk1;
        *(uint4*)(&sVt[r0 * 72 + c0]) = nv0;
        *(uint4*)(&sVt[r1 * 72 + c0]) = nv1;
        __syncthreads();
        if (kc + 64 < kc0 + 1024) {
            nk0 = *(const uint4*)(&Kp[(long)(kc + 64 + r0) * HSq + c0]);
            nk1 = *(const uint4*)(&Kp[(long)(kc + 64 + r1) * HSq + c0]);
            nv0 = *(const uint4*)(&Vtp[(long)r0 * Tq + kc + 64 + c0]);
            nv1 = *(const uint4*)(&Vtp[(long)r1 * Tq + kc + 64 + c0]);
        }
#pragma unroll
        for (int nt = 0; nt < 2; ++nt) {
            f32x16 zz;
#pragma unroll
            for (int r = 0; r < 16; ++r) zz[r] = 0.f;
            __builtin_amdgcn_s_setprio(1);
#pragma unroll
            for (int s2 = 0; s2 < 4; ++s2) {
                bf16x8 kb =
                    *(const bf16x8*)(&sK[(nt * 32 + lane31) * 72 + s2 * 16 + laneh * 8]);
                zz = __builtin_amdgcn_mfma_f32_32x32x16_bf16(kb, qa[s2], zz, 0, 0, 0);
            }
            __builtin_amdgcn_s_setprio(0);
            float e[16];
#pragma unroll
            for (int r = 0; r < 16; ++r) {
                e[r] = __builtin_amdgcn_exp2f(zz[r]);  // raw v_exp_f32 (q pre-scaled)
                rs += e[r];
            }
            unsigned int pk[8];
#pragma unroll
            for (int g = 0; g < 4; ++g)
#pragma unroll
                for (int h = 0; h < 2; ++h)
                    pk[g * 2 + h] = (unsigned int)f2u(e[g * 4 + 2 * h]) |
                                    ((unsigned int)f2u(e[g * 4 + 2 * h + 1]) << 16);
            unsigned int sa0 = laneh ? pk[0] : pk[2], sa1 = laneh ? pk[1] : pk[3];
            unsigned int ra0 = __shfl_xor((int)sa0, 32), ra1 = __shfl_xor((int)sa1, 32);
            unsigned int sb0 = laneh ? pk[4] : pk[6], sb1 = laneh ? pk[5] : pk[7];
            unsigned int rb0 = __shfl_xor((int)sb0, 32), rb1 = __shfl_xor((int)sb1, 32);
            uint4 f0, f1;
            if (laneh == 0) {
                f0 = {pk[0], pk[1], ra0, ra1};
                f1 = {pk[4], pk[5], rb0, rb1};
            } else {
                f0 = {ra0, ra1, pk[2], pk[3]};
                f1 = {rb0, rb1, pk[6], pk[7]};
            }
            bf16x8 pa0 = __builtin_bit_cast(bf16x8, f0);
            bf16x8 pa1 = __builtin_bit_cast(bf16x8, f1);
            __builtin_amdgcn_s_setprio(1);
#pragma unroll
            for (int dt = 0; dt < 2; ++dt) {
                bf16x8 vb0 =
                    *(const bf16x8*)(&sVt[(dt * 32 + lane31) * 72 + nt * 32 + laneh * 8]);
                bf16x8 vb1 = *(const bf16x8*)(&sVt[(dt * 32 + lane31) * 72 + nt * 32 + 16 +
                                                   laneh * 8]);
                o[dt] = __builtin_amdgcn_mfma_f32_32x32x16_bf16(pa0, vb0, o[dt], 0, 0, 0);
                o[dt] = __builtin_amdgcn_mfma_f32_32x32x16_bf16(pa1, vb1, o[dt], 0, 0, 0);
            }
            __builtin_amdgcn_s_setprio(0);
        }
    }
    // partial epilogue: store unnormalized O (f32) + this half's row sums
    float ltot = rs + __shfl_xor(rs, 32);
    if (laneh == 0) rsb[(bh << 11) + q0 + wave * 32 + lane31] = ltot;
#pragma unroll
    for (int r = 0; r < 16; ++r) {
        const int tl = (r & 3) + 8 * (r >> 2) + 4 * laneh;
        const int t = q0 + wave * 32 + tl;
        float* pb = po + ((long)(bh << 11) + t) * 64;
#pragma unroll
        for (int dt = 0; dt < 2; ++dt) pb[dt * 32 + lane31] = o[dt][r];
    }
}

// combine: out[b][t][h*64+d] = bf16((po0+po1) / (rs0+rs1)) — 4 floats/thread
__global__ __launch_bounds__(256) void k_attn_combine(
    const float* __restrict__ po0, const float* __restrict__ po1,
    const float* __restrict__ rs0, const float* __restrict__ rs1,
    bf16* __restrict__ out) {
    const long i = ((long)blockIdx.x * 256 + threadIdx.x) * 4;
    const int d = (int)(i & 63);
    const long qq = i >> 6;  // bh*2048 + t
    const int bh = (int)(qq >> 11), t = (int)(qq & 2047);
    const float inv = 1.0f / (rs0[qq] + rs1[qq]);
    const f32x4 a = *(const f32x4*)(po0 + i);
    const f32x4 b = *(const f32x4*)(po1 + i);
    const int bb = bh >> 4, hh = bh & 15;
    ushort4 pk;
    pk.x = f2u((a[0] + b[0]) * inv);
    pk.y = f2u((a[1] + b[1]) * inv);
    pk.z = f2u((a[2] + b[2]) * inv);
    pk.w = f2u((a[3] + b[3]) * inv);
    *(ushort4*)(&out[(((long)bb * Tq + t) << 10) + hh * 64 + d]) = pk;
}

extern "C" void kernel_launch(void* const* d_in, const int* in_sizes, int n_in,
                              void* d_out, int out_size, void* d_ws, size_t ws_size,
                              hipStream_t stream) {
    const float* x = (const float*)d_in[0];
    const float* Wq = (const float*)d_in[1];
    const float* bqv = (const float*)d_in[2];
    const float* Wk = (const float*)d_in[3];
    const float* bkv = (const float*)d_in[4];
    const float* Wv = (const float*)d_in[5];
    const float* bvv = (const float*)d_in[6];
    const float* Wo = (const float*)d_in[7];
    const float* bo = (const float*)d_in[8];
    const float* W1 = (const float*)d_in[9];
    const float* b1 = (const float*)d_in[10];
    const float* W2 = (const float*)d_in[11];
    const float* b2 = (const float*)d_in[12];
    const float* g1 = (const float*)d_in[13];
    const float* be1 = (const float*)d_in[14];
    const float* g2 = (const float*)d_in[15];
    const float* be2 = (const float*)d_in[16];

    // ---- workspace: ~56.7 MiB total (safe under 64 MiB) ----
    char* ws = (char*)d_ws;
    size_t off = 0;
    auto alloc = [&](size_t bytes) {
        void* p = ws + off;
        off += (bytes + 255) & ~(size_t)255;
        return p;
    };
    bf16* regA = (bf16*)alloc(32L * 1024 * 1024);  // qkv (24 MiB)+attn_out tail, then a1 (32 MiB)
    float* x2 = (float*)alloc(4096L * 1024 * 4);   // 16 MiB: attn po0 scratch, then f32 residual
    bf16* buf1 = (bf16*)alloc(4096L * 1024 * 2);   // 8 MiB: WqkvT -> WoT -> W1T -> W2T
    float* bqkv = (float*)alloc(3072L * 4);
    float* ps = (float*)alloc(32L * Bq * Cq * 4);  // LN partials; attn rs0 scratch
    float* pss = (float*)alloc(32L * Bq * Cq * 4); // LN partials; attn rs1 scratch
    float* mean1 = (float*)alloc(Bq * Cq * 4);
    float* rstd1 = (float*)alloc(Bq * Cq * 4);
    float* mean2 = (float*)alloc(Bq * Cq * 4);
    float* rstd2 = (float*)alloc(Bq * Cq * 4);
    bf16* dres = (bf16*)d_out;          // d_out first 8 MiB bf16 scratch: h -> h2
    float* outF = (float*)d_out;
    float* po1 = (float*)d_out;         // full 16 MiB of d_out as attn po1 (h dead then)
    bf16* attn_out = regA + 12582912;   // 8 MiB free tail of regA (qkv uses 24 of 32 MiB)

    // LN1 -> h (bf16, in d_out)
    k_ln_part<<<dim3(4, Bq, 32), 256, 0, stream>>>(x, ps, pss);
    k_ln_fin<<<dim3(8), 256, 0, stream>>>(ps, pss, mean1, rstd1);
    k_ln_apply<<<dim3(16384), 256, 0, stream>>>(x, mean1, rstd1, g1, be1, dres);

    // Wq/Wk/Wv per-head transpose + bias pack (single launch)
    k_transpose3<<<dim3(2, 32, 48), 256, 0, stream>>>(Wq, Wk, Wv, bqv, bkv, bvv, buf1, bqkv);
    // QKV projection -> q(scaled),k,vt in regA  (8-phase 256^2 pipeline, 192 blocks)
    k_gemm_8ph<0><<<dim3(12, 16), 512, 0, stream>>>(dres, 1024, buf1, 1024, 1024, bqkv, regA, 0);
    // attention kc-split x2 -> partials (po0=x2, po1=d_out, rs in ps/pss)
    k_attn<<<dim3(16, 32, 2), 256, 0, stream>>>(regA, x2, po1, ps, pss);
    k_attn_combine<<<dim3(4096), 256, 0, stream>>>(x2, po1, ps, pss, attn_out);
    // Wo^T -> buf1; x2 = attn@Wo + bo + x   (128x128 depth-3 pipeline, 256 blocks)
    k_transpose<<<dim3(32, 32, 1), 256, 0, stream>>>(Wo, buf1, 1024, 1024, 0, 0);
    k_gemm_p128<1><<<dim3(8, 32), 256, 0, stream>>>(attn_out, 1024, buf1, 1024, 1024, bo, x,
                                                    x2, 1024);
    // LN2 -> h2 (bf16, in d_out; po1 dead)
    k_ln_part<<<dim3(4, Bq, 32), 256, 0, stream>>>(x2, ps, pss);
    k_ln_fin<<<dim3(8), 256, 0, stream>>>(ps, pss, mean2, rstd2);
    k_ln_apply<<<dim3(16384), 256, 0, stream>>>(x2, mean2, rstd2, g2, be2, dres);

    // ---- FF ----
    k_transpose<<<dim3(128, 32, 1), 256, 0, stream>>>(W1, buf1, 1024, 4096, 0, 0);  // W1T
    // a1 = relu(h2 @ W1T + b1) -> regA [4096][4096] bf16  (8-phase 256^2 pipeline)
    k_gemm_8ph<2><<<dim3(16, 16), 512, 0, stream>>>(dres, 1024, buf1, 1024, 1024, b1, regA,
                                                    4096);
    k_transpose<<<dim3(32, 128, 1), 256, 0, stream>>>(W2, buf1, 4096, 1024, 0, 0);  // W2T
    // d_out(f32) = a1 @ W2T + b2 + x2   (128x128 depth-3 pipeline, 256 blocks)
    k_gemm_p128<3><<<dim3(8, 32), 256, 0, stream>>>(regA, 4096, buf1, 4096, 4096, b2, x2,
                                                    outF, 1024);
}

// Round 11
// 366.247 us; speedup vs baseline: 1.0620x; 1.0354x over previous
//
#include <hip/hip_runtime.h>
#include <hip/hip_bf16.h>

#define Bq 2
#define Tq 2048
#define Cq 1024
#define Hq 16
#define HSq 64
#define EPSq 1e-5f

using bf16 = __hip_bfloat16;
using f32x4 = __attribute__((ext_vector_type(4))) float;
using f32x16 = __attribute__((ext_vector_type(16))) float;
using bf16x8 = __attribute__((ext_vector_type(8))) __bf16;

__device__ __forceinline__ bf16 f2bf(float f) { return __float2bfloat16(f); }
__device__ __forceinline__ unsigned short f2u(float f) {
    return __builtin_bit_cast(unsigned short, __float2bfloat16(f));
}
// async global->LDS, 16B per lane; LDS dest = wave-uniform base + lane*16
__device__ __forceinline__ void gload16(const void* g, void* l) {
    __builtin_amdgcn_global_load_lds((const __attribute__((address_space(1))) void*)g,
                                     (__attribute__((address_space(3))) void*)l, 16, 0, 0);
}

// q pre-scale: softmax 1/sqrt(64) * log2(e); attn uses raw v_exp_f32 (exp2).
#define QSCALE 0.180336884f

// ------------- transpose f32 src -> bf16 dst (dims multiples of 32) -------------
__global__ void k_transpose(const float* __restrict__ src, bf16* __restrict__ dst,
                            int R, int Cc, long strideSrc, long strideDst) {
    __shared__ bf16 tile[32][33];
    const long zb = blockIdx.z;
    src += zb * strideSrc;
    dst += zb * strideDst;
    int c0 = blockIdx.x * 32, r0 = blockIdx.y * 32;
    int tx = threadIdx.x & 31, ty = threadIdx.x >> 5;
    for (int i = ty; i < 32; i += 8)
        tile[i][tx] = f2bf(src[(long)(r0 + i) * Cc + (c0 + tx)]);
    __syncthreads();
    for (int i = ty; i < 32; i += 8)
        dst[(long)(c0 + i) * R + (r0 + tx)] = tile[tx][i];
}

// ==== k_prep: ALL input-only prologue work in ONE launch (4 kernels merged) =====
// blocks [0,3072): Wq/Wk/Wv per-head transpose -> wqkvT (+ bias pack piggyback)
// blocks [3072,4096): Wo^T -> woT
// blocks [4096,8192): W1^T -> w1T
// blocks [8192,8448): LN1 partial sums over sequence axis
// These are mutually independent; merging saves 3 launch overheads and lets the
// small memory-bound pieces co-schedule (hide each other's tails).
__global__ void k_prep(const float* __restrict__ Wq, const float* __restrict__ Wk,
                       const float* __restrict__ Wv, const float* __restrict__ bqv,
                       const float* __restrict__ bkv, const float* __restrict__ bvv,
                       const float* __restrict__ Wo, const float* __restrict__ W1,
                       const float* __restrict__ x, bf16* __restrict__ wqkvT,
                       float* __restrict__ bqkvd, bf16* __restrict__ woT,
                       bf16* __restrict__ w1T, float* __restrict__ ps,
                       float* __restrict__ pss) {
    __shared__ bf16 tile[32][33];
    const int gb = blockIdx.x;
    const int tx = threadIdx.x & 31, ty = threadIdx.x >> 5;
    if (gb < 3072) {  // transpose3 (orig grid (2,32,48))
        const int bx2 = gb & 1, by2 = (gb >> 1) & 31, zb = gb >> 6;
        const int which = zb >> 4, head = zb & 15;
        const float* src = (which == 0 ? Wq : which == 1 ? Wk : Wv) + (long)head * 65536;
        bf16* d = wqkvT + (long)which * 1048576 + (long)head * 65536;
        const int c0 = bx2 * 32, r0 = by2 * 32;
        for (int i = ty; i < 32; i += 8)
            tile[i][tx] = f2bf(src[(long)(r0 + i) * 64 + (c0 + tx)]);
        if (bx2 == 0 && by2 == 0 && zb < 12) {
            int i = zb * 256 + threadIdx.x;  // 0..3071
            bqkvd[i] = i < 1024 ? bqv[i] : i < 2048 ? bkv[i - 1024] : bvv[i - 2048];
        }
        __syncthreads();
        for (int i = ty; i < 32; i += 8)
            d[(long)(c0 + i) * 1024 + (r0 + tx)] = tile[tx][i];
    } else if (gb < 4096) {  // WoT (orig grid (32,32))
        const int g = gb - 3072;
        const int c0 = (g & 31) * 32, r0 = (g >> 5) * 32;
        for (int i = ty; i < 32; i += 8)
            tile[i][tx] = f2bf(Wo[(long)(r0 + i) * 1024 + (c0 + tx)]);
        __syncthreads();
        for (int i = ty; i < 32; i += 8)
            woT[(long)(c0 + i) * 1024 + (r0 + tx)] = tile[tx][i];
    } else if (gb < 8192) {  // W1T (orig grid (128,32); src [1024][4096])
        const int g = gb - 4096;
        const int c0 = (g & 127) * 32, r0 = (g >> 7) * 32;
        for (int i = ty; i < 32; i += 8)
            tile[i][tx] = f2bf(W1[(long)(r0 + i) * 4096 + (c0 + tx)]);
        __syncthreads();
        for (int i = ty; i < 32; i += 8)
            w1T[(long)(c0 + i) * 1024 + (r0 + tx)] = tile[tx][i];
    } else {  // LN1 partial (orig grid (4,2,32))
        const int g = gb - 8192;
        const int c = (g & 3) * 256 + threadIdx.x;
        const int b = (g >> 2) & 1;
        const int tc = g >> 3;
        const float* p = x + (long)b * Tq * Cq + (long)tc * 64 * Cq + c;
        float s = 0.f, ss = 0.f;
        for (int t = 0; t < 64; ++t) {
            float v = p[(long)t * Cq];
            s += v;
            ss += v * v;
        }
        long o = ((long)tc * Bq + b) * Cq + c;
        ps[o] = s;
        pss[o] = ss;
    }
}

// ---------------- LayerNorm over the SEQUENCE axis (per (b,c)), f32 in ----------
__global__ void k_ln_part(const float* __restrict__ x, float* __restrict__ ps,
                          float* __restrict__ pss) {
    int c = blockIdx.x * 256 + threadIdx.x;
    int b = blockIdx.y;
    int tc = blockIdx.z;  // 32 chunks of 64 timesteps
    const float* p = x + (long)b * Tq * Cq + (long)tc * 64 * Cq + c;
    float s = 0.f, ss = 0.f;
    for (int t = 0; t < 64; ++t) {
        float v = p[(long)t * Cq];
        s += v;
        ss += v * v;
    }
    long o = ((long)tc * Bq + b) * Cq + c;
    ps[o] = s;
    pss[o] = ss;
}

__global__ void k_ln_fin(const float* __restrict__ ps, const float* __restrict__ pss,
                         float* __restrict__ mean, float* __restrict__ rstd) {
    int i = blockIdx.x * 256 + threadIdx.x;  // b*Cq + c
    float s = 0.f, ss = 0.f;
    for (int tc = 0; tc < 32; ++tc) {
        s += ps[(long)tc * (Bq * Cq) + i];
        ss += pss[(long)tc * (Bq * Cq) + i];
    }
    float m = s / (float)Tq;
    float var = (ss - s * m) / (float)(Tq - 1);  // ddof=1 (unbiased)
    var = fmaxf(var, 0.f);
    mean[i] = m;
    rstd[i] = 1.0f / (sqrtf(var) + EPSq);  // eps OUTSIDE sqrt
}

__global__ void k_ln_apply(const float* __restrict__ x, const float* __restrict__ mean,
                           const float* __restrict__ rstd, const float* __restrict__ gamma,
                           const float* __restrict__ beta, bf16* __restrict__ out) {
    long i = (long)blockIdx.x * 256 + threadIdx.x;
    int c = (int)(i & (Cq - 1));
    long bt = i >> 10;
    int b = (int)(bt >> 11);
    float m = mean[b * Cq + c], r = rstd[b * Cq + c];
    out[i] = f2bf(gamma[c] * ((x[i] - m) * r) + beta[c]);
}

// XCD-aware bijective chunked swizzle (nwg % 8 == 0 for all our grids)
__device__ __forceinline__ void xcd_swizzle(int& bx, int& by) {
    const int gx = gridDim.x;
    const int nwg = gx * gridDim.y;
    const int bid = blockIdx.y * gx + blockIdx.x;
    const int swz = (bid & 7) * (nwg >> 3) + (bid >> 3);
    bx = swz % gx;
    by = swz / gx;
}

// ======= bf16 NT-GEMM 128x64, 2-deep counted-vmcnt pipeline (proj, FF2) =========
// r9-validated (FF2 51.5us; r10's BK=32 128x128 variant regressed to 55.5 --
// step-overhead amortization beats LDS-traffic reduction). T3/T4: 3 LDS buffers
// (72 KiB -> 2 blocks/CU), stage(t+2) post-barrier, ONE counted vmcnt(6)/step.
// MODE 1/3: outF = acc+bias+residF.
template <int MODE>
__global__ __launch_bounds__(256, 2) void k_gemm_n64p(
    const bf16* __restrict__ A, int lda, const bf16* __restrict__ Bt, int ldb, int K,
    const float* __restrict__ bias, const float* __restrict__ residF,
    float* __restrict__ outF, int ldout) {
    __shared__ __bf16 lds[36864];  // 3 x 12288 (72 KiB)
    int bx, by;
    xcd_swizzle(bx, by);
    const int m0 = by * 128, n0 = bx * 64;
    const int tid = threadIdx.x;
    const int lane = tid & 63, wave = tid >> 6;
    const int lane15 = lane & 15, quad = lane >> 4;
    const int wm = wave * 32;
    const int srow = wave * 16 + (lane >> 2);
    const int scol = (((lane & 3) ^ ((lane >> 3) & 3)) * 8);  // pre-swizzled source
    const int sq8 = (quad ^ ((lane15 >> 1) & 3)) * 8;         // swizzled read slot
    const bf16* Ap = A + (long)(m0 + srow) * lda + scol;
    const bf16* Ap2 = Ap + 64L * lda;
    const bf16* Bp = Bt + (long)(n0 + srow) * ldb + scol;
    const int NT = K >> 6;

    f32x4 acc[2][4];
#pragma unroll
    for (int i = 0; i < 2; ++i)
#pragma unroll
        for (int j = 0; j < 4; ++j)
#pragma unroll
            for (int p = 0; p < 4; ++p) acc[i][j][p] = 0.f;

    auto stage = [&](int t, int ofs) {
        const long ko = (long)t << 6;
        __bf16* b = &lds[ofs + wave * 512];
        gload16(Ap + ko, b);
        gload16(Ap2 + ko, b + 2048);
        gload16(Ap + ko + 32, b + 4096);
        gload16(Ap2 + ko + 32, b + 6144);
        gload16(Bp + ko, b + 8192);
        gload16(Bp + ko + 32, b + 10240);
    };
    auto comp = [&](int ofs) {
        const __bf16* base = &lds[ofs];
#pragma unroll
        for (int kk = 0; kk < 2; ++kk) {
            bf16x8 af[2], bfr[4];
#pragma unroll
            for (int i = 0; i < 2; ++i)
                af[i] = *(const bf16x8*)(base + kk * 4096 + (wm + i * 16 + lane15) * 32 + sq8);
#pragma unroll
            for (int j = 0; j < 4; ++j)
                bfr[j] =
                    *(const bf16x8*)(base + 8192 + kk * 2048 + (j * 16 + lane15) * 32 + sq8);
#pragma unroll
            for (int i = 0; i < 2; ++i)
#pragma unroll
                for (int j = 0; j < 4; ++j)
                    acc[i][j] = __builtin_amdgcn_mfma_f32_16x16x32_bf16(af[i], bfr[j],
                                                                        acc[i][j], 0, 0, 0);
        }
    };

    stage(0, 0);
    stage(1, 12288);
    int o0 = 0, o1 = 12288, o2 = 24576;  // cur / next / staging target
    for (int t = 0; t < NT - 1; ++t) {
        asm volatile("s_waitcnt vmcnt(6)" ::: "memory");  // tile t landed (all 6)
        __builtin_amdgcn_s_barrier();
        if (t + 2 < NT) stage(t + 2, o2);
        comp(o0);
        const int tmp = o0;
        o0 = o1;
        o1 = o2;
        o2 = tmp;
    }
    asm volatile("s_waitcnt vmcnt(0)" ::: "memory");  // last tile
    __builtin_amdgcn_s_barrier();
    comp(o0);

#pragma unroll
    for (int i = 0; i < 2; ++i) {
#pragma unroll
        for (int p = 0; p < 4; ++p) {
            const int m = m0 + wm + i * 16 + quad * 4 + p;
#pragma unroll
            for (int j = 0; j < 4; ++j) {
                const int n = n0 + j * 16 + lane15;
                outF[(long)m * ldout + n] =
                    acc[i][j][p] + bias[n] + residF[(long)m * ldout + n];
            }
        }
    }
}

// ======== 256x256 8-phase pipelined NT-GEMM (m201 template, plain HIP) ==========
// Verified r5-r10. T3+T4+T5; counted vmcnt(4) per K-tile.
// MODE 0: +bias, scatter qkv (q scaled by QSCALE, k plain, V^T packed).
// MODE 2: relu(+bias) -> bf16.
template <int MODE>
__global__ __launch_bounds__(512, 2) void k_gemm_8ph(
    const bf16* __restrict__ A, int lda, const bf16* __restrict__ Bt, int ldb, int K,
    const float* __restrict__ bias, bf16* __restrict__ outB, int ldout) {
    __shared__ __bf16 sA[2][2][256 * 32];
    __shared__ __bf16 sB[2][2][256 * 32];
    int bx, by;
    xcd_swizzle(bx, by);
    const int m0 = by * 256, n0 = bx * 256;
    const int tid = threadIdx.x;
    const int lane = tid & 63, wave = tid >> 6;
    const int lane15 = lane & 15, quad = lane >> 4;
    const int wr = wave >> 2, wc = wave & 3;  // wave tile: rows wr*128, cols wc*64
    const int sq8 = (quad ^ ((lane15 >> 1) & 3)) * 8;  // swizzled read slot
    const int arow = wr * 128 + lane15;
    const int brow = wc * 64 + lane15;
    const int sr = wave * 16 + (lane >> 2);                  // stage row
    const int sc = ((lane & 3) ^ ((lane >> 3) & 3)) * 8;     // pre-swizzled src slot
    const bf16* ApS = A + (long)(m0 + sr) * lda + sc;
    const bf16* BpS = Bt + (long)(n0 + sr) * ldb + sc;
    const int NT = K >> 6;       // K-tiles
    const int NP = NT << 2;      // planes (4 per tile)

    auto stage_plane = [&](int q) {
        if (q >= NP) return;
        const int t = q >> 2, slot = q & 3;
        const int db = t & 1, kk = slot >> 1;
        const long ko = ((long)t << 6) + kk * 32;
        if (!(slot & 1)) {
            gload16(ApS + ko, &sA[db][kk][wave * 512]);
            gload16(ApS + ko + 128L * lda, &sA[db][kk][4096 + wave * 512]);
        } else {
            gload16(BpS + ko, &sB[db][kk][wave * 512]);
            gload16(BpS + ko + 128L * ldb, &sB[db][kk][4096 + wave * 512]);
        }
    };

    f32x4 acc[8][4];
#pragma unroll
    for (int i = 0; i < 8; ++i)
#pragma unroll
        for (int j = 0; j < 4; ++j)
#pragma unroll
            for (int p = 0; p < 4; ++p) acc[i][j][p] = 0.f;

    stage_plane(0);
    stage_plane(1);
    stage_plane(2);
    stage_plane(3);
    stage_plane(4);
    stage_plane(5);
    asm volatile("s_waitcnt vmcnt(4)" ::: "memory");
    __builtin_amdgcn_s_barrier();

    for (int t = 0; t < NT; ++t) {
        const int db = t & 1;
        const __bf16* A0 = sA[db][0];
        const __bf16* A1 = sA[db][1];
        const __bf16* B0 = sB[db][0];
        const __bf16* B1 = sB[db][1];
        bf16x8 af[4], bfx[4];
        // ---- phase 0: kk0, m-half 0 ----
#pragma unroll
        for (int j = 0; j < 4; ++j)
            bfx[j] = *(const bf16x8*)(&B0[(brow + j * 16) * 32 + sq8]);
#pragma unroll
        for (int ii = 0; ii < 4; ++ii)
            af[ii] = *(const bf16x8*)(&A0[(arow + ii * 16) * 32 + sq8]);
        stage_plane(4 * t + 6);
        __builtin_amdgcn_s_barrier();
        __builtin_amdgcn_s_setprio(1);
#pragma unroll
        for (int ii = 0; ii < 4; ++ii)
#pragma unroll
            for (int j = 0; j < 4; ++j)
                acc[ii][j] =
                    __builtin_amdgcn_mfma_f32_16x16x32_bf16(af[ii], bfx[j], acc[ii][j], 0, 0, 0);
        __builtin_amdgcn_s_setprio(0);
        __builtin_amdgcn_s_barrier();
        // ---- phase 1: kk0, m-half 1 ----
#pragma unroll
        for (int ii = 0; ii < 4; ++ii)
            af[ii] = *(const bf16x8*)(&A0[(arow + 64 + ii * 16) * 32 + sq8]);
        stage_plane(4 * t + 7);
        __builtin_amdgcn_s_barrier();
        __builtin_amdgcn_s_setprio(1);
#pragma unroll
        for (int ii = 0; ii < 4; ++ii)
#pragma unroll
            for (int j = 0; j < 4; ++j)
                acc[4 + ii][j] = __builtin_amdgcn_mfma_f32_16x16x32_bf16(af[ii], bfx[j],
                                                                         acc[4 + ii][j], 0, 0, 0);
        __builtin_amdgcn_s_setprio(0);
        __builtin_amdgcn_s_barrier();
        // ---- phase 2: kk1, m-half 0 ----
#pragma unroll
        for (int j = 0; j < 4; ++j)
            bfx[j] = *(const bf16x8*)(&B1[(brow + j * 16) * 32 + sq8]);
#pragma unroll
        for (int ii = 0; ii < 4; ++ii)
            af[ii] = *(const bf16x8*)(&A1[(arow + ii * 16) * 32 + sq8]);
        stage_plane(4 * t + 8);
        __builtin_amdgcn_s_barrier();
        __builtin_amdgcn_s_setprio(1);
#pragma unroll
        for (int ii = 0; ii < 4; ++ii)
#pragma unroll
            for (int j = 0; j < 4; ++j)
                acc[ii][j] =
                    __builtin_amdgcn_mfma_f32_16x16x32_bf16(af[ii], bfx[j], acc[ii][j], 0, 0, 0);
        __builtin_amdgcn_s_setprio(0);
        __builtin_amdgcn_s_barrier();
        // ---- phase 3: kk1, m-half 1 ----
#pragma unroll
        for (int ii = 0; ii < 4; ++ii)
            af[ii] = *(const bf16x8*)(&A1[(arow + 64 + ii * 16) * 32 + sq8]);
        stage_plane(4 * t + 9);
        __builtin_amdgcn_s_barrier();
        __builtin_amdgcn_s_setprio(1);
#pragma unroll
        for (int ii = 0; ii < 4; ++ii)
#pragma unroll
            for (int j = 0; j < 4; ++j)
                acc[4 + ii][j] = __builtin_amdgcn_mfma_f32_16x16x32_bf16(af[ii], bfx[j],
                                                                         acc[4 + ii][j], 0, 0, 0);
        __builtin_amdgcn_s_setprio(0);
        asm volatile("s_waitcnt vmcnt(4)" ::: "memory");
        __builtin_amdgcn_s_barrier();
    }
    // epilogue (C/D layout col=lane&15, row=quad*4+reg; verified m89/m91)
    if (MODE == 0) {
#pragma unroll
        for (int i = 0; i < 8; ++i) {
            const int mm = m0 + wr * 128 + i * 16 + quad * 4;  // t base; p adds 0..3
            const int b = mm >> 11, t4 = mm & (Tq - 1);
#pragma unroll
            for (int j = 0; j < 4; ++j) {
                const int n = n0 + wc * 64 + j * 16 + lane15;
                const int which = n >> 10, hh = (n >> 6) & (Hq - 1), d = n & (HSq - 1);
                const long bh = (long)b * Hq + hh;
                const float bb = bias[n];
                if (which == 0) {  // q, pre-scaled by QSCALE (softmax*log2e folded)
#pragma unroll
                    for (int p = 0; p < 4; ++p)
                        outB[bh * 131072 + (long)(t4 + p) * HSq + d] =
                            f2bf((acc[i][j][p] + bb) * QSCALE);
                } else if (which == 1) {  // k
#pragma unroll
                    for (int p = 0; p < 4; ++p)
                        outB[4194304L + bh * 131072 + (long)(t4 + p) * HSq + d] =
                            f2bf(acc[i][j][p] + bb);
                } else {  // V stored transposed [bh][d][t], 4 consecutive t packed
                    ushort4 pk;
                    pk.x = f2u(acc[i][j][0] + bb);
                    pk.y = f2u(acc[i][j][1] + bb);
                    pk.z = f2u(acc[i][j][2] + bb);
                    pk.w = f2u(acc[i][j][3] + bb);
                    *(ushort4*)(&outB[8388608L + bh * 131072 + (long)d * Tq + t4]) = pk;
                }
            }
        }
    } else {  // MODE 2: relu(acc + bias) -> bf16
#pragma unroll
        for (int i = 0; i < 8; ++i) {
#pragma unroll
            for (int p = 0; p < 4; ++p) {
                const int m = m0 + wr * 128 + i * 16 + quad * 4 + p;
#pragma unroll
                for (int j = 0; j < 4; ++j) {
                    const int n = n0 + wc * 64 + j * 16 + lane15;
                    outB[(long)m * ldout + n] = f2bf(fmaxf(acc[i][j][p] + bias[n], 0.f));
                }
            }
        }
    }
}

// ---------------- flash attention, kc-split x2, bh-major XCD locality ------------
// Verified r8/r9/r10: FETCH 69.7 -> 12.3 MB (K/V L2-resident); raw v_exp_f32.
__global__ __launch_bounds__(256, 4) void k_attn(const bf16* __restrict__ qkv,
                                                 float* __restrict__ po0,
                                                 float* __restrict__ po1,
                                                 float* __restrict__ rs0,
                                                 float* __restrict__ rs1) {
    __shared__ __bf16 sK[64 * 72];
    __shared__ __bf16 sVt[64 * 72];
    const int nlin = blockIdx.x + (int)(gridDim.x * (blockIdx.y + gridDim.y * blockIdx.z));
    const int xcd = nlin & 7, s = nlin >> 3;
    const int bh = (xcd << 2) | (s >> 5);
    const int rem = s & 31;
    const int q0 = (rem & 15) * 128;
    const int z = rem >> 4;
    const int kc0 = z << 10;
    float* __restrict__ po = z ? po1 : po0;
    float* __restrict__ rsb = z ? rs1 : rs0;
    const int tid = threadIdx.x, wave = tid >> 6, lane = tid & 63;
    const int lane31 = lane & 31, laneh = lane >> 5;
    const bf16* Qp = qkv + (long)bh * 131072;
    const bf16* Kp = qkv + 4194304L + (long)bh * 131072;
    const bf16* Vtp = qkv + 8388608L + (long)bh * 131072;
    bf16x8 qa[4];
#pragma unroll
    for (int s2 = 0; s2 < 4; ++s2)
        qa[s2] = *(const bf16x8*)(&Qp[(long)(q0 + wave * 32 + lane31) * HSq + s2 * 16 + laneh * 8]);
    f32x16 o[2];
#pragma unroll
    for (int dt = 0; dt < 2; ++dt)
#pragma unroll
        for (int r = 0; r < 16; ++r) o[dt][r] = 0.f;
    float rs = 0.f;
    const int r0 = tid >> 3, c0 = (tid & 7) * 8;
    const int r1 = r0 + 32;

    uint4 nk0 = *(const uint4*)(&Kp[(long)(kc0 + r0) * HSq + c0]);
    uint4 nk1 = *(const uint4*)(&Kp[(long)(kc0 + r1) * HSq + c0]);
    uint4 nv0 = *(const uint4*)(&Vtp[(long)r0 * Tq + kc0 + c0]);
    uint4 nv1 = *(const uint4*)(&Vtp[(long)r1 * Tq + kc0 + c0]);

    for (int kc = kc0; kc < kc0 + 1024; kc += 64) {
        __syncthreads();
        *(uint4*)(&sK[r0 * 72 + c0]) = nk0;
        *(uint4*)(&sK[r1 * 72 + c0]) = nk1;
        *(uint4*)(&sVt[r0 * 72 + c0]) = nv0;
        *(uint4*)(&sVt[r1 * 72 + c0]) = nv1;
        __syncthreads();
        if (kc + 64 < kc0 + 1024) {
            nk0 = *(const uint4*)(&Kp[(long)(kc + 64 + r0) * HSq + c0]);
            nk1 = *(const uint4*)(&Kp[(long)(kc + 64 + r1) * HSq + c0]);
            nv0 = *(const uint4*)(&Vtp[(long)r0 * Tq + kc + 64 + c0]);
            nv1 = *(const uint4*)(&Vtp[(long)r1 * Tq + kc + 64 + c0]);
        }
#pragma unroll
        for (int nt = 0; nt < 2; ++nt) {
            f32x16 zz;
#pragma unroll
            for (int r = 0; r < 16; ++r) zz[r] = 0.f;
            __builtin_amdgcn_s_setprio(1);
#pragma unroll
            for (int s2 = 0; s2 < 4; ++s2) {
                bf16x8 kb =
                    *(const bf16x8*)(&sK[(nt * 32 + lane31) * 72 + s2 * 16 + laneh * 8]);
                zz = __builtin_amdgcn_mfma_f32_32x32x16_bf16(kb, qa[s2], zz, 0, 0, 0);
            }
            __builtin_amdgcn_s_setprio(0);
            float e[16];
#pragma unroll
            for (int r = 0; r < 16; ++r) {
                e[r] = __builtin_amdgcn_exp2f(zz[r]);  // raw v_exp_f32 (q pre-scaled)
                rs += e[r];
            }
            unsigned int pk[8];
#pragma unroll
            for (int g = 0; g < 4; ++g)
#pragma unroll
                for (int h = 0; h < 2; ++h)
                    pk[g * 2 + h] = (unsigned int)f2u(e[g * 4 + 2 * h]) |
                                    ((unsigned int)f2u(e[g * 4 + 2 * h + 1]) << 16);
            unsigned int sa0 = laneh ? pk[0] : pk[2], sa1 = laneh ? pk[1] : pk[3];
            unsigned int ra0 = __shfl_xor((int)sa0, 32), ra1 = __shfl_xor((int)sa1, 32);
            unsigned int sb0 = laneh ? pk[4] : pk[6], sb1 = laneh ? pk[5] : pk[7];
            unsigned int rb0 = __shfl_xor((int)sb0, 32), rb1 = __shfl_xor((int)sb1, 32);
            uint4 f0, f1;
            if (laneh == 0) {
                f0 = {pk[0], pk[1], ra0, ra1};
                f1 = {pk[4], pk[5], rb0, rb1};
            } else {
                f0 = {ra0, ra1, pk[2], pk[3]};
                f1 = {rb0, rb1, pk[6], pk[7]};
            }
            bf16x8 pa0 = __builtin_bit_cast(bf16x8, f0);
            bf16x8 pa1 = __builtin_bit_cast(bf16x8, f1);
            __builtin_amdgcn_s_setprio(1);
#pragma unroll
            for (int dt = 0; dt < 2; ++dt) {
                bf16x8 vb0 =
                    *(const bf16x8*)(&sVt[(dt * 32 + lane31) * 72 + nt * 32 + laneh * 8]);
                bf16x8 vb1 = *(const bf16x8*)(&sVt[(dt * 32 + lane31) * 72 + nt * 32 + 16 +
                                                   laneh * 8]);
                o[dt] = __builtin_amdgcn_mfma_f32_32x32x16_bf16(pa0, vb0, o[dt], 0, 0, 0);
                o[dt] = __builtin_amdgcn_mfma_f32_32x32x16_bf16(pa1, vb1, o[dt], 0, 0, 0);
            }
            __builtin_amdgcn_s_setprio(0);
        }
    }
    // partial epilogue: store unnormalized O (f32) + this half's row sums
    float ltot = rs + __shfl_xor(rs, 32);
    if (laneh == 0) rsb[(bh << 11) + q0 + wave * 32 + lane31] = ltot;
#pragma unroll
    for (int r = 0; r < 16; ++r) {
        const int tl = (r & 3) + 8 * (r >> 2) + 4 * laneh;
        const int t = q0 + wave * 32 + tl;
        float* pb = po + ((long)(bh << 11) + t) * 64;
#pragma unroll
        for (int dt = 0; dt < 2; ++dt) pb[dt * 32 + lane31] = o[dt][r];
    }
}

// combine: out[b][t][h*64+d] = bf16((po0+po1) / (rs0+rs1)) — 4 floats/thread
__global__ __launch_bounds__(256) void k_attn_combine(
    const float* __restrict__ po0, const float* __restrict__ po1,
    const float* __restrict__ rs0, const float* __restrict__ rs1,
    bf16* __restrict__ out) {
    const long i = ((long)blockIdx.x * 256 + threadIdx.x) * 4;
    const int d = (int)(i & 63);
    const long qq = i >> 6;  // bh*2048 + t
    const int bh = (int)(qq >> 11), t = (int)(qq & 2047);
    const float inv = 1.0f / (rs0[qq] + rs1[qq]);
    const f32x4 a = *(const f32x4*)(po0 + i);
    const f32x4 b = *(const f32x4*)(po1 + i);
    const int bb = bh >> 4, hh = bh & 15;
    ushort4 pk;
    pk.x = f2u((a[0] + b[0]) * inv);
    pk.y = f2u((a[1] + b[1]) * inv);
    pk.z = f2u((a[2] + b[2]) * inv);
    pk.w = f2u((a[3] + b[3]) * inv);
    *(ushort4*)(&out[(((long)bb * Tq + t) << 10) + hh * 64 + d]) = pk;
}

extern "C" void kernel_launch(void* const* d_in, const int* in_sizes, int n_in,
                              void* d_out, int out_size, void* d_ws, size_t ws_size,
                              hipStream_t stream) {
    const float* x = (const float*)d_in[0];
    const float* Wq = (const float*)d_in[1];
    const float* bqv = (const float*)d_in[2];
    const float* Wk = (const float*)d_in[3];
    const float* bkv = (const float*)d_in[4];
    const float* Wv = (const float*)d_in[5];
    const float* bvv = (const float*)d_in[6];
    const float* Wo = (const float*)d_in[7];
    const float* bo = (const float*)d_in[8];
    const float* W1 = (const float*)d_in[9];
    const float* b1 = (const float*)d_in[10];
    const float* W2 = (const float*)d_in[11];
    const float* b2 = (const float*)d_in[12];
    const float* g1 = (const float*)d_in[13];
    const float* be1 = (const float*)d_in[14];
    const float* g2 = (const float*)d_in[15];
    const float* be2 = (const float*)d_in[16];

    // ---- workspace: ~58.8 MiB total ----
    char* ws = (char*)d_ws;
    size_t off = 0;
    auto alloc = [&](size_t bytes) {
        void* p = ws + off;
        off += (bytes + 255) & ~(size_t)255;
        return p;
    };
    bf16* regA = (bf16*)alloc(32L * 1024 * 1024);  // qkv [0,24M) + {wqkvT then attn_out} [24M,32M); later a1 (32 MiB)
    float* x2 = (float*)alloc(4096L * 1024 * 4);   // 16 MiB: attn po0 scratch, then f32 residual
    bf16* buf1 = (bf16*)alloc(4096L * 1024 * 2);   // 8 MiB: W1T (from k_prep) -> W2T (after FF1)
    bf16* bufWo = (bf16*)alloc(1024L * 1024 * 2);  // 2 MiB: WoT (from k_prep)
    float* bqkv = (float*)alloc(3072L * 4);
    float* ps = (float*)alloc(32L * Bq * Cq * 4);  // LN partials; attn rs0 scratch
    float* pss = (float*)alloc(32L * Bq * Cq * 4); // LN partials; attn rs1 scratch
    float* mean1 = (float*)alloc(Bq * Cq * 4);
    float* rstd1 = (float*)alloc(Bq * Cq * 4);
    float* mean2 = (float*)alloc(Bq * Cq * 4);
    float* rstd2 = (float*)alloc(Bq * Cq * 4);
    bf16* dres = (bf16*)d_out;          // d_out first 8 MiB bf16 scratch: h -> h2
    float* outF = (float*)d_out;
    float* po1 = (float*)d_out;         // full 16 MiB of d_out as attn po1 (h dead then)
    bf16* wqkvT = regA + 12582912;      // 6 MiB at regA[24M,30M): read only by QKV gemm
    bf16* attn_out = regA + 12582912;   // same region, written by combine AFTER QKV done

    // prologue: Wqkv^T + Wo^T + W1^T + LN1-partials, ONE launch (all input-only)
    k_prep<<<dim3(8448), 256, 0, stream>>>(Wq, Wk, Wv, bqv, bkv, bvv, Wo, W1, x, wqkvT,
                                           bqkv, bufWo, buf1, ps, pss);
    k_ln_fin<<<dim3(8), 256, 0, stream>>>(ps, pss, mean1, rstd1);
    k_ln_apply<<<dim3(16384), 256, 0, stream>>>(x, mean1, rstd1, g1, be1, dres);

    // QKV projection -> q(scaled),k,vt in regA[0,24M)  (8-phase, 192 blocks)
    k_gemm_8ph<0><<<dim3(12, 16), 512, 0, stream>>>(dres, 1024, wqkvT, 1024, 1024, bqkv, regA,
                                                    0);
    // attention kc-split x2 -> partials (po0=x2, po1=d_out, rs in ps/pss)
    k_attn<<<dim3(16, 32, 2), 256, 0, stream>>>(regA, x2, po1, ps, pss);
    k_attn_combine<<<dim3(4096), 256, 0, stream>>>(x2, po1, ps, pss, attn_out);
    // x2 = attn@Wo + bo + x   (n64p pipelined 128x64, 512 blocks, 2/CU)
    k_gemm_n64p<1><<<dim3(16, 32), 256, 0, stream>>>(attn_out, 1024, bufWo, 1024, 1024, bo, x,
                                                     x2, 1024);
    // LN2 -> h2 (bf16, in d_out; po1 dead)
    k_ln_part<<<dim3(4, Bq, 32), 256, 0, stream>>>(x2, ps, pss);
    k_ln_fin<<<dim3(8), 256, 0, stream>>>(ps, pss, mean2, rstd2);
    k_ln_apply<<<dim3(16384), 256, 0, stream>>>(x2, mean2, rstd2, g2, be2, dres);

    // ---- FF ----
    // a1 = relu(h2 @ W1T + b1) -> regA [4096][4096] bf16  (8-phase 256^2 pipeline)
    k_gemm_8ph<2><<<dim3(16, 16), 512, 0, stream>>>(dres, 1024, buf1, 1024, 1024, b1, regA,
                                                    4096);
    k_transpose<<<dim3(32, 128, 1), 256, 0, stream>>>(W2, buf1, 4096, 1024, 0, 0);  // W2T
    // d_out(f32) = a1 @ W2T + b2 + x2   (n64p pipelined 128x64, 512 blocks, 2/CU)
    k_gemm_n64p<3><<<dim3(16, 32), 256, 0, stream>>>(regA, 4096, buf1, 4096, 4096, b2, x2,
                                                     outF, 1024);
}

// Round 12
// 362.907 us; speedup vs baseline: 1.0718x; 1.0092x over previous
//
#include <hip/hip_runtime.h>
#include <hip/hip_bf16.h>

#define Bq 2
#define Tq 2048
#define Cq 1024
#define Hq 16
#define HSq 64
#define EPSq 1e-5f

using bf16 = __hip_bfloat16;
using f32x4 = __attribute__((ext_vector_type(4))) float;
using f32x16 = __attribute__((ext_vector_type(16))) float;
using bf16x8 = __attribute__((ext_vector_type(8))) __bf16;

__device__ __forceinline__ bf16 f2bf(float f) { return __float2bfloat16(f); }
__device__ __forceinline__ unsigned short f2u(float f) {
    return __builtin_bit_cast(unsigned short, __float2bfloat16(f));
}
// async global->LDS, 16B per lane; LDS dest = wave-uniform base + lane*16
__device__ __forceinline__ void gload16(const void* g, void* l) {
    __builtin_amdgcn_global_load_lds((const __attribute__((address_space(1))) void*)g,
                                     (__attribute__((address_space(3))) void*)l, 16, 0, 0);
}

// q pre-scale: softmax 1/sqrt(64) * log2(e); attn uses raw v_exp_f32 (exp2).
#define QSCALE 0.180336884f

// ------------- transpose f32 src -> bf16 dst (dims multiples of 32) -------------
__global__ void k_transpose(const float* __restrict__ src, bf16* __restrict__ dst,
                            int R, int Cc, long strideSrc, long strideDst) {
    __shared__ bf16 tile[32][33];
    const long zb = blockIdx.z;
    src += zb * strideSrc;
    dst += zb * strideDst;
    int c0 = blockIdx.x * 32, r0 = blockIdx.y * 32;
    int tx = threadIdx.x & 31, ty = threadIdx.x >> 5;
    for (int i = ty; i < 32; i += 8)
        tile[i][tx] = f2bf(src[(long)(r0 + i) * Cc + (c0 + tx)]);
    __syncthreads();
    for (int i = ty; i < 32; i += 8)
        dst[(long)(c0 + i) * R + (r0 + tx)] = tile[tx][i];
}

// ==== k_prep: ALL input-only prologue work in ONE launch (verified r11) =========
// blocks [0,3072): Wq/Wk/Wv per-head transpose -> wqkvT (+ bias pack piggyback)
// blocks [3072,4096): Wo^T -> woT
// blocks [4096,8192): W1^T -> w1T
// blocks [8192,8448): LN1 partial sums over sequence axis
__global__ void k_prep(const float* __restrict__ Wq, const float* __restrict__ Wk,
                       const float* __restrict__ Wv, const float* __restrict__ bqv,
                       const float* __restrict__ bkv, const float* __restrict__ bvv,
                       const float* __restrict__ Wo, const float* __restrict__ W1,
                       const float* __restrict__ x, bf16* __restrict__ wqkvT,
                       float* __restrict__ bqkvd, bf16* __restrict__ woT,
                       bf16* __restrict__ w1T, float* __restrict__ ps,
                       float* __restrict__ pss) {
    __shared__ bf16 tile[32][33];
    const int gb = blockIdx.x;
    const int tx = threadIdx.x & 31, ty = threadIdx.x >> 5;
    if (gb < 3072) {  // transpose3 (orig grid (2,32,48))
        const int bx2 = gb & 1, by2 = (gb >> 1) & 31, zb = gb >> 6;
        const int which = zb >> 4, head = zb & 15;
        const float* src = (which == 0 ? Wq : which == 1 ? Wk : Wv) + (long)head * 65536;
        bf16* d = wqkvT + (long)which * 1048576 + (long)head * 65536;
        const int c0 = bx2 * 32, r0 = by2 * 32;
        for (int i = ty; i < 32; i += 8)
            tile[i][tx] = f2bf(src[(long)(r0 + i) * 64 + (c0 + tx)]);
        if (bx2 == 0 && by2 == 0 && zb < 12) {
            int i = zb * 256 + threadIdx.x;  // 0..3071
            bqkvd[i] = i < 1024 ? bqv[i] : i < 2048 ? bkv[i - 1024] : bvv[i - 2048];
        }
        __syncthreads();
        for (int i = ty; i < 32; i += 8)
            d[(long)(c0 + i) * 1024 + (r0 + tx)] = tile[tx][i];
    } else if (gb < 4096) {  // WoT (orig grid (32,32))
        const int g = gb - 3072;
        const int c0 = (g & 31) * 32, r0 = (g >> 5) * 32;
        for (int i = ty; i < 32; i += 8)
            tile[i][tx] = f2bf(Wo[(long)(r0 + i) * 1024 + (c0 + tx)]);
        __syncthreads();
        for (int i = ty; i < 32; i += 8)
            woT[(long)(c0 + i) * 1024 + (r0 + tx)] = tile[tx][i];
    } else if (gb < 8192) {  // W1T (orig grid (128,32); src [1024][4096])
        const int g = gb - 4096;
        const int c0 = (g & 127) * 32, r0 = (g >> 7) * 32;
        for (int i = ty; i < 32; i += 8)
            tile[i][tx] = f2bf(W1[(long)(r0 + i) * 4096 + (c0 + tx)]);
        __syncthreads();
        for (int i = ty; i < 32; i += 8)
            w1T[(long)(c0 + i) * 1024 + (r0 + tx)] = tile[tx][i];
    } else {  // LN1 partial (orig grid (4,2,32))
        const int g = gb - 8192;
        const int c = (g & 3) * 256 + threadIdx.x;
        const int b = (g >> 2) & 1;
        const int tc = g >> 3;
        const float* p = x + (long)b * Tq * Cq + (long)tc * 64 * Cq + c;
        float s = 0.f, ss = 0.f;
        for (int t = 0; t < 64; ++t) {
            float v = p[(long)t * Cq];
            s += v;
            ss += v * v;
        }
        long o = ((long)tc * Bq + b) * Cq + c;
        ps[o] = s;
        pss[o] = ss;
    }
}

// ---------------- LayerNorm over the SEQUENCE axis (per (b,c)), f32 in ----------
__global__ void k_ln_part(const float* __restrict__ x, float* __restrict__ ps,
                          float* __restrict__ pss) {
    int c = blockIdx.x * 256 + threadIdx.x;
    int b = blockIdx.y;
    int tc = blockIdx.z;  // 32 chunks of 64 timesteps
    const float* p = x + (long)b * Tq * Cq + (long)tc * 64 * Cq + c;
    float s = 0.f, ss = 0.f;
    for (int t = 0; t < 64; ++t) {
        float v = p[(long)t * Cq];
        s += v;
        ss += v * v;
    }
    long o = ((long)tc * Bq + b) * Cq + c;
    ps[o] = s;
    pss[o] = ss;
}

__global__ void k_ln_fin(const float* __restrict__ ps, const float* __restrict__ pss,
                         float* __restrict__ mean, float* __restrict__ rstd) {
    int i = blockIdx.x * 256 + threadIdx.x;  // b*Cq + c
    float s = 0.f, ss = 0.f;
    for (int tc = 0; tc < 32; ++tc) {
        s += ps[(long)tc * (Bq * Cq) + i];
        ss += pss[(long)tc * (Bq * Cq) + i];
    }
    float m = s / (float)Tq;
    float var = (ss - s * m) / (float)(Tq - 1);  // ddof=1 (unbiased)
    var = fmaxf(var, 0.f);
    mean[i] = m;
    rstd[i] = 1.0f / (sqrtf(var) + EPSq);  // eps OUTSIDE sqrt
}

__global__ void k_ln_apply(const float* __restrict__ x, const float* __restrict__ mean,
                           const float* __restrict__ rstd, const float* __restrict__ gamma,
                           const float* __restrict__ beta, bf16* __restrict__ out) {
    long i = (long)blockIdx.x * 256 + threadIdx.x;
    int c = (int)(i & (Cq - 1));
    long bt = i >> 10;
    int b = (int)(bt >> 11);
    float m = mean[b * Cq + c], r = rstd[b * Cq + c];
    out[i] = f2bf(gamma[c] * ((x[i] - m) * r) + beta[c]);
}

// XCD-aware bijective chunked swizzle (nwg % 8 == 0 for all our grids)
__device__ __forceinline__ void xcd_swizzle(int& bx, int& by) {
    const int gx = gridDim.x;
    const int nwg = gx * gridDim.y;
    const int bid = blockIdx.y * gx + blockIdx.x;
    const int swz = (bid & 7) * (nwg >> 3) + (bid >> 3);
    bx = swz % gx;
    by = swz / gx;
}

// ==== bf16 NT-GEMM 128x128, 64x64 wave-tiles, BK=64, n64p rotation (proj, FF2) ==
// The untried cell of the r9/r10 matrix: square wave-tiles (LDS fragment traffic
// 64 reads/CU-step vs n64p's 96 -- r9 PMC showed n64p LDS-bound at 1152/1950 cyc)
// COMBINED with BK=64 (r10's BK=32 doubled step count and regressed). Schedule is
// the twice-validated n64p rotation: 3 buffers (32 KiB each = 96 KiB -> 1
// block/CU), stage(t+2) post-barrier, counted vmcnt(8) per step (8 loads/tile/
// wave; prologue 16 outstanding; tail drains 8 -> 0; never 0 in-loop).
// Overwrite hazard: stage(t+2) targets buf(t-1), last read comp(t-1) before the
// barrier all waves passed. Geometry (wave map + epilogue) byte-identical to
// r10's p128, which refcheck'd clean. MODE 1/3: outF = acc + bias + residF.
// Buffer layout (elems): A-kk0 [0,4096) A-kk1 [4096,8192) B-kk0 [8192,12288)
// B-kk1 [12288,16384); each plane 128 rows x 32 cols row-major.
template <int MODE>
__global__ __launch_bounds__(256, 1) void k_gemm_sq128(
    const bf16* __restrict__ A, int lda, const bf16* __restrict__ Bt, int ldb, int K,
    const float* __restrict__ bias, const float* __restrict__ residF,
    float* __restrict__ outF, int ldout) {
    __shared__ __bf16 lds[3 * 16384];  // 3 x 32 KiB = 96 KiB
    int bx, by;
    xcd_swizzle(bx, by);
    const int m0 = by * 128, n0 = bx * 128;
    const int tid = threadIdx.x;
    const int lane = tid & 63, wave = tid >> 6;
    const int lane15 = lane & 15, quad = lane >> 4;
    const int wm = (wave >> 1) * 64, wn = (wave & 1) * 64;  // 2x2 waves of 64x64
    const int srow = wave * 16 + (lane >> 2);
    const int scol = (((lane & 3) ^ ((lane >> 3) & 3)) * 8);  // pre-swizzled source
    const int sq8 = (quad ^ ((lane15 >> 1) & 3)) * 8;         // swizzled read slot
    const bf16* Ap = A + (long)(m0 + srow) * lda + scol;
    const bf16* Ap2 = Ap + 64L * lda;
    const bf16* Bp = Bt + (long)(n0 + srow) * ldb + scol;
    const bf16* Bp2 = Bp + 64L * ldb;
    const int NT = K >> 6;

    f32x4 acc[4][4];
#pragma unroll
    for (int i = 0; i < 4; ++i)
#pragma unroll
        for (int j = 0; j < 4; ++j)
#pragma unroll
            for (int p = 0; p < 4; ++p) acc[i][j][p] = 0.f;

    auto stage = [&](int t, int ofs) {
        const long ko = (long)t << 6;
        __bf16* b = &lds[ofs + wave * 512];
        gload16(Ap + ko, b);                 // A kk0 rows 0-63
        gload16(Ap2 + ko, b + 2048);         // A kk0 rows 64-127
        gload16(Ap + ko + 32, b + 4096);     // A kk1 rows 0-63
        gload16(Ap2 + ko + 32, b + 6144);    // A kk1 rows 64-127
        gload16(Bp + ko, b + 8192);          // B kk0 rows 0-63
        gload16(Bp2 + ko, b + 10240);        // B kk0 rows 64-127
        gload16(Bp + ko + 32, b + 12288);    // B kk1 rows 0-63
        gload16(Bp2 + ko + 32, b + 14336);   // B kk1 rows 64-127
    };
    auto comp = [&](int ofs) {
        const __bf16* base = &lds[ofs];
#pragma unroll
        for (int kk = 0; kk < 2; ++kk) {
            bf16x8 af[4], bfr[4];
#pragma unroll
            for (int i = 0; i < 4; ++i)
                af[i] = *(const bf16x8*)(base + kk * 4096 + (wm + i * 16 + lane15) * 32 + sq8);
#pragma unroll
            for (int j = 0; j < 4; ++j)
                bfr[j] =
                    *(const bf16x8*)(base + 8192 + kk * 4096 + (wn + j * 16 + lane15) * 32 + sq8);
#pragma unroll
            for (int i = 0; i < 4; ++i)
#pragma unroll
                for (int j = 0; j < 4; ++j)
                    acc[i][j] = __builtin_amdgcn_mfma_f32_16x16x32_bf16(af[i], bfr[j],
                                                                        acc[i][j], 0, 0, 0);
        }
    };

    stage(0, 0);
    stage(1, 16384);
    int o0 = 0, o1 = 16384, o2 = 32768;  // cur / next / staging target
    for (int t = 0; t < NT - 1; ++t) {
        asm volatile("s_waitcnt vmcnt(8)" ::: "memory");  // tile t landed (all 8)
        __builtin_amdgcn_s_barrier();
        if (t + 2 < NT) stage(t + 2, o2);
        comp(o0);
        const int tmp = o0;
        o0 = o1;
        o1 = o2;
        o2 = tmp;
    }
    asm volatile("s_waitcnt vmcnt(0)" ::: "memory");  // last tile
    __builtin_amdgcn_s_barrier();
    comp(o0);

#pragma unroll
    for (int i = 0; i < 4; ++i) {
#pragma unroll
        for (int p = 0; p < 4; ++p) {
            const int m = m0 + wm + i * 16 + quad * 4 + p;
#pragma unroll
            for (int j = 0; j < 4; ++j) {
                const int n = n0 + wn + j * 16 + lane15;
                outF[(long)m * ldout + n] =
                    acc[i][j][p] + bias[n] + residF[(long)m * ldout + n];
            }
        }
    }
}

// ======== 256x256 8-phase pipelined NT-GEMM (m201 template, plain HIP) ==========
// Verified r5-r11. T3+T4+T5; counted vmcnt(4) per K-tile.
// MODE 0: +bias, scatter qkv (q scaled by QSCALE, k plain, V^T packed).
// MODE 2: relu(+bias) -> bf16.
template <int MODE>
__global__ __launch_bounds__(512, 2) void k_gemm_8ph(
    const bf16* __restrict__ A, int lda, const bf16* __restrict__ Bt, int ldb, int K,
    const float* __restrict__ bias, bf16* __restrict__ outB, int ldout) {
    __shared__ __bf16 sA[2][2][256 * 32];
    __shared__ __bf16 sB[2][2][256 * 32];
    int bx, by;
    xcd_swizzle(bx, by);
    const int m0 = by * 256, n0 = bx * 256;
    const int tid = threadIdx.x;
    const int lane = tid & 63, wave = tid >> 6;
    const int lane15 = lane & 15, quad = lane >> 4;
    const int wr = wave >> 2, wc = wave & 3;  // wave tile: rows wr*128, cols wc*64
    const int sq8 = (quad ^ ((lane15 >> 1) & 3)) * 8;  // swizzled read slot
    const int arow = wr * 128 + lane15;
    const int brow = wc * 64 + lane15;
    const int sr = wave * 16 + (lane >> 2);                  // stage row
    const int sc = ((lane & 3) ^ ((lane >> 3) & 3)) * 8;     // pre-swizzled src slot
    const bf16* ApS = A + (long)(m0 + sr) * lda + sc;
    const bf16* BpS = Bt + (long)(n0 + sr) * ldb + sc;
    const int NT = K >> 6;       // K-tiles
    const int NP = NT << 2;      // planes (4 per tile)

    auto stage_plane = [&](int q) {
        if (q >= NP) return;
        const int t = q >> 2, slot = q & 3;
        const int db = t & 1, kk = slot >> 1;
        const long ko = ((long)t << 6) + kk * 32;
        if (!(slot & 1)) {
            gload16(ApS + ko, &sA[db][kk][wave * 512]);
            gload16(ApS + ko + 128L * lda, &sA[db][kk][4096 + wave * 512]);
        } else {
            gload16(BpS + ko, &sB[db][kk][wave * 512]);
            gload16(BpS + ko + 128L * ldb, &sB[db][kk][4096 + wave * 512]);
        }
    };

    f32x4 acc[8][4];
#pragma unroll
    for (int i = 0; i < 8; ++i)
#pragma unroll
        for (int j = 0; j < 4; ++j)
#pragma unroll
            for (int p = 0; p < 4; ++p) acc[i][j][p] = 0.f;

    stage_plane(0);
    stage_plane(1);
    stage_plane(2);
    stage_plane(3);
    stage_plane(4);
    stage_plane(5);
    asm volatile("s_waitcnt vmcnt(4)" ::: "memory");
    __builtin_amdgcn_s_barrier();

    for (int t = 0; t < NT; ++t) {
        const int db = t & 1;
        const __bf16* A0 = sA[db][0];
        const __bf16* A1 = sA[db][1];
        const __bf16* B0 = sB[db][0];
        const __bf16* B1 = sB[db][1];
        bf16x8 af[4], bfx[4];
        // ---- phase 0: kk0, m-half 0 ----
#pragma unroll
        for (int j = 0; j < 4; ++j)
            bfx[j] = *(const bf16x8*)(&B0[(brow + j * 16) * 32 + sq8]);
#pragma unroll
        for (int ii = 0; ii < 4; ++ii)
            af[ii] = *(const bf16x8*)(&A0[(arow + ii * 16) * 32 + sq8]);
        stage_plane(4 * t + 6);
        __builtin_amdgcn_s_barrier();
        __builtin_amdgcn_s_setprio(1);
#pragma unroll
        for (int ii = 0; ii < 4; ++ii)
#pragma unroll
            for (int j = 0; j < 4; ++j)
                acc[ii][j] =
                    __builtin_amdgcn_mfma_f32_16x16x32_bf16(af[ii], bfx[j], acc[ii][j], 0, 0, 0);
        __builtin_amdgcn_s_setprio(0);
        __builtin_amdgcn_s_barrier();
        // ---- phase 1: kk0, m-half 1 ----
#pragma unroll
        for (int ii = 0; ii < 4; ++ii)
            af[ii] = *(const bf16x8*)(&A0[(arow + 64 + ii * 16) * 32 + sq8]);
        stage_plane(4 * t + 7);
        __builtin_amdgcn_s_barrier();
        __builtin_amdgcn_s_setprio(1);
#pragma unroll
        for (int ii = 0; ii < 4; ++ii)
#pragma unroll
            for (int j = 0; j < 4; ++j)
                acc[4 + ii][j] = __builtin_amdgcn_mfma_f32_16x16x32_bf16(af[ii], bfx[j],
                                                                         acc[4 + ii][j], 0, 0, 0);
        __builtin_amdgcn_s_setprio(0);
        __builtin_amdgcn_s_barrier();
        // ---- phase 2: kk1, m-half 0 ----
#pragma unroll
        for (int j = 0; j < 4; ++j)
            bfx[j] = *(const bf16x8*)(&B1[(brow + j * 16) * 32 + sq8]);
#pragma unroll
        for (int ii = 0; ii < 4; ++ii)
            af[ii] = *(const bf16x8*)(&A1[(arow + ii * 16) * 32 + sq8]);
        stage_plane(4 * t + 8);
        __builtin_amdgcn_s_barrier();
        __builtin_amdgcn_s_setprio(1);
#pragma unroll
        for (int ii = 0; ii < 4; ++ii)
#pragma unroll
            for (int j = 0; j < 4; ++j)
                acc[ii][j] =
                    __builtin_amdgcn_mfma_f32_16x16x32_bf16(af[ii], bfx[j], acc[ii][j], 0, 0, 0);
        __builtin_amdgcn_s_setprio(0);
        __builtin_amdgcn_s_barrier();
        // ---- phase 3: kk1, m-half 1 ----
#pragma unroll
        for (int ii = 0; ii < 4; ++ii)
            af[ii] = *(const bf16x8*)(&A1[(arow + 64 + ii * 16) * 32 + sq8]);
        stage_plane(4 * t + 9);
        __builtin_amdgcn_s_barrier();
        __builtin_amdgcn_s_setprio(1);
#pragma unroll
        for (int ii = 0; ii < 4; ++ii)
#pragma unroll
            for (int j = 0; j < 4; ++j)
                acc[4 + ii][j] = __builtin_amdgcn_mfma_f32_16x16x32_bf16(af[ii], bfx[j],
                                                                         acc[4 + ii][j], 0, 0, 0);
        __builtin_amdgcn_s_setprio(0);
        asm volatile("s_waitcnt vmcnt(4)" ::: "memory");
        __builtin_amdgcn_s_barrier();
    }
    // epilogue (C/D layout col=lane&15, row=quad*4+reg; verified m89/m91)
    if (MODE == 0) {
#pragma unroll
        for (int i = 0; i < 8; ++i) {
            const int mm = m0 + wr * 128 + i * 16 + quad * 4;  // t base; p adds 0..3
            const int b = mm >> 11, t4 = mm & (Tq - 1);
#pragma unroll
            for (int j = 0; j < 4; ++j) {
                const int n = n0 + wc * 64 + j * 16 + lane15;
                const int which = n >> 10, hh = (n >> 6) & (Hq - 1), d = n & (HSq - 1);
                const long bh = (long)b * Hq + hh;
                const float bb = bias[n];
                if (which == 0) {  // q, pre-scaled by QSCALE (softmax*log2e folded)
#pragma unroll
                    for (int p = 0; p < 4; ++p)
                        outB[bh * 131072 + (long)(t4 + p) * HSq + d] =
                            f2bf((acc[i][j][p] + bb) * QSCALE);
                } else if (which == 1) {  // k
#pragma unroll
                    for (int p = 0; p < 4; ++p)
                        outB[4194304L + bh * 131072 + (long)(t4 + p) * HSq + d] =
                            f2bf(acc[i][j][p] + bb);
                } else {  // V stored transposed [bh][d][t], 4 consecutive t packed
                    ushort4 pk;
                    pk.x = f2u(acc[i][j][0] + bb);
                    pk.y = f2u(acc[i][j][1] + bb);
                    pk.z = f2u(acc[i][j][2] + bb);
                    pk.w = f2u(acc[i][j][3] + bb);
                    *(ushort4*)(&outB[8388608L + bh * 131072 + (long)d * Tq + t4]) = pk;
                }
            }
        }
    } else {  // MODE 2: relu(acc + bias) -> bf16
#pragma unroll
        for (int i = 0; i < 8; ++i) {
#pragma unroll
            for (int p = 0; p < 4; ++p) {
                const int m = m0 + wr * 128 + i * 16 + quad * 4 + p;
#pragma unroll
                for (int j = 0; j < 4; ++j) {
                    const int n = n0 + wc * 64 + j * 16 + lane15;
                    outB[(long)m * ldout + n] = f2bf(fmaxf(acc[i][j][p] + bias[n], 0.f));
                }
            }
        }
    }
}

// ---------------- flash attention, kc-split x2, bh-major XCD locality ------------
// Verified r8-r11: FETCH 69.7 -> 12.3 MB (K/V L2-resident); raw v_exp_f32.
__global__ __launch_bounds__(256, 4) void k_attn(const bf16* __restrict__ qkv,
                                                 float* __restrict__ po0,
                                                 float* __restrict__ po1,
                                                 float* __restrict__ rs0,
                                                 float* __restrict__ rs1) {
    __shared__ __bf16 sK[64 * 72];
    __shared__ __bf16 sVt[64 * 72];
    const int nlin = blockIdx.x + (int)(gridDim.x * (blockIdx.y + gridDim.y * blockIdx.z));
    const int xcd = nlin & 7, s = nlin >> 3;
    const int bh = (xcd << 2) | (s >> 5);
    const int rem = s & 31;
    const int q0 = (rem & 15) * 128;
    const int z = rem >> 4;
    const int kc0 = z << 10;
    float* __restrict__ po = z ? po1 : po0;
    float* __restrict__ rsb = z ? rs1 : rs0;
    const int tid = threadIdx.x, wave = tid >> 6, lane = tid & 63;
    const int lane31 = lane & 31, laneh = lane >> 5;
    const bf16* Qp = qkv + (long)bh * 131072;
    const bf16* Kp = qkv + 4194304L + (long)bh * 131072;
    const bf16* Vtp = qkv + 8388608L + (long)bh * 131072;
    bf16x8 qa[4];
#pragma unroll
    for (int s2 = 0; s2 < 4; ++s2)
        qa[s2] = *(const bf16x8*)(&Qp[(long)(q0 + wave * 32 + lane31) * HSq + s2 * 16 + laneh * 8]);
    f32x16 o[2];
#pragma unroll
    for (int dt = 0; dt < 2; ++dt)
#pragma unroll
        for (int r = 0; r < 16; ++r) o[dt][r] = 0.f;
    float rs = 0.f;
    const int r0 = tid >> 3, c0 = (tid & 7) * 8;
    const int r1 = r0 + 32;

    uint4 nk0 = *(const uint4*)(&Kp[(long)(kc0 + r0) * HSq + c0]);
    uint4 nk1 = *(const uint4*)(&Kp[(long)(kc0 + r1) * HSq + c0]);
    uint4 nv0 = *(const uint4*)(&Vtp[(long)r0 * Tq + kc0 + c0]);
    uint4 nv1 = *(const uint4*)(&Vtp[(long)r1 * Tq + kc0 + c0]);

    for (int kc = kc0; kc < kc0 + 1024; kc += 64) {
        __syncthreads();
        *(uint4*)(&sK[r0 * 72 + c0]) = nk0;
        *(uint4*)(&sK[r1 * 72 + c0]) = nk1;
        *(uint4*)(&sVt[r0 * 72 + c0]) = nv0;
        *(uint4*)(&sVt[r1 * 72 + c0]) = nv1;
        __syncthreads();
        if (kc + 64 < kc0 + 1024) {
            nk0 = *(const uint4*)(&Kp[(long)(kc + 64 + r0) * HSq + c0]);
            nk1 = *(const uint4*)(&Kp[(long)(kc + 64 + r1) * HSq + c0]);
            nv0 = *(const uint4*)(&Vtp[(long)r0 * Tq + kc + 64 + c0]);
            nv1 = *(const uint4*)(&Vtp[(long)r1 * Tq + kc + 64 + c0]);
        }
#pragma unroll
        for (int nt = 0; nt < 2; ++nt) {
            f32x16 zz;
#pragma unroll
            for (int r = 0; r < 16; ++r) zz[r] = 0.f;
            __builtin_amdgcn_s_setprio(1);
#pragma unroll
            for (int s2 = 0; s2 < 4; ++s2) {
                bf16x8 kb =
                    *(const bf16x8*)(&sK[(nt * 32 + lane31) * 72 + s2 * 16 + laneh * 8]);
                zz = __builtin_amdgcn_mfma_f32_32x32x16_bf16(kb, qa[s2], zz, 0, 0, 0);
            }
            __builtin_amdgcn_s_setprio(0);
            float e[16];
#pragma unroll
            for (int r = 0; r < 16; ++r) {
                e[r] = __builtin_amdgcn_exp2f(zz[r]);  // raw v_exp_f32 (q pre-scaled)
                rs += e[r];
            }
            unsigned int pk[8];
#pragma unroll
            for (int g = 0; g < 4; ++g)
#pragma unroll
                for (int h = 0; h < 2; ++h)
                    pk[g * 2 + h] = (unsigned int)f2u(e[g * 4 + 2 * h]) |
                                    ((unsigned int)f2u(e[g * 4 + 2 * h + 1]) << 16);
            unsigned int sa0 = laneh ? pk[0] : pk[2], sa1 = laneh ? pk[1] : pk[3];
            unsigned int ra0 = __shfl_xor((int)sa0, 32), ra1 = __shfl_xor((int)sa1, 32);
            unsigned int sb0 = laneh ? pk[4] : pk[6], sb1 = laneh ? pk[5] : pk[7];
            unsigned int rb0 = __shfl_xor((int)sb0, 32), rb1 = __shfl_xor((int)sb1, 32);
            uint4 f0, f1;
            if (laneh == 0) {
                f0 = {pk[0], pk[1], ra0, ra1};
                f1 = {pk[4], pk[5], rb0, rb1};
            } else {
                f0 = {ra0, ra1, pk[2], pk[3]};
                f1 = {rb0, rb1, pk[6], pk[7]};
            }
            bf16x8 pa0 = __builtin_bit_cast(bf16x8, f0);
            bf16x8 pa1 = __builtin_bit_cast(bf16x8, f1);
            __builtin_amdgcn_s_setprio(1);
#pragma unroll
            for (int dt = 0; dt < 2; ++dt) {
                bf16x8 vb0 =
                    *(const bf16x8*)(&sVt[(dt * 32 + lane31) * 72 + nt * 32 + laneh * 8]);
                bf16x8 vb1 = *(const bf16x8*)(&sVt[(dt * 32 + lane31) * 72 + nt * 32 + 16 +
                                                   laneh * 8]);
                o[dt] = __builtin_amdgcn_mfma_f32_32x32x16_bf16(pa0, vb0, o[dt], 0, 0, 0);
                o[dt] = __builtin_amdgcn_mfma_f32_32x32x16_bf16(pa1, vb1, o[dt], 0, 0, 0);
            }
            __builtin_amdgcn_s_setprio(0);
        }
    }
    // partial epilogue: store unnormalized O (f32) + this half's row sums
    float ltot = rs + __shfl_xor(rs, 32);
    if (laneh == 0) rsb[(bh << 11) + q0 + wave * 32 + lane31] = ltot;
#pragma unroll
    for (int r = 0; r < 16; ++r) {
        const int tl = (r & 3) + 8 * (r >> 2) + 4 * laneh;
        const int t = q0 + wave * 32 + tl;
        float* pb = po + ((long)(bh << 11) + t) * 64;
#pragma unroll
        for (int dt = 0; dt < 2; ++dt) pb[dt * 32 + lane31] = o[dt][r];
    }
}

// combine: out[b][t][h*64+d] = bf16((po0+po1) / (rs0+rs1)) — 4 floats/thread
__global__ __launch_bounds__(256) void k_attn_combine(
    const float* __restrict__ po0, const float* __restrict__ po1,
    const float* __restrict__ rs0, const float* __restrict__ rs1,
    bf16* __restrict__ out) {
    const long i = ((long)blockIdx.x * 256 + threadIdx.x) * 4;
    const int d = (int)(i & 63);
    const long qq = i >> 6;  // bh*2048 + t
    const int bh = (int)(qq >> 11), t = (int)(qq & 2047);
    const float inv = 1.0f / (rs0[qq] + rs1[qq]);
    const f32x4 a = *(const f32x4*)(po0 + i);
    const f32x4 b = *(const f32x4*)(po1 + i);
    const int bb = bh >> 4, hh = bh & 15;
    ushort4 pk;
    pk.x = f2u((a[0] + b[0]) * inv);
    pk.y = f2u((a[1] + b[1]) * inv);
    pk.z = f2u((a[2] + b[2]) * inv);
    pk.w = f2u((a[3] + b[3]) * inv);
    *(ushort4*)(&out[(((long)bb * Tq + t) << 10) + hh * 64 + d]) = pk;
}

extern "C" void kernel_launch(void* const* d_in, const int* in_sizes, int n_in,
                              void* d_out, int out_size, void* d_ws, size_t ws_size,
                              hipStream_t stream) {
    const float* x = (const float*)d_in[0];
    const float* Wq = (const float*)d_in[1];
    const float* bqv = (const float*)d_in[2];
    const float* Wk = (const float*)d_in[3];
    const float* bkv = (const float*)d_in[4];
    const float* Wv = (const float*)d_in[5];
    const float* bvv = (const float*)d_in[6];
    const float* Wo = (const float*)d_in[7];
    const float* bo = (const float*)d_in[8];
    const float* W1 = (const float*)d_in[9];
    const float* b1 = (const float*)d_in[10];
    const float* W2 = (const float*)d_in[11];
    const float* b2 = (const float*)d_in[12];
    const float* g1 = (const float*)d_in[13];
    const float* be1 = (const float*)d_in[14];
    const float* g2 = (const float*)d_in[15];
    const float* be2 = (const float*)d_in[16];

    // ---- workspace: ~58.8 MiB total ----
    char* ws = (char*)d_ws;
    size_t off = 0;
    auto alloc = [&](size_t bytes) {
        void* p = ws + off;
        off += (bytes + 255) & ~(size_t)255;
        return p;
    };
    bf16* regA = (bf16*)alloc(32L * 1024 * 1024);  // qkv [0,24M) + {wqkvT then attn_out} [24M,32M); later a1 (32 MiB)
    float* x2 = (float*)alloc(4096L * 1024 * 4);   // 16 MiB: attn po0 scratch, then f32 residual
    bf16* buf1 = (bf16*)alloc(4096L * 1024 * 2);   // 8 MiB: W1T (from k_prep) -> W2T (after FF1)
    bf16* bufWo = (bf16*)alloc(1024L * 1024 * 2);  // 2 MiB: WoT (from k_prep)
    float* bqkv = (float*)alloc(3072L * 4);
    float* ps = (float*)alloc(32L * Bq * Cq * 4);  // LN partials; attn rs0 scratch
    float* pss = (float*)alloc(32L * Bq * Cq * 4); // LN partials; attn rs1 scratch
    float* mean1 = (float*)alloc(Bq * Cq * 4);
    float* rstd1 = (float*)alloc(Bq * Cq * 4);
    float* mean2 = (float*)alloc(Bq * Cq * 4);
    float* rstd2 = (float*)alloc(Bq * Cq * 4);
    bf16* dres = (bf16*)d_out;          // d_out first 8 MiB bf16 scratch: h -> h2
    float* outF = (float*)d_out;
    float* po1 = (float*)d_out;         // full 16 MiB of d_out as attn po1 (h dead then)
    bf16* wqkvT = regA + 12582912;      // 6 MiB at regA[24M,30M): read only by QKV gemm
    bf16* attn_out = regA + 12582912;   // same region, written by combine AFTER QKV done

    // prologue: Wqkv^T + Wo^T + W1^T + LN1-partials, ONE launch (all input-only)
    k_prep<<<dim3(8448), 256, 0, stream>>>(Wq, Wk, Wv, bqv, bkv, bvv, Wo, W1, x, wqkvT,
                                           bqkv, bufWo, buf1, ps, pss);
    k_ln_fin<<<dim3(8), 256, 0, stream>>>(ps, pss, mean1, rstd1);
    k_ln_apply<<<dim3(16384), 256, 0, stream>>>(x, mean1, rstd1, g1, be1, dres);

    // QKV projection -> q(scaled),k,vt in regA[0,24M)  (8-phase, 192 blocks)
    k_gemm_8ph<0><<<dim3(12, 16), 512, 0, stream>>>(dres, 1024, wqkvT, 1024, 1024, bqkv, regA,
                                                    0);
    // attention kc-split x2 -> partials (po0=x2, po1=d_out, rs in ps/pss)
    k_attn<<<dim3(16, 32, 2), 256, 0, stream>>>(regA, x2, po1, ps, pss);
    k_attn_combine<<<dim3(4096), 256, 0, stream>>>(x2, po1, ps, pss, attn_out);
    // x2 = attn@Wo + bo + x   (sq128 depth-2 pipeline, 256 blocks)
    k_gemm_sq128<1><<<dim3(8, 32), 256, 0, stream>>>(attn_out, 1024, bufWo, 1024, 1024, bo, x,
                                                     x2, 1024);
    // LN2 -> h2 (bf16, in d_out; po1 dead)
    k_ln_part<<<dim3(4, Bq, 32), 256, 0, stream>>>(x2, ps, pss);
    k_ln_fin<<<dim3(8), 256, 0, stream>>>(ps, pss, mean2, rstd2);
    k_ln_apply<<<dim3(16384), 256, 0, stream>>>(x2, mean2, rstd2, g2, be2, dres);

    // ---- FF ----
    // a1 = relu(h2 @ W1T + b1) -> regA [4096][4096] bf16  (8-phase 256^2 pipeline)
    k_gemm_8ph<2><<<dim3(16, 16), 512, 0, stream>>>(dres, 1024, buf1, 1024, 1024, b1, regA,
                                                    4096);
    k_transpose<<<dim3(32, 128, 1), 256, 0, stream>>>(W2, buf1, 4096, 1024, 0, 0);  // W2T
    // d_out(f32) = a1 @ W2T + b2 + x2   (sq128 depth-2 pipeline, 256 blocks)
    k_gemm_sq128<3><<<dim3(8, 32), 256, 0, stream>>>(regA, 4096, buf1, 4096, 4096, b2, x2,
                                                     outF, 1024);
}

// Round 13
// 361.384 us; speedup vs baseline: 1.0763x; 1.0042x over previous
//
#include <hip/hip_runtime.h>
#include <hip/hip_bf16.h>

#define Bq 2
#define Tq 2048
#define Cq 1024
#define Hq 16
#define HSq 64
#define EPSq 1e-5f

using bf16 = __hip_bfloat16;
using f32x4 = __attribute__((ext_vector_type(4))) float;
using f32x16 = __attribute__((ext_vector_type(16))) float;
using bf16x8 = __attribute__((ext_vector_type(8))) __bf16;

__device__ __forceinline__ bf16 f2bf(float f) { return __float2bfloat16(f); }
__device__ __forceinline__ unsigned short f2u(float f) {
    return __builtin_bit_cast(unsigned short, __float2bfloat16(f));
}
// async global->LDS, 16B per lane; LDS dest = wave-uniform base + lane*16
__device__ __forceinline__ void gload16(const void* g, void* l) {
    __builtin_amdgcn_global_load_lds((const __attribute__((address_space(1))) void*)g,
                                     (__attribute__((address_space(3))) void*)l, 16, 0, 0);
}

// q pre-scale: softmax 1/sqrt(64) * log2(e); attn uses raw v_exp_f32 (exp2).
#define QSCALE 0.180336884f

// ------------- transpose f32 src -> bf16 dst (dims multiples of 32) -------------
__global__ void k_transpose(const float* __restrict__ src, bf16* __restrict__ dst,
                            int R, int Cc, long strideSrc, long strideDst) {
    __shared__ bf16 tile[32][33];
    const long zb = blockIdx.z;
    src += zb * strideSrc;
    dst += zb * strideDst;
    int c0 = blockIdx.x * 32, r0 = blockIdx.y * 32;
    int tx = threadIdx.x & 31, ty = threadIdx.x >> 5;
    for (int i = ty; i < 32; i += 8)
        tile[i][tx] = f2bf(src[(long)(r0 + i) * Cc + (c0 + tx)]);
    __syncthreads();
    for (int i = ty; i < 32; i += 8)
        dst[(long)(c0 + i) * R + (r0 + tx)] = tile[tx][i];
}

// ==== k_prep: ALL input-only prologue work in ONE launch (verified r11/r12) =====
// blocks [0,3072): Wq/Wk/Wv per-head transpose -> wqkvT (+ bias pack piggyback)
// blocks [3072,4096): Wo^T -> woT
// blocks [4096,8192): W1^T -> w1T
// blocks [8192,8448): LN1 partial sums over sequence axis
__global__ void k_prep(const float* __restrict__ Wq, const float* __restrict__ Wk,
                       const float* __restrict__ Wv, const float* __restrict__ bqv,
                       const float* __restrict__ bkv, const float* __restrict__ bvv,
                       const float* __restrict__ Wo, const float* __restrict__ W1,
                       const float* __restrict__ x, bf16* __restrict__ wqkvT,
                       float* __restrict__ bqkvd, bf16* __restrict__ woT,
                       bf16* __restrict__ w1T, float* __restrict__ ps,
                       float* __restrict__ pss) {
    __shared__ bf16 tile[32][33];
    const int gb = blockIdx.x;
    const int tx = threadIdx.x & 31, ty = threadIdx.x >> 5;
    if (gb < 3072) {  // transpose3 (orig grid (2,32,48))
        const int bx2 = gb & 1, by2 = (gb >> 1) & 31, zb = gb >> 6;
        const int which = zb >> 4, head = zb & 15;
        const float* src = (which == 0 ? Wq : which == 1 ? Wk : Wv) + (long)head * 65536;
        bf16* d = wqkvT + (long)which * 1048576 + (long)head * 65536;
        const int c0 = bx2 * 32, r0 = by2 * 32;
        for (int i = ty; i < 32; i += 8)
            tile[i][tx] = f2bf(src[(long)(r0 + i) * 64 + (c0 + tx)]);
        if (bx2 == 0 && by2 == 0 && zb < 12) {
            int i = zb * 256 + threadIdx.x;  // 0..3071
            bqkvd[i] = i < 1024 ? bqv[i] : i < 2048 ? bkv[i - 1024] : bvv[i - 2048];
        }
        __syncthreads();
        for (int i = ty; i < 32; i += 8)
            d[(long)(c0 + i) * 1024 + (r0 + tx)] = tile[tx][i];
    } else if (gb < 4096) {  // WoT (orig grid (32,32))
        const int g = gb - 3072;
        const int c0 = (g & 31) * 32, r0 = (g >> 5) * 32;
        for (int i = ty; i < 32; i += 8)
            tile[i][tx] = f2bf(Wo[(long)(r0 + i) * 1024 + (c0 + tx)]);
        __syncthreads();
        for (int i = ty; i < 32; i += 8)
            woT[(long)(c0 + i) * 1024 + (r0 + tx)] = tile[tx][i];
    } else if (gb < 8192) {  // W1T (orig grid (128,32); src [1024][4096])
        const int g = gb - 4096;
        const int c0 = (g & 127) * 32, r0 = (g >> 7) * 32;
        for (int i = ty; i < 32; i += 8)
            tile[i][tx] = f2bf(W1[(long)(r0 + i) * 4096 + (c0 + tx)]);
        __syncthreads();
        for (int i = ty; i < 32; i += 8)
            w1T[(long)(c0 + i) * 1024 + (r0 + tx)] = tile[tx][i];
    } else {  // LN1 partial (orig grid (4,2,32))
        const int g = gb - 8192;
        const int c = (g & 3) * 256 + threadIdx.x;
        const int b = (g >> 2) & 1;
        const int tc = g >> 3;
        const float* p = x + (long)b * Tq * Cq + (long)tc * 64 * Cq + c;
        float s = 0.f, ss = 0.f;
        for (int t = 0; t < 64; ++t) {
            float v = p[(long)t * Cq];
            s += v;
            ss += v * v;
        }
        long o = ((long)tc * Bq + b) * Cq + c;
        ps[o] = s;
        pss[o] = ss;
    }
}

// ---------------- LayerNorm over the SEQUENCE axis (per (b,c)), f32 in ----------
__global__ void k_ln_part(const float* __restrict__ x, float* __restrict__ ps,
                          float* __restrict__ pss) {
    int c = blockIdx.x * 256 + threadIdx.x;
    int b = blockIdx.y;
    int tc = blockIdx.z;  // 32 chunks of 64 timesteps
    const float* p = x + (long)b * Tq * Cq + (long)tc * 64 * Cq + c;
    float s = 0.f, ss = 0.f;
    for (int t = 0; t < 64; ++t) {
        float v = p[(long)t * Cq];
        s += v;
        ss += v * v;
    }
    long o = ((long)tc * Bq + b) * Cq + c;
    ps[o] = s;
    pss[o] = ss;
}

__global__ void k_ln_fin(const float* __restrict__ ps, const float* __restrict__ pss,
                         float* __restrict__ mean, float* __restrict__ rstd) {
    int i = blockIdx.x * 256 + threadIdx.x;  // b*Cq + c
    float s = 0.f, ss = 0.f;
    for (int tc = 0; tc < 32; ++tc) {
        s += ps[(long)tc * (Bq * Cq) + i];
        ss += pss[(long)tc * (Bq * Cq) + i];
    }
    float m = s / (float)Tq;
    float var = (ss - s * m) / (float)(Tq - 1);  // ddof=1 (unbiased)
    var = fmaxf(var, 0.f);
    mean[i] = m;
    rstd[i] = 1.0f / (sqrtf(var) + EPSq);  // eps OUTSIDE sqrt
}

__global__ void k_ln_apply(const float* __restrict__ x, const float* __restrict__ mean,
                           const float* __restrict__ rstd, const float* __restrict__ gamma,
                           const float* __restrict__ beta, bf16* __restrict__ out) {
    long i = (long)blockIdx.x * 256 + threadIdx.x;
    int c = (int)(i & (Cq - 1));
    long bt = i >> 10;
    int b = (int)(bt >> 11);
    float m = mean[b * Cq + c], r = rstd[b * Cq + c];
    out[i] = f2bf(gamma[c] * ((x[i] - m) * r) + beta[c]);
}

// XCD-aware bijective chunked swizzle (nwg % 8 == 0 for all our grids)
__device__ __forceinline__ void xcd_swizzle(int& bx, int& by) {
    const int gx = gridDim.x;
    const int nwg = gx * gridDim.y;
    const int bid = blockIdx.y * gx + blockIdx.x;
    const int swz = (bid & 7) * (nwg >> 3) + (bid >> 3);
    bx = swz % gx;
    by = swz / gx;
}

// ======= bf16 NT-GEMM 128x64, 2-deep counted-vmcnt pipeline (proj, FF2) =========
// PERMANENT per r9/r10/r12 tile-shape matrix: thin 32x64 wave-tiles + BK=64 +
// 2 blocks/CU beats both BK=32 square (r10: 55.5) and BK=64 square 1-block/CU
// (r12: 54.2) -- cross-block TLP + step amortization dominate LDS traffic.
// T3/T4: 3 LDS buffers (72 KiB), stage(t+2) post-barrier, counted vmcnt(6)/step.
// MODE 1/3: outF = acc+bias+residF.
template <int MODE>
__global__ __launch_bounds__(256, 2) void k_gemm_n64p(
    const bf16* __restrict__ A, int lda, const bf16* __restrict__ Bt, int ldb, int K,
    const float* __restrict__ bias, const float* __restrict__ residF,
    float* __restrict__ outF, int ldout) {
    __shared__ __bf16 lds[36864];  // 3 x 12288 (72 KiB)
    int bx, by;
    xcd_swizzle(bx, by);
    const int m0 = by * 128, n0 = bx * 64;
    const int tid = threadIdx.x;
    const int lane = tid & 63, wave = tid >> 6;
    const int lane15 = lane & 15, quad = lane >> 4;
    const int wm = wave * 32;
    const int srow = wave * 16 + (lane >> 2);
    const int scol = (((lane & 3) ^ ((lane >> 3) & 3)) * 8);  // pre-swizzled source
    const int sq8 = (quad ^ ((lane15 >> 1) & 3)) * 8;         // swizzled read slot
    const bf16* Ap = A + (long)(m0 + srow) * lda + scol;
    const bf16* Ap2 = Ap + 64L * lda;
    const bf16* Bp = Bt + (long)(n0 + srow) * ldb + scol;
    const int NT = K >> 6;

    f32x4 acc[2][4];
#pragma unroll
    for (int i = 0; i < 2; ++i)
#pragma unroll
        for (int j = 0; j < 4; ++j)
#pragma unroll
            for (int p = 0; p < 4; ++p) acc[i][j][p] = 0.f;

    auto stage = [&](int t, int ofs) {
        const long ko = (long)t << 6;
        __bf16* b = &lds[ofs + wave * 512];
        gload16(Ap + ko, b);
        gload16(Ap2 + ko, b + 2048);
        gload16(Ap + ko + 32, b + 4096);
        gload16(Ap2 + ko + 32, b + 6144);
        gload16(Bp + ko, b + 8192);
        gload16(Bp + ko + 32, b + 10240);
    };
    auto comp = [&](int ofs) {
        const __bf16* base = &lds[ofs];
#pragma unroll
        for (int kk = 0; kk < 2; ++kk) {
            bf16x8 af[2], bfr[4];
#pragma unroll
            for (int i = 0; i < 2; ++i)
                af[i] = *(const bf16x8*)(base + kk * 4096 + (wm + i * 16 + lane15) * 32 + sq8);
#pragma unroll
            for (int j = 0; j < 4; ++j)
                bfr[j] =
                    *(const bf16x8*)(base + 8192 + kk * 2048 + (j * 16 + lane15) * 32 + sq8);
#pragma unroll
            for (int i = 0; i < 2; ++i)
#pragma unroll
                for (int j = 0; j < 4; ++j)
                    acc[i][j] = __builtin_amdgcn_mfma_f32_16x16x32_bf16(af[i], bfr[j],
                                                                        acc[i][j], 0, 0, 0);
        }
    };

    stage(0, 0);
    stage(1, 12288);
    int o0 = 0, o1 = 12288, o2 = 24576;  // cur / next / staging target
    for (int t = 0; t < NT - 1; ++t) {
        asm volatile("s_waitcnt vmcnt(6)" ::: "memory");  // tile t landed (all 6)
        __builtin_amdgcn_s_barrier();
        if (t + 2 < NT) stage(t + 2, o2);
        comp(o0);
        const int tmp = o0;
        o0 = o1;
        o1 = o2;
        o2 = tmp;
    }
    asm volatile("s_waitcnt vmcnt(0)" ::: "memory");  // last tile
    __builtin_amdgcn_s_barrier();
    comp(o0);

#pragma unroll
    for (int i = 0; i < 2; ++i) {
#pragma unroll
        for (int p = 0; p < 4; ++p) {
            const int m = m0 + wm + i * 16 + quad * 4 + p;
#pragma unroll
            for (int j = 0; j < 4; ++j) {
                const int n = n0 + j * 16 + lane15;
                outF[(long)m * ldout + n] =
                    acc[i][j][p] + bias[n] + residF[(long)m * ldout + n];
            }
        }
    }
}

// ======== 256x256 8-phase pipelined NT-GEMM (m201 template, plain HIP) ==========
// Verified r5-r12. T3+T4+T5; counted vmcnt(4) per K-tile.
// MODE 0: +bias, scatter qkv (q scaled by QSCALE, k plain, V^T packed).
// MODE 2: relu(+bias) -> bf16.
template <int MODE>
__global__ __launch_bounds__(512, 2) void k_gemm_8ph(
    const bf16* __restrict__ A, int lda, const bf16* __restrict__ Bt, int ldb, int K,
    const float* __restrict__ bias, bf16* __restrict__ outB, int ldout) {
    __shared__ __bf16 sA[2][2][256 * 32];
    __shared__ __bf16 sB[2][2][256 * 32];
    int bx, by;
    xcd_swizzle(bx, by);
    const int m0 = by * 256, n0 = bx * 256;
    const int tid = threadIdx.x;
    const int lane = tid & 63, wave = tid >> 6;
    const int lane15 = lane & 15, quad = lane >> 4;
    const int wr = wave >> 2, wc = wave & 3;  // wave tile: rows wr*128, cols wc*64
    const int sq8 = (quad ^ ((lane15 >> 1) & 3)) * 8;  // swizzled read slot
    const int arow = wr * 128 + lane15;
    const int brow = wc * 64 + lane15;
    const int sr = wave * 16 + (lane >> 2);                  // stage row
    const int sc = ((lane & 3) ^ ((lane >> 3) & 3)) * 8;     // pre-swizzled src slot
    const bf16* ApS = A + (long)(m0 + sr) * lda + sc;
    const bf16* BpS = Bt + (long)(n0 + sr) * ldb + sc;
    const int NT = K >> 6;       // K-tiles
    const int NP = NT << 2;      // planes (4 per tile)

    auto stage_plane = [&](int q) {
        if (q >= NP) return;
        const int t = q >> 2, slot = q & 3;
        const int db = t & 1, kk = slot >> 1;
        const long ko = ((long)t << 6) + kk * 32;
        if (!(slot & 1)) {
            gload16(ApS + ko, &sA[db][kk][wave * 512]);
            gload16(ApS + ko + 128L * lda, &sA[db][kk][4096 + wave * 512]);
        } else {
            gload16(BpS + ko, &sB[db][kk][wave * 512]);
            gload16(BpS + ko + 128L * ldb, &sB[db][kk][4096 + wave * 512]);
        }
    };

    f32x4 acc[8][4];
#pragma unroll
    for (int i = 0; i < 8; ++i)
#pragma unroll
        for (int j = 0; j < 4; ++j)
#pragma unroll
            for (int p = 0; p < 4; ++p) acc[i][j][p] = 0.f;

    stage_plane(0);
    stage_plane(1);
    stage_plane(2);
    stage_plane(3);
    stage_plane(4);
    stage_plane(5);
    asm volatile("s_waitcnt vmcnt(4)" ::: "memory");
    __builtin_amdgcn_s_barrier();

    for (int t = 0; t < NT; ++t) {
        const int db = t & 1;
        const __bf16* A0 = sA[db][0];
        const __bf16* A1 = sA[db][1];
        const __bf16* B0 = sB[db][0];
        const __bf16* B1 = sB[db][1];
        bf16x8 af[4], bfx[4];
        // ---- phase 0: kk0, m-half 0 ----
#pragma unroll
        for (int j = 0; j < 4; ++j)
            bfx[j] = *(const bf16x8*)(&B0[(brow + j * 16) * 32 + sq8]);
#pragma unroll
        for (int ii = 0; ii < 4; ++ii)
            af[ii] = *(const bf16x8*)(&A0[(arow + ii * 16) * 32 + sq8]);
        stage_plane(4 * t + 6);
        __builtin_amdgcn_s_barrier();
        __builtin_amdgcn_s_setprio(1);
#pragma unroll
        for (int ii = 0; ii < 4; ++ii)
#pragma unroll
            for (int j = 0; j < 4; ++j)
                acc[ii][j] =
                    __builtin_amdgcn_mfma_f32_16x16x32_bf16(af[ii], bfx[j], acc[ii][j], 0, 0, 0);
        __builtin_amdgcn_s_setprio(0);
        __builtin_amdgcn_s_barrier();
        // ---- phase 1: kk0, m-half 1 ----
#pragma unroll
        for (int ii = 0; ii < 4; ++ii)
            af[ii] = *(const bf16x8*)(&A0[(arow + 64 + ii * 16) * 32 + sq8]);
        stage_plane(4 * t + 7);
        __builtin_amdgcn_s_barrier();
        __builtin_amdgcn_s_setprio(1);
#pragma unroll
        for (int ii = 0; ii < 4; ++ii)
#pragma unroll
            for (int j = 0; j < 4; ++j)
                acc[4 + ii][j] = __builtin_amdgcn_mfma_f32_16x16x32_bf16(af[ii], bfx[j],
                                                                         acc[4 + ii][j], 0, 0, 0);
        __builtin_amdgcn_s_setprio(0);
        __builtin_amdgcn_s_barrier();
        // ---- phase 2: kk1, m-half 0 ----
#pragma unroll
        for (int j = 0; j < 4; ++j)
            bfx[j] = *(const bf16x8*)(&B1[(brow + j * 16) * 32 + sq8]);
#pragma unroll
        for (int ii = 0; ii < 4; ++ii)
            af[ii] = *(const bf16x8*)(&A1[(arow + ii * 16) * 32 + sq8]);
        stage_plane(4 * t + 8);
        __builtin_amdgcn_s_barrier();
        __builtin_amdgcn_s_setprio(1);
#pragma unroll
        for (int ii = 0; ii < 4; ++ii)
#pragma unroll
            for (int j = 0; j < 4; ++j)
                acc[ii][j] =
                    __builtin_amdgcn_mfma_f32_16x16x32_bf16(af[ii], bfx[j], acc[ii][j], 0, 0, 0);
        __builtin_amdgcn_s_setprio(0);
        __builtin_amdgcn_s_barrier();
        // ---- phase 3: kk1, m-half 1 ----
#pragma unroll
        for (int ii = 0; ii < 4; ++ii)
            af[ii] = *(const bf16x8*)(&A1[(arow + 64 + ii * 16) * 32 + sq8]);
        stage_plane(4 * t + 9);
        __builtin_amdgcn_s_barrier();
        __builtin_amdgcn_s_setprio(1);
#pragma unroll
        for (int ii = 0; ii < 4; ++ii)
#pragma unroll
            for (int j = 0; j < 4; ++j)
                acc[4 + ii][j] = __builtin_amdgcn_mfma_f32_16x16x32_bf16(af[ii], bfx[j],
                                                                         acc[4 + ii][j], 0, 0, 0);
        __builtin_amdgcn_s_setprio(0);
        asm volatile("s_waitcnt vmcnt(4)" ::: "memory");
        __builtin_amdgcn_s_barrier();
    }
    // epilogue (C/D layout col=lane&15, row=quad*4+reg; verified m89/m91)
    if (MODE == 0) {
#pragma unroll
        for (int i = 0; i < 8; ++i) {
            const int mm = m0 + wr * 128 + i * 16 + quad * 4;  // t base; p adds 0..3
            const int b = mm >> 11, t4 = mm & (Tq - 1);
#pragma unroll
            for (int j = 0; j < 4; ++j) {
                const int n = n0 + wc * 64 + j * 16 + lane15;
                const int which = n >> 10, hh = (n >> 6) & (Hq - 1), d = n & (HSq - 1);
                const long bh = (long)b * Hq + hh;
                const float bb = bias[n];
                if (which == 0) {  // q, pre-scaled by QSCALE (softmax*log2e folded)
#pragma unroll
                    for (int p = 0; p < 4; ++p)
                        outB[bh * 131072 + (long)(t4 + p) * HSq + d] =
                            f2bf((acc[i][j][p] + bb) * QSCALE);
                } else if (which == 1) {  // k
#pragma unroll
                    for (int p = 0; p < 4; ++p)
                        outB[4194304L + bh * 131072 + (long)(t4 + p) * HSq + d] =
                            f2bf(acc[i][j][p] + bb);
                } else {  // V stored transposed [bh][d][t], 4 consecutive t packed
                    ushort4 pk;
                    pk.x = f2u(acc[i][j][0] + bb);
                    pk.y = f2u(acc[i][j][1] + bb);
                    pk.z = f2u(acc[i][j][2] + bb);
                    pk.w = f2u(acc[i][j][3] + bb);
                    *(ushort4*)(&outB[8388608L + bh * 131072 + (long)d * Tq + t4]) = pk;
                }
            }
        }
    } else {  // MODE 2: relu(acc + bias) -> bf16
#pragma unroll
        for (int i = 0; i < 8; ++i) {
#pragma unroll
            for (int p = 0; p < 4; ++p) {
                const int m = m0 + wr * 128 + i * 16 + quad * 4 + p;
#pragma unroll
                for (int j = 0; j < 4; ++j) {
                    const int n = n0 + wc * 64 + j * 16 + lane15;
                    outB[(long)m * ldout + n] = f2bf(fmaxf(acc[i][j][p] + bias[n], 0.f));
                }
            }
        }
    }
}

// ---------------- flash attention, kc-split x2, bh-major XCD locality ------------
// Verified r8-r12: FETCH 69.7 -> 12.3 MB (K/V L2-resident); raw v_exp_f32.
// r13: shuffle-transpose pack replaced by v_permlane32_swap (T12 primitive,
// 1.20x vs ds_bpermute for lane[i]<->lane[i+32]). Word mapping verified against
// the shfl_xor version: f0 = {swap(pk0,pk2).lo, swap(pk1,pk3).lo,
// swap(pk0,pk2).hi, swap(pk1,pk3).hi}, same for f1 with pk4..pk7.
__global__ __launch_bounds__(256, 4) void k_attn(const bf16* __restrict__ qkv,
                                                 float* __restrict__ po0,
                                                 float* __restrict__ po1,
                                                 float* __restrict__ rs0,
                                                 float* __restrict__ rs1) {
    __shared__ __bf16 sK[64 * 72];
    __shared__ __bf16 sVt[64 * 72];
    const int nlin = blockIdx.x + (int)(gridDim.x * (blockIdx.y + gridDim.y * blockIdx.z));
    const int xcd = nlin & 7, s = nlin >> 3;
    const int bh = (xcd << 2) | (s >> 5);
    const int rem = s & 31;
    const int q0 = (rem & 15) * 128;
    const int z = rem >> 4;
    const int kc0 = z << 10;
    float* __restrict__ po = z ? po1 : po0;
    float* __restrict__ rsb = z ? rs1 : rs0;
    const int tid = threadIdx.x, wave = tid >> 6, lane = tid & 63;
    const int lane31 = lane & 31, laneh = lane >> 5;
    const bf16* Qp = qkv + (long)bh * 131072;
    const bf16* Kp = qkv + 4194304L + (long)bh * 131072;
    const bf16* Vtp = qkv + 8388608L + (long)bh * 131072;
    bf16x8 qa[4];
#pragma unroll
    for (int s2 = 0; s2 < 4; ++s2)
        qa[s2] = *(const bf16x8*)(&Qp[(long)(q0 + wave * 32 + lane31) * HSq + s2 * 16 + laneh * 8]);
    f32x16 o[2];
#pragma unroll
    for (int dt = 0; dt < 2; ++dt)
#pragma unroll
        for (int r = 0; r < 16; ++r) o[dt][r] = 0.f;
    float rs = 0.f;
    const int r0 = tid >> 3, c0 = (tid & 7) * 8;
    const int r1 = r0 + 32;

    uint4 nk0 = *(const uint4*)(&Kp[(long)(kc0 + r0) * HSq + c0]);
    uint4 nk1 = *(const uint4*)(&Kp[(long)(kc0 + r1) * HSq + c0]);
    uint4 nv0 = *(const uint4*)(&Vtp[(long)r0 * Tq + kc0 + c0]);
    uint4 nv1 = *(const uint4*)(&Vtp[(long)r1 * Tq + kc0 + c0]);

    for (int kc = kc0; kc < kc0 + 1024; kc += 64) {
        __syncthreads();
        *(uint4*)(&sK[r0 * 72 + c0]) = nk0;
        *(uint4*)(&sK[r1 * 72 + c0]) = nk1;
        *(uint4*)(&sVt[r0 * 72 + c0]) = nv0;
        *(uint4*)(&sVt[r1 * 72 + c0]) = nv1;
        __syncthreads();
        if (kc + 64 < kc0 + 1024) {
            nk0 = *(const uint4*)(&Kp[(long)(kc + 64 + r0) * HSq + c0]);
            nk1 = *(const uint4*)(&Kp[(long)(kc + 64 + r1) * HSq + c0]);
            nv0 = *(const uint4*)(&Vtp[(long)r0 * Tq + kc + 64 + c0]);
            nv1 = *(const uint4*)(&Vtp[(long)r1 * Tq + kc + 64 + c0]);
        }
#pragma unroll
        for (int nt = 0; nt < 2; ++nt) {
            f32x16 zz;
#pragma unroll
            for (int r = 0; r < 16; ++r) zz[r] = 0.f;
            __builtin_amdgcn_s_setprio(1);
#pragma unroll
            for (int s2 = 0; s2 < 4; ++s2) {
                bf16x8 kb =
                    *(const bf16x8*)(&sK[(nt * 32 + lane31) * 72 + s2 * 16 + laneh * 8]);
                zz = __builtin_amdgcn_mfma_f32_32x32x16_bf16(kb, qa[s2], zz, 0, 0, 0);
            }
            __builtin_amdgcn_s_setprio(0);
            float e[16];
#pragma unroll
            for (int r = 0; r < 16; ++r) {
                e[r] = __builtin_amdgcn_exp2f(zz[r]);  // raw v_exp_f32 (q pre-scaled)
                rs += e[r];
            }
            unsigned int pk[8];
#pragma unroll
            for (int g = 0; g < 4; ++g)
#pragma unroll
                for (int h = 0; h < 2; ++h)
                    pk[g * 2 + h] = (unsigned int)f2u(e[g * 4 + 2 * h]) |
                                    ((unsigned int)f2u(e[g * 4 + 2 * h + 1]) << 16);
            // lane<->lane+32 redistribution via v_permlane32_swap (4 insts,
            // replaces 4 ds_bpermute + ~12 cndmask)
            auto wA = __builtin_amdgcn_permlane32_swap((int)pk[0], (int)pk[2], false, false);
            auto wB = __builtin_amdgcn_permlane32_swap((int)pk[1], (int)pk[3], false, false);
            auto wC = __builtin_amdgcn_permlane32_swap((int)pk[4], (int)pk[6], false, false);
            auto wD = __builtin_amdgcn_permlane32_swap((int)pk[5], (int)pk[7], false, false);
            uint4 f0 = {(unsigned)wA[0], (unsigned)wB[0], (unsigned)wA[1], (unsigned)wB[1]};
            uint4 f1 = {(unsigned)wC[0], (unsigned)wD[0], (unsigned)wC[1], (unsigned)wD[1]};
            bf16x8 pa0 = __builtin_bit_cast(bf16x8, f0);
            bf16x8 pa1 = __builtin_bit_cast(bf16x8, f1);
            __builtin_amdgcn_s_setprio(1);
#pragma unroll
            for (int dt = 0; dt < 2; ++dt) {
                bf16x8 vb0 =
                    *(const bf16x8*)(&sVt[(dt * 32 + lane31) * 72 + nt * 32 + laneh * 8]);
                bf16x8 vb1 = *(const bf16x8*)(&sVt[(dt * 32 + lane31) * 72 + nt * 32 + 16 +
                                                   laneh * 8]);
                o[dt] = __builtin_amdgcn_mfma_f32_32x32x16_bf16(pa0, vb0, o[dt], 0, 0, 0);
                o[dt] = __builtin_amdgcn_mfma_f32_32x32x16_bf16(pa1, vb1, o[dt], 0, 0, 0);
            }
            __builtin_amdgcn_s_setprio(0);
        }
    }
    // partial epilogue: store unnormalized O (f32) + this half's row sums
    float ltot = rs + __shfl_xor(rs, 32);
    if (laneh == 0) rsb[(bh << 11) + q0 + wave * 32 + lane31] = ltot;
#pragma unroll
    for (int r = 0; r < 16; ++r) {
        const int tl = (r & 3) + 8 * (r >> 2) + 4 * laneh;
        const int t = q0 + wave * 32 + tl;
        float* pb = po + ((long)(bh << 11) + t) * 64;
#pragma unroll
        for (int dt = 0; dt < 2; ++dt) pb[dt * 32 + lane31] = o[dt][r];
    }
}

// combine: out[b][t][h*64+d] = bf16((po0+po1) / (rs0+rs1)) — 4 floats/thread
__global__ __launch_bounds__(256) void k_attn_combine(
    const float* __restrict__ po0, const float* __restrict__ po1,
    const float* __restrict__ rs0, const float* __restrict__ rs1,
    bf16* __restrict__ out) {
    const long i = ((long)blockIdx.x * 256 + threadIdx.x) * 4;
    const int d = (int)(i & 63);
    const long qq = i >> 6;  // bh*2048 + t
    const int bh = (int)(qq >> 11), t = (int)(qq & 2047);
    const float inv = 1.0f / (rs0[qq] + rs1[qq]);
    const f32x4 a = *(const f32x4*)(po0 + i);
    const f32x4 b = *(const f32x4*)(po1 + i);
    const int bb = bh >> 4, hh = bh & 15;
    ushort4 pk;
    pk.x = f2u((a[0] + b[0]) * inv);
    pk.y = f2u((a[1] + b[1]) * inv);
    pk.z = f2u((a[2] + b[2]) * inv);
    pk.w = f2u((a[3] + b[3]) * inv);
    *(ushort4*)(&out[(((long)bb * Tq + t) << 10) + hh * 64 + d]) = pk;
}

extern "C" void kernel_launch(void* const* d_in, const int* in_sizes, int n_in,
                              void* d_out, int out_size, void* d_ws, size_t ws_size,
                              hipStream_t stream) {
    const float* x = (const float*)d_in[0];
    const float* Wq = (const float*)d_in[1];
    const float* bqv = (const float*)d_in[2];
    const float* Wk = (const float*)d_in[3];
    const float* bkv = (const float*)d_in[4];
    const float* Wv = (const float*)d_in[5];
    const float* bvv = (const float*)d_in[6];
    const float* Wo = (const float*)d_in[7];
    const float* bo = (const float*)d_in[8];
    const float* W1 = (const float*)d_in[9];
    const float* b1 = (const float*)d_in[10];
    const float* W2 = (const float*)d_in[11];
    const float* b2 = (const float*)d_in[12];
    const float* g1 = (const float*)d_in[13];
    const float* be1 = (const float*)d_in[14];
    const float* g2 = (const float*)d_in[15];
    const float* be2 = (const float*)d_in[16];

    // ---- workspace: ~58.8 MiB total ----
    char* ws = (char*)d_ws;
    size_t off = 0;
    auto alloc = [&](size_t bytes) {
        void* p = ws + off;
        off += (bytes + 255) & ~(size_t)255;
        return p;
    };
    bf16* regA = (bf16*)alloc(32L * 1024 * 1024);  // qkv [0,24M) + {wqkvT then attn_out} [24M,32M); later a1 (32 MiB)
    float* x2 = (float*)alloc(4096L * 1024 * 4);   // 16 MiB: attn po0 scratch, then f32 residual
    bf16* buf1 = (bf16*)alloc(4096L * 1024 * 2);   // 8 MiB: W1T (from k_prep) -> W2T (after FF1)
    bf16* bufWo = (bf16*)alloc(1024L * 1024 * 2);  // 2 MiB: WoT (from k_prep)
    float* bqkv = (float*)alloc(3072L * 4);
    float* ps = (float*)alloc(32L * Bq * Cq * 4);  // LN partials; attn rs0 scratch
    float* pss = (float*)alloc(32L * Bq * Cq * 4); // LN partials; attn rs1 scratch
    float* mean1 = (float*)alloc(Bq * Cq * 4);
    float* rstd1 = (float*)alloc(Bq * Cq * 4);
    float* mean2 = (float*)alloc(Bq * Cq * 4);
    float* rstd2 = (float*)alloc(Bq * Cq * 4);
    bf16* dres = (bf16*)d_out;          // d_out first 8 MiB bf16 scratch: h -> h2
    float* outF = (float*)d_out;
    float* po1 = (float*)d_out;         // full 16 MiB of d_out as attn po1 (h dead then)
    bf16* wqkvT = regA + 12582912;      // 6 MiB at regA[24M,30M): read only by QKV gemm
    bf16* attn_out = regA + 12582912;   // same region, written by combine AFTER QKV done

    // prologue: Wqkv^T + Wo^T + W1^T + LN1-partials, ONE launch (all input-only)
    k_prep<<<dim3(8448), 256, 0, stream>>>(Wq, Wk, Wv, bqv, bkv, bvv, Wo, W1, x, wqkvT,
                                           bqkv, bufWo, buf1, ps, pss);
    k_ln_fin<<<dim3(8), 256, 0, stream>>>(ps, pss, mean1, rstd1);
    k_ln_apply<<<dim3(16384), 256, 0, stream>>>(x, mean1, rstd1, g1, be1, dres);

    // QKV projection -> q(scaled),k,vt in regA[0,24M)  (8-phase, 192 blocks)
    k_gemm_8ph<0><<<dim3(12, 16), 512, 0, stream>>>(dres, 1024, wqkvT, 1024, 1024, bqkv, regA,
                                                    0);
    // attention kc-split x2 -> partials (po0=x2, po1=d_out, rs in ps/pss)
    k_attn<<<dim3(16, 32, 2), 256, 0, stream>>>(regA, x2, po1, ps, pss);
    k_attn_combine<<<dim3(4096), 256, 0, stream>>>(x2, po1, ps, pss, attn_out);
    // x2 = attn@Wo + bo + x   (n64p pipelined 128x64, 512 blocks, 2/CU)
    k_gemm_n64p<1><<<dim3(16, 32), 256, 0, stream>>>(attn_out, 1024, bufWo, 1024, 1024, bo, x,
                                                     x2, 1024);
    // LN2 -> h2 (bf16, in d_out; po1 dead)
    k_ln_part<<<dim3(4, Bq, 32), 256, 0, stream>>>(x2, ps, pss);
    k_ln_fin<<<dim3(8), 256, 0, stream>>>(ps, pss, mean2, rstd2);
    k_ln_apply<<<dim3(16384), 256, 0, stream>>>(x2, mean2, rstd2, g2, be2, dres);

    // ---- FF ----
    // a1 = relu(h2 @ W1T + b1) -> regA [4096][4096] bf16  (8-phase 256^2 pipeline)
    k_gemm_8ph<2><<<dim3(16, 16), 512, 0, stream>>>(dres, 1024, buf1, 1024, 1024, b1, regA,
                                                    4096);
    k_transpose<<<dim3(32, 128, 1), 256, 0, stream>>>(W2, buf1, 4096, 1024, 0, 0);  // W2T
    // d_out(f32) = a1 @ W2T + b2 + x2   (n64p pipelined 128x64, 512 blocks, 2/CU)
    k_gemm_n64p<3><<<dim3(16, 32), 256, 0, stream>>>(regA, 4096, buf1, 4096, 4096, b2, x2,
                                                     outF, 1024);
}